// Round 1
// baseline (64550.439 us; speedup 1.0000x reference)
//
#include <hip/hip_runtime.h>
#include <math.h>

#define NT 512
#define NB 32

// ---------------- fp32 arena (per-batch, element offsets) ----------------
#define OF_D    0        // 124416 : double-tensor D_j (max 144 x 864)
#define OF_A    124416   // 124416 : A1/A2/A4
#define OF_A3   248832   // 124416 : A3 (kept through round)
#define OF_Q2   373248   // 31104  : Q2 (216 x K)
#define OF_Q4   404352   // 31104  : Q4 (6K x 36)
#define OF_TB   435456   // 20736  : t-matrix buffer (max 144x144)
#define OF_Q1   456192   // 1296
#define OF_Q0   457488   // 64
#define OF_ROW  457552   // 5616   : gathered row tensors
#define OF_R    463168   // 20736  : current R (dense, fp32)
#define OF_T    483904   // 20736  : current T = R^-1 (fp32)
#define OF_T3   504640   // 20736  : T3 kept
#define F_STRIDE 525392

// ---------------- fp64 arena ----------------
#define OD_G    0        // 20736 : Gram / chol workspace
#define OD_CA   20736    // 8712  : cand buffer A
#define OD_CB   29448    // 8712  : cand buffer B
#define OD_X    38160    // 3456  : push factor X (max 144x24)
#define OD_Z    41616    // 3456  : Z = T3*X4
#define OD_T5   45072    // 216   : t5 (36x6)
#define OD_X5   45288    // 216   : X5 (36x6)
#define OD_QP   45504    // 64    : Q' (6x6)
#define OD_X1   45568    // 64    : X1 (6x6)
#define OD_T1   45632    // 864   : t1 (6x144)
#define D_STRIDE 46528

__device__ float  g_f32[(size_t)NB * F_STRIDE];
__device__ double g_f64[(size_t)NB * D_STRIDE];

// ---------------- LDS layout (byte offsets into dynamic pool) ----------------
#define LO_J     82944   // J accumulator 36x36 fp32 (after 144x144 B region)
#define LO_NORM  88128   // double[144]
#define LO_S     89280   // double[24]
#define LO_E     89472   // double[144]
#define LO_E2    90624   // double[144]
#define LO_SEL   91776   // int[24]
#define LO_FLAG  91872   // int
#define LO_LOG   91880   // double
#define LO_SCALE 91888   // double
#define LDS_BYTES 92160

__device__ __forceinline__ char* ldsp() {
  extern __shared__ char lds_pool[];
  return lds_pool;
}
#define L_B(p)     ((float*)(p))
#define L_J(p)     ((float*)((p)+LO_J))
#define L_NORM(p)  ((double*)((p)+LO_NORM))
#define L_S(p)     ((double*)((p)+LO_S))
#define L_E(p)     ((double*)((p)+LO_E))
#define L_E2(p)    ((double*)((p)+LO_E2))
#define L_SEL(p)   ((int*)((p)+LO_SEL))
#define L_FLAG(p)  ((int*)((p)+LO_FLAG))
#define L_LOG(p)   ((double*)((p)+LO_LOG))
#define L_SCALE(p) ((double*)((p)+LO_SCALE))

// ---------------- generic small matmuls (tid-strided, fp64/chunked-fp32 acc) ----------------
template<typename TA, typename TB, typename TC>
__device__ void mm_nn(const TA* __restrict__ A, int lda, const TB* __restrict__ Bm, int ldb,
                      TC* __restrict__ C, int ldc, int M, int N, int Kd, int tid) {
  constexpr bool FF = (sizeof(TA) == 4) && (sizeof(TB) == 4);
  for (int idx = tid; idx < M * N; idx += NT) {
    int i = idx / N, j = idx - i * N;
    const TA* a = A + (size_t)i * lda;
    double acc = 0.0;
    if constexpr (FF) {
      int k = 0;
      while (k < Kd) {
        int ke = k + 64; if (ke > Kd) ke = Kd;
        float f = 0.f;
        for (; k < ke; ++k) f += (float)a[k] * (float)Bm[(size_t)k * ldb + j];
        acc += (double)f;
      }
    } else {
      for (int k = 0; k < Kd; ++k) acc += (double)a[k] * (double)Bm[(size_t)k * ldb + j];
    }
    C[(size_t)i * ldc + j] = (TC)acc;
  }
  __syncthreads();
}

template<typename TA, typename TB, typename TC>
__device__ void mm_tn(const TA* __restrict__ A, int lda, const TB* __restrict__ Bm, int ldb,
                      TC* __restrict__ C, int ldc, int M, int N, int Kd, int tid) {
  constexpr bool FF = (sizeof(TA) == 4) && (sizeof(TB) == 4);
  for (int idx = tid; idx < M * N; idx += NT) {
    int i = idx / N, j = idx - i * N;
    double acc = 0.0;
    if constexpr (FF) {
      int k = 0;
      while (k < Kd) {
        int ke = k + 64; if (ke > Kd) ke = Kd;
        float f = 0.f;
        for (; k < ke; ++k) f += (float)A[(size_t)k * lda + i] * (float)Bm[(size_t)k * ldb + j];
        acc += (double)f;
      }
    } else {
      for (int k = 0; k < Kd; ++k) acc += (double)A[(size_t)k * lda + i] * (double)Bm[(size_t)k * ldb + j];
    }
    C[(size_t)i * ldc + j] = (TC)acc;
  }
  __syncthreads();
}

template<typename TA, typename TB, typename TC>
__device__ void mm_nt(const TA* __restrict__ A, int lda, const TB* __restrict__ Bm, int ldb,
                      TC* __restrict__ C, int ldc, int M, int N, int Kd, int tid) {
  for (int idx = tid; idx < M * N; idx += NT) {
    int i = idx / N, j = idx - i * N;
    double acc = 0.0;
    for (int k = 0; k < Kd; ++k) acc += (double)A[(size_t)i * lda + k] * (double)Bm[(size_t)j * ldb + k];
    C[(size_t)i * ldc + j] = (TC)acc;
  }
  __syncthreads();
}

// ---------------- Cholesky (fp64, in-place upper R, G = R^T R) ----------------
__device__ void cholesky(double* G, int n, int tid) {
  for (int j = 0; j < n; ++j) {
    __syncthreads();
    double piv = G[(size_t)j * n + j];
    double r = sqrt(piv > 1e-30 ? piv : 1e-30);
    double inv = 1.0 / r;
    __syncthreads();
    for (int i = j + tid; i < n; i += NT) {
      G[(size_t)j * n + i] = (i == j) ? r : G[(size_t)j * n + i] * inv;
    }
    __syncthreads();
    int w = n - j - 1;
    for (int idx = tid; idx < w * w; idx += NT) {
      int ii = idx / w, kk = idx - ii * w;
      int i = j + 1 + ii, k2 = j + 1 + kk;
      if (k2 >= i) G[(size_t)i * n + k2] -= G[(size_t)j * n + i] * G[(size_t)j * n + k2];
    }
  }
  __syncthreads();
}

// T = R^{-1} (upper), read fp64 G upper, write fp32 dense T (lower zeroed)
__device__ void trinv(const double* G, int n, float* T, int tid) {
  for (int c = tid; c < n; c += NT) {
    T[(size_t)c * n + c] = (float)(1.0 / G[(size_t)c * n + c]);
    for (int r = c - 1; r >= 0; --r) {
      double s = 0.0;
      for (int k = r + 1; k <= c; ++k) s += G[(size_t)r * n + k] * (double)T[(size_t)k * n + c];
      T[(size_t)r * n + c] = (float)(-s / G[(size_t)r * n + r]);
    }
    for (int r = c + 1; r < n; ++r) T[(size_t)r * n + c] = 0.f;
  }
  __syncthreads();
}

__device__ void copyR(const double* G, int n, float* Rw, int tid) {
  for (int idx = tid; idx < n * n; idx += NT) {
    int i = idx / n, k = idx - i * n;
    Rw[idx] = (k >= i) ? (float)G[idx] : 0.f;
  }
  __syncthreads();
}

// tall CholQR: A (Mr x Nc), Mr >= Nc. Q optional, Rw optional (dense NcxNc fp32)
__device__ void tallQR(const float* A, int Mr, int Nc, float* Q, float* Rw,
                       double* G, float* T, int tid) {
  mm_tn<float,float,double>(A, Nc, A, Nc, G, Nc, Nc, Nc, Mr, tid);
  cholesky(G, Nc, tid);
  trinv(G, Nc, T, tid);
  if (Q)  mm_nn<float,float,float>(A, Nc, T, Nc, Q, Nc, Mr, Nc, Nc, tid);
  if (Rw) copyR(G, Nc, Rw, tid);
}

// wide QR (Mr < Nc): QR of first Mr cols, Rw = Q^T A (Mr x Nc)
__device__ void wideQR(const float* A, int Mr, int Nc, float* Q, float* Rw,
                       double* G, float* T, int tid) {
  mm_tn<float,float,double>(A, Nc, A, Nc, G, Mr, Mr, Mr, Mr, tid);
  cholesky(G, Mr, tid);
  trinv(G, Mr, T, tid);
  mm_nn<float,float,float>(A, Nc, T, Mr, Q, Mr, Mr, Mr, Mr, tid);
  mm_tn<float,float,float>(Q, Mr, A, Nc, Rw, Nc, Mr, Nc, Mr, tid);
}

// ---------------- double-tensor build ----------------
// cand (cl,6,cr) fp64 ; rowS (al,6,6,ar) fp32 ; D rows=(cl*al), cols=6*(cr*ar)
__device__ void build_D(const double* __restrict__ cand, int cl, int cr,
                        const float* __restrict__ rowS, int al, int ar,
                        float* __restrict__ D, int tid) {
  int mnext = cr * ar;
  int ncols = 6 * mnext;
  int n = cl * al * ncols;
  for (int idx = tid; idx < n; idx += NT) {
    int row = idx / ncols, col = idx - row * ncols;
    int l = row / al, L = row - l * al;
    int d = col / mnext, rem = col - d * mnext;
    int rr = rem / ar, R_ = rem - rr * ar;
    double acc = 0.0;
#pragma unroll
    for (int mu = 0; mu < 6; ++mu)
      acc += cand[(l * 6 + mu) * cr + rr] * (double)rowS[((L * 6 + mu) * 6 + d) * ar + R_];
    D[idx] = (float)acc;
  }
  __syncthreads();
}

// gather a physical row r into ROW buffer; dd = down-dim (6 normal, 1 for row 5)
__device__ void gather_row(const int* cfg, const float* tens, int b, int r, int dd,
                           float* ROW, const int* roff, int tid) {
  for (int j = 0; j < 6; ++j) {
    int al = (j == 0) ? 1 : 6, ar = (j == 5) ? 1 : 6;
    const float* base = tens + (size_t)(((r * 6 + j) * 2 + cfg[b * 36 + r * 6 + j])) * 1296;
    int n = al * 6 * dd * ar;
    float* dst = ROW + roff[j];
    for (int idx = tid; idx < n; idx += NT) {
      int R_ = idx % ar; int t2 = idx / ar;
      int d = t2 % dd; t2 /= dd;
      int mu = t2 % 6; int L = t2 / 6;
      dst[idx] = base[L * 216 + mu * 36 + d * 6 + R_];
    }
  }
  __syncthreads();
}

// ---------------- one-sided Jacobi SVD ----------------
// C=36 columns, R rows, with J (36x36) accumulation. 8 threads/pair.
__device__ void jacobi36(float* B, int R, float* J, int* flag, int tid) {
  for (int i = tid; i < 36 * 36; i += NT) J[i] = ((i / 36) == (i % 36)) ? 1.f : 0.f;
  __syncthreads();
  for (int sw = 0; sw < 9; ++sw) {
    if (tid == 0) *flag = 0;
    __syncthreads();
    for (int t = 0; t < 35; ++t) {
      int s = tid >> 3, h = tid & 7;
      bool act = (tid < 144);
      int p = 0, q = 0; float c = 1.f, sn = 0.f; bool doit = false;
      if (act) {
        if (s == 0) { p = 35; q = t % 35; }
        else { p = (t + s) % 35; q = (t - s + 35) % 35; }
        float app = 0.f, aqq = 0.f, apq = 0.f;
        for (int r = h; r < R; r += 8) {
          float x = B[r * 36 + p], y = B[r * 36 + q];
          app += x * x; aqq += y * y; apq += x * y;
        }
        app += __shfl_xor(app, 1); aqq += __shfl_xor(aqq, 1); apq += __shfl_xor(apq, 1);
        app += __shfl_xor(app, 2); aqq += __shfl_xor(aqq, 2); apq += __shfl_xor(apq, 2);
        app += __shfl_xor(app, 4); aqq += __shfl_xor(aqq, 4); apq += __shfl_xor(apq, 4);
        double g = (double)apq, aa = (double)app, bb = (double)aqq;
        if (g * g > 1e-14 * aa * bb) {
          doit = true;
          if (h == 0) *flag = 1;
          double tau = (bb - aa) / (2.0 * g);
          double tt = (tau >= 0.0 ? 1.0 : -1.0) / (fabs(tau) + sqrt(1.0 + tau * tau));
          double cc = 1.0 / sqrt(1.0 + tt * tt);
          c = (float)cc; sn = (float)(tt * cc);
        }
      }
      if (doit) {
        for (int r = h; r < R; r += 8) {
          float x = B[r * 36 + p], y = B[r * 36 + q];
          B[r * 36 + p] = c * x - sn * y;
          B[r * 36 + q] = sn * x + c * y;
        }
        for (int r = h; r < 36; r += 8) {
          float x = J[r * 36 + p], y = J[r * 36 + q];
          J[r * 36 + p] = c * x - sn * y;
          J[r * 36 + q] = sn * x + c * y;
        }
      }
      __syncthreads();
    }
    int f = *flag;
    __syncthreads();
    if (!f) break;
  }
}

// C=144 columns, 144 rows, no J accumulation. 4 threads/pair, columns cached in regs.
__device__ void jacobi144(float* B, int* flag, int tid) {
  for (int sw = 0; sw < 9; ++sw) {
    if (tid == 0) *flag = 0;
    __syncthreads();
    for (int t = 0; t < 143; ++t) {
      int s = tid >> 2, h = tid & 3;
      bool act = (tid < 288);
      float xp[36], xq[36];
      int p = 0, q = 0; float c = 1.f, sn = 0.f; bool doit = false;
      if (act) {
        if (s == 0) { p = 143; q = t % 143; }
        else { p = (t + s) % 143; q = (t - s + 143) % 143; }
        float app = 0.f, aqq = 0.f, apq = 0.f;
#pragma unroll
        for (int i = 0; i < 36; ++i) {
          int r = h + 4 * i;
          float x = B[r * 144 + p], y = B[r * 144 + q];
          xp[i] = x; xq[i] = y;
          app += x * x; aqq += y * y; apq += x * y;
        }
        app += __shfl_xor(app, 1); aqq += __shfl_xor(aqq, 1); apq += __shfl_xor(apq, 1);
        app += __shfl_xor(app, 2); aqq += __shfl_xor(aqq, 2); apq += __shfl_xor(apq, 2);
        double g = (double)apq, aa = (double)app, bb = (double)aqq;
        if (g * g > 1e-14 * aa * bb) {
          doit = true;
          if (h == 0) *flag = 1;
          double tau = (bb - aa) / (2.0 * g);
          double tt = (tau >= 0.0 ? 1.0 : -1.0) / (fabs(tau) + sqrt(1.0 + tau * tau));
          double cc = 1.0 / sqrt(1.0 + tt * tt);
          c = (float)cc; sn = (float)(tt * cc);
        }
      }
      if (doit) {
#pragma unroll
        for (int i = 0; i < 36; ++i) {
          int r = h + 4 * i;
          B[r * 144 + p] = c * xp[i] - sn * xq[i];
          B[r * 144 + q] = sn * xp[i] + c * xq[i];
        }
      }
      __syncthreads();
    }
    int f = *flag;
    __syncthreads();
    if (!f) break;
  }
}

// column norms + top-`keep` selection (sel + S=sqrt(norm))
__device__ void colnorms_sel(const float* B, int R, int C, int keep, char* lp, int tid) {
  double* NORM = L_NORM(lp); int* SEL = L_SEL(lp); double* S = L_S(lp);
  for (int c = tid; c < C; c += NT) {
    double a = 0.0;
    for (int r = 0; r < R; ++r) { float v = B[r * C + c]; a += (double)v * (double)v; }
    NORM[c] = a;
  }
  __syncthreads();
  if (tid == 0) {
    for (int i = 0; i < keep; ++i) {
      int bi = 0; double bv = -1.0;
      for (int x = 0; x < C; ++x) if (NORM[x] > bv) { bv = NORM[x]; bi = x; }
      SEL[i] = bi;
      S[i] = sqrt(bv > 1e-300 ? bv : 1e-300);
      NORM[bi] = -2.0;
    }
  }
  __syncthreads();
}

// SVD of t (R x 36), keep 24: site = Vh24 (24x36), X = U24*S24 (R x 24)
__device__ void svdV36(const float* t, int R, double* site, double* X, char* lp, int tid) {
  float* B = L_B(lp); float* J = L_J(lp);
  for (int i = tid; i < R * 36; i += NT) B[i] = t[i];
  __syncthreads();
  jacobi36(B, R, J, L_FLAG(lp), tid);
  colnorms_sel(B, R, 36, 24, lp, tid);
  int* SEL = L_SEL(lp);
  for (int i = tid; i < 24 * 36; i += NT) {
    int c = i / 36, x = i - c * 36;
    site[i] = (double)J[x * 36 + SEL[c]];
  }
  for (int i = tid; i < R * 24; i += NT) {
    int k = i / 24, c = i - k * 24;
    X[i] = (double)B[k * 36 + SEL[c]];
  }
  __syncthreads();
}

// SVD of t (36 x 144), keep 24: site = Vh24 (24x144), X = U24*S24 (36 x 24)
__device__ void svdU36(const float* t, double* site, double* X, char* lp, int tid) {
  float* B = L_B(lp); float* J = L_J(lp);
  for (int i = tid; i < 144 * 36; i += NT) {
    int x = i / 36, k = i - x * 36;
    B[i] = t[k * 144 + x];          // B = t^T
  }
  __syncthreads();
  jacobi36(B, 144, J, L_FLAG(lp), tid);
  colnorms_sel(B, 144, 36, 24, lp, tid);
  int* SEL = L_SEL(lp); double* S = L_S(lp);
  for (int i = tid; i < 24 * 144; i += NT) {
    int c = i / 144, x = i - c * 144;
    site[i] = (double)B[x * 36 + SEL[c]] / S[c];
  }
  for (int i = tid; i < 36 * 24; i += NT) {
    int k = i / 24, c = i - k * 24;
    X[i] = (double)J[k * 36 + SEL[c]] * S[c];
  }
  __syncthreads();
}

// SVD of t (144 x 144), keep 24: X = U24*S24 (144x24), site = Vh24 = S^-2 X^T t (24x144)
__device__ void stepJ3big(const float* t, double* site, double* X, char* lp, int tid) {
  float* B = L_B(lp);
  for (int i = tid; i < 144 * 144; i += NT) B[i] = t[i];
  __syncthreads();
  jacobi144(B, L_FLAG(lp), tid);
  colnorms_sel(B, 144, 144, 24, lp, tid);
  int* SEL = L_SEL(lp); double* S = L_S(lp);
  for (int i = tid; i < 144 * 24; i += NT) {
    int k = i / 24, c = i - k * 24;
    X[i] = (double)B[k * 144 + SEL[c]];
  }
  __syncthreads();
  mm_tn<double,float,double>(X, 24, t, 144, site, 144, 24, 144, 144, tid);
  for (int i = tid; i < 24 * 144; i += NT) {
    int c = i / 144;
    site[i] /= (S[c] * S[c]);       // X^T t = S^2 Vh  ->  Vh
  }
  __syncthreads();
}

// LQ of t5 (36x6): t5 = X5 * Y, Y (6x6) orthonormal rows -> cand5, X5
__device__ void stepJ5(const double* t5, double* G, float* T, double* Qp,
                       double* cand5, double* X5, int tid) {
  mm_nt<double,double,double>(t5, 6, t5, 6, G, 6, 6, 6, 6, tid);   // Gram of t5 rows 0..5
  cholesky(G, 6, tid);
  trinv(G, 6, T, tid);
  mm_tn<double,float,double>(t5, 6, T, 6, Qp, 6, 6, 6, 6, tid);    // Q' (6x6) orthogonal
  for (int i = tid; i < 36; i += NT) {
    int l = i / 6, mu = i - l * 6;
    cand5[i] = Qp[mu * 6 + l];                                     // Y = Q'^T
  }
  __syncthreads();
  mm_nn<double,double,double>(t5, 6, Qp, 6, X5, 6, 36, 6, 6, tid); // X5 = t5 Q'
}

// LQ of t1 (6x144): t1 = X1 * Y1, Y1 orthonormal rows -> cand1, X1
__device__ void stepJ1(const double* t1, double* G, float* T,
                       double* cand1, double* X1, int tid) {
  mm_nt<double,double,double>(t1, 144, t1, 144, G, 6, 6, 6, 144, tid); // G = t1 t1^T
  cholesky(G, 6, tid);
  trinv(G, 6, T, tid);
  mm_tn<float,double,double>(T, 6, t1, 144, cand1, 144, 6, 144, 6, tid); // Y1 = T^T t1
  for (int i = tid; i < 36; i += NT) {
    int r = i / 6, c = i - r * 6;
    X1[i] = (c <= r) ? G[c * 6 + r] : 0.0;                             // X1 = R^T
  }
  __syncthreads();
}

__device__ void rescale0(double* cout_, char* lp, int tid) {
  if (tid == 0) {
    double m = 0.0;
    for (int i = 0; i < 36; ++i) { double v = fabs(cout_[i]); if (v > m) m = v; }
    if (!(m > 1e-300)) m = 1.0;
    *L_SCALE(lp) = m;
    *L_LOG(lp) += log(m);
  }
  __syncthreads();
  double m = *L_SCALE(lp);
  for (int i = tid; i < 36; i += NT) cout_[i] /= m;
  __syncthreads();
}

// ---------------- one _bmps round (truncating compress to DC=24) ----------------
__device__ void run_round(int r, int b, const int* cfg, const float* tens,
                          const double* cin_, double* cout_, int tid) {
  char* lp = ldsp();
  float*  F  = g_f32 + (size_t)b * F_STRIDE;
  double* Dd = g_f64 + (size_t)b * D_STRIDE;
  const int K  = (r == 1) ? 36 : 144;   // m2=m3=m4 = k2=k3
  const int cK = (r == 1) ? 6 : 24;
  int cb[7] = {1, 6, cK, cK, cK, 6, 1};
  int co[6]; co[0] = 0;
  for (int j = 0; j < 5; ++j) co[j + 1] = co[j] + cb[j] * 6 * cb[j + 1];
  const int ob[7] = {1, 6, 24, 24, 24, 6, 1};
  int oo[6]; oo[0] = 0;
  for (int j = 0; j < 5; ++j) oo[j + 1] = oo[j] + ob[j] * 6 * ob[j + 1];
  const int roff6[6] = {0, 216, 1512, 2808, 4104, 5400};

  float* ROW = F + OF_ROW;
  float* Dbuf = F + OF_D;  float* Abuf = F + OF_A;  float* A3 = F + OF_A3;
  float* Q2 = F + OF_Q2;   float* Q4 = F + OF_Q4;   float* Q1 = F + OF_Q1;  float* Q0 = F + OF_Q0;
  float* TB = F + OF_TB;   float* Rw = F + OF_R;    float* Tw = F + OF_T;   float* T3 = F + OF_T3;
  double* G = Dd + OD_G;   double* X = Dd + OD_X;   double* Z = Dd + OD_Z;
  double* t5 = Dd + OD_T5; double* X5 = Dd + OD_X5; double* Qp = Dd + OD_QP;
  double* X1 = Dd + OD_X1; double* t1 = Dd + OD_T1;

  gather_row(cfg, tens, b, r, 6, ROW, roff6, tid);

  // ---- QR sweep (left-canonicalize) ----
  // j=0 : A0 = D0 (6 x 36), wide
  build_D(cin_ + co[0], 1, cb[1], ROW + roff6[0], 1, 6, Dbuf, tid);
  wideQR(Dbuf, 6, 36, Q0, Rw, G, Tw, tid);
  // j=1 : A1 (36 x K)
  build_D(cin_ + co[1], 6, cb[2], ROW + roff6[1], 6, 6, Dbuf, tid);
  mm_nn<float,float,float>(Rw, 36, Dbuf, 6 * K, Abuf, 6 * K, 6, 6 * K, 36, tid);
  if (K == 36) tallQR(Abuf, 36, 36, Q1, Rw, G, Tw, tid);
  else         wideQR(Abuf, 36, 144, Q1, Rw, G, Tw, tid);
  // j=2 : A2 (216 x K)
  build_D(cin_ + co[2], cb[2], cb[3], ROW + roff6[2], 6, 6, Dbuf, tid);
  mm_nn<float,float,float>(Rw, K, Dbuf, 6 * K, Abuf, 6 * K, 36, 6 * K, K, tid);
  tallQR(Abuf, 216, K, Q2, Rw, G, Tw, tid);
  // j=3 : A3 (6K x K), keep A3 + T3 (skip forming Q3)
  build_D(cin_ + co[3], cb[3], cb[4], ROW + roff6[3], 6, 6, Dbuf, tid);
  mm_nn<float,float,float>(Rw, K, Dbuf, 6 * K, A3, 6 * K, K, 6 * K, K, tid);
  tallQR(A3, 6 * K, K, nullptr, Rw, G, T3, tid);
  // j=4 : A4 (6K x 36)
  build_D(cin_ + co[4], cb[4], cb[5], ROW + roff6[4], 6, 6, Dbuf, tid);
  mm_nn<float,float,float>(Rw, K, Dbuf, 216, Abuf, 216, K, 216, K, tid);
  tallQR(Abuf, 6 * K, 36, Q4, Rw, G, Tw, tid);
  // j=5 : t5 = R4 * D5  (36 x 6)
  build_D(cin_ + co[5], cb[5], 1, ROW + roff6[5], 6, 1, Dbuf, tid);
  mm_nn<float,float,double>(Rw, 36, Dbuf, 6, t5, 6, 36, 6, 36, tid);

  // ---- SVD sweep (right-to-left, truncate at j=4,3,2) ----
  stepJ5(t5, G, Tw, Qp, cout_ + oo[5], X5, tid);
  mm_nn<float,double,float>(Q4, 36, X5, 6, TB, 6, 6 * K, 6, 36, tid);      // t4 (K x 36)
  svdV36(TB, K, cout_ + oo[4], X, lp, tid);                                // X (K x 24)
  mm_nn<float,double,double>(T3, K, X, 24, Z, 24, K, 24, K, tid);          // Z = T3 X4
  mm_nn<float,double,float>(A3, K, Z, 24, TB, 24, 6 * K, 24, K, tid);      // t3 (K x 144)
  if (K == 144) stepJ3big(TB, cout_ + oo[3], X, lp, tid);
  else          svdU36(TB, cout_ + oo[3], X, lp, tid);                     // X (K x 24)
  mm_nn<float,double,float>(Q2, K, X, 24, TB, 24, 216, 24, K, tid);        // t2 (36 x 144)
  svdU36(TB, cout_ + oo[2], X, lp, tid);                                   // X (36 x 24)
  mm_nn<float,double,double>(Q1, 36, X, 24, t1, 24, 36, 24, 36, tid);      // t1 (6 x 144)
  stepJ1(t1, G, Tw, cout_ + oo[1], X1, tid);
  mm_nn<float,double,double>(Q0, 6, X1, 6, cout_ + oo[0], 6, 6, 6, 6, tid);// site0 (1,6,6)
  rescale0(cout_, lp, tid);
}

// ---------------- kernel ----------------
extern "C" __global__ void __launch_bounds__(NT)
peps_kernel(const int* __restrict__ cfg, const float* __restrict__ tens, float* __restrict__ out) {
  const int b = blockIdx.x;
  const int tid = threadIdx.x;
  char* lp = ldsp();
  double* CA = g_f64 + (size_t)b * D_STRIDE + OD_CA;
  double* CB = g_f64 + (size_t)b * D_STRIDE + OD_CB;
  if (tid == 0) *L_LOG(lp) = 0.0;

  // init cand = row 0 (bonds 1,6,6,6,6,6,1 ; u=1, m=down)
  {
    const int c1off[6] = {0, 36, 252, 468, 684, 900};
    for (int j = 0; j < 6; ++j) {
      int al = (j == 0) ? 1 : 6, ar = (j == 5) ? 1 : 6;
      const float* base = tens + (size_t)((j * 2 + cfg[b * 36 + j])) * 1296;
      int n = al * 6 * ar;
      double* dst = CA + c1off[j];
      for (int idx = tid; idx < n; idx += NT) {
        int l = idx / (6 * ar); int rest = idx - l * (6 * ar);
        int mu = rest / ar; int rr = rest - mu * ar;
        dst[idx] = (double)base[l * 216 + mu * 6 + rr];   // up index = 0
      }
    }
    __syncthreads();
  }

  run_round(1, b, cfg, tens, CA, CB, tid);
  run_round(2, b, cfg, tens, CB, CA, tid);
  run_round(3, b, cfg, tens, CA, CB, tid);
  run_round(4, b, cfg, tens, CB, CA, tid);

  // final exact contraction of cand (in CA) with row 5 (down dim = 1)
  {
    const int roff1[6] = {0, 36, 252, 468, 684, 900};
    float* ROW = g_f32 + (size_t)b * F_STRIDE + OF_ROW;
    gather_row(cfg, tens, b, 5, 1, ROW, roff1, tid);
    double* E = L_E(lp); double* E2 = L_E2(lp);
    if (tid == 0) E[0] = 1.0;
    __syncthreads();
    const int ob[7] = {1, 6, 24, 24, 24, 6, 1};
    int oo[6]; oo[0] = 0;
    for (int j = 0; j < 5; ++j) oo[j + 1] = oo[j] + ob[j] * 6 * ob[j + 1];
    const double* candF = CA;
    double* src = E; double* dst = E2;
    for (int j = 0; j < 6; ++j) {
      int cl = ob[j], cr = ob[j + 1];
      int al = (j == 0) ? 1 : 6, ar = (j == 5) ? 1 : 6;
      int n = cr * ar;
      for (int idx = tid; idx < n; idx += NT) {
        int rr = idx / ar, R_ = idx - rr * ar;
        double acc = 0.0;
        for (int l = 0; l < cl; ++l) {
          for (int L = 0; L < al; ++L) {
            double e = src[l * al + L];
            double s2 = 0.0;
#pragma unroll
            for (int mu = 0; mu < 6; ++mu)
              s2 += candF[oo[j] + (l * 6 + mu) * cr + rr] * (double)ROW[roff1[j] + (L * 6 + mu) * ar + R_];
            acc += e * s2;
          }
        }
        dst[idx] = acc;
      }
      __syncthreads();
      double* tmp = src; src = dst; dst = tmp;
    }
    if (tid == 0) out[b] = (float)(src[0] * exp(*L_LOG(lp)));
  }
}

// ---------------- launch ----------------
extern "C" void kernel_launch(void* const* d_in, const int* in_sizes, int n_in,
                              void* d_out, int out_size, void* d_ws, size_t ws_size,
                              hipStream_t stream) {
  (void)in_sizes; (void)n_in; (void)out_size; (void)d_ws; (void)ws_size;
  const int* cfg = (const int*)d_in[0];
  const float* tens = (const float*)d_in[1];
  float* out = (float*)d_out;
  // opt-in to >64KB dynamic LDS (ignore error; gfx950 supports up to 160KB)
  (void)hipFuncSetAttribute((const void*)peps_kernel,
                            hipFuncAttributeMaxDynamicSharedMemorySize, LDS_BYTES);
  peps_kernel<<<dim3(NB), dim3(NT), LDS_BYTES, stream>>>(cfg, tens, out);
}

// Round 7
// 48917.041 us; speedup vs baseline: 1.3196x; 1.3196x over previous
//
#include <hip/hip_runtime.h>
#include <math.h>

#define NT 512
#define NB 32

// ---------------- unified fp64 arena (per-batch, element offsets) ----------------
#define M_D    0        // 124416 : double-tensor D_j (max 144 x 864)
#define M_A    124416   // 124416 : A1/A2/A4
#define M_A3   248832   // 124416 : A3 (kept through round)
#define M_Q2   373248   // 31104  : Q2 (216 x K)
#define M_Q4   404352   // 31104  : Q4 (6K x 36)
#define M_TB   435456   // 20736  : t-matrix buffer (max 144x144)
#define M_Q1   456192   // 1296
#define M_Q0   457488   // 64
#define M_ROW  457552   // 5616   : gathered row tensors
#define M_R    463168   // 20736  : current R (dense)
#define M_T    483904   // 20736  : current T = R^-1 (also T24 in refine)
#define M_T3   504640   // 20736  : T3 kept
#define M_G    525392   // 20736  : Gram / chol workspace
#define M_CA   546128   // 8712   : cand buffer A
#define M_CB   554840   // 8712   : cand buffer B
#define M_X    563552   // 3456   : push factor X (max 144x24)
#define M_Z    567008   // 3456   : Z = T3*X4
#define M_T5   570464   // 216
#define M_X5   570680   // 216
#define M_QP   570896   // 64
#define M_X1   570960   // 64
#define M_T1   571024   // 864
#define M_Y0   571888   // 3456   : refine: approx subspace basis (My x 24)
#define M_YH   575344   // 3456   : refine: orthonormal basis
#define M_W    578800   // 576    : refine: sorted right-rotation
#define M_P    579376   // 3456   : refine: YH * W
#define M_STRIDE 582832

__device__ __align__(16) double g_m[(size_t)NB * M_STRIDE];

// ---------------- LDS layout (byte offsets) ----------------
// phase A (f32 Jacobi): B f32 [0, 82944), J f32 [82944, 88128)
// phase B (fp64 refine): Zr fp64 [0, 27648), J24 fp64 [27648, 32256)  (B/J dead)
#define LO_J     82944
#define LO_NORM  88128   // double[144]
#define LO_S     89280   // double[24]
#define LO_E     89472   // double[144]
#define LO_E2    90624   // double[144]
#define LO_SEL   91776   // int[24]
#define LO_FLAG  91872   // int
#define LO_LOG   91880   // double
#define LO_SCALE 91888   // double
#define LDS_BYTES 92160

__device__ __forceinline__ char* ldsp() {
  extern __shared__ char lds_pool[];
  return lds_pool;
}
#define L_B(p)     ((float*)(p))
#define L_J(p)     ((float*)((p)+LO_J))
#define L_ZR(p)    ((double*)(p))
#define L_J24(p)   ((double*)((p)+27648))
#define L_NORM(p)  ((double*)((p)+LO_NORM))
#define L_S(p)     ((double*)((p)+LO_S))
#define L_E(p)     ((double*)((p)+LO_E))
#define L_E2(p)    ((double*)((p)+LO_E2))
#define L_SEL(p)   ((int*)((p)+LO_SEL))
#define L_FLAG(p)  ((int*)((p)+LO_FLAG))
#define L_LOG(p)   ((double*)((p)+LO_LOG))
#define L_SCALE(p) ((double*)((p)+LO_SCALE))

// ---------------- fp64 matmuls (4-wide strip when N%4==0) ----------------
__device__ void mm_nn(const double* __restrict__ A, int lda, const double* __restrict__ Bm, int ldb,
                      double* __restrict__ C, int ldc, int M, int N, int Kd, int tid) {
  if ((N & 3) == 0) {
    int nstrip = N >> 2;
    for (int u = tid; u < M * nstrip; u += NT) {
      int i = u / nstrip, j0 = (u - i * nstrip) << 2;
      const double* a = A + (size_t)i * lda;
      const double* b = Bm + j0;
      double d0 = 0, d1 = 0, d2 = 0, d3 = 0;
      for (int k = 0; k < Kd; ++k) {
        double av = a[k];
        const double* br = b + (size_t)k * ldb;
        d0 += av * br[0]; d1 += av * br[1]; d2 += av * br[2]; d3 += av * br[3];
      }
      size_t o = (size_t)i * ldc + j0;
      C[o] = d0; C[o + 1] = d1; C[o + 2] = d2; C[o + 3] = d3;
    }
  } else {
    for (int idx = tid; idx < M * N; idx += NT) {
      int i = idx / N, j = idx - i * N;
      const double* a = A + (size_t)i * lda;
      double acc = 0.0;
      for (int k = 0; k < Kd; ++k) acc += a[k] * Bm[(size_t)k * ldb + j];
      C[(size_t)i * ldc + j] = acc;
    }
  }
  __syncthreads();
}

__device__ void mm_tn(const double* __restrict__ A, int lda, const double* __restrict__ Bm, int ldb,
                      double* __restrict__ C, int ldc, int M, int N, int Kd, int tid) {
  if ((N & 3) == 0) {
    int nstrip = N >> 2;
    for (int u = tid; u < M * nstrip; u += NT) {
      int i = u / nstrip, j0 = (u - i * nstrip) << 2;
      double d0 = 0, d1 = 0, d2 = 0, d3 = 0;
      for (int k = 0; k < Kd; ++k) {
        double av = A[(size_t)k * lda + i];
        const double* br = Bm + (size_t)k * ldb + j0;
        d0 += av * br[0]; d1 += av * br[1]; d2 += av * br[2]; d3 += av * br[3];
      }
      size_t o = (size_t)i * ldc + j0;
      C[o] = d0; C[o + 1] = d1; C[o + 2] = d2; C[o + 3] = d3;
    }
  } else {
    for (int idx = tid; idx < M * N; idx += NT) {
      int i = idx / N, j = idx - i * N;
      double acc = 0.0;
      for (int k = 0; k < Kd; ++k) acc += A[(size_t)k * lda + i] * Bm[(size_t)k * ldb + j];
      C[(size_t)i * ldc + j] = acc;
    }
  }
  __syncthreads();
}

__device__ void mm_nt(const double* __restrict__ A, int lda, const double* __restrict__ Bm, int ldb,
                      double* __restrict__ C, int ldc, int M, int N, int Kd, int tid) {
  for (int idx = tid; idx < M * N; idx += NT) {
    int i = idx / N, j = idx - i * N;
    double acc = 0.0;
    for (int k = 0; k < Kd; ++k) acc += A[(size_t)i * lda + k] * Bm[(size_t)j * ldb + k];
    C[(size_t)i * ldc + j] = acc;
  }
  __syncthreads();
}

// ---------------- Cholesky (fp64, in-place upper R, G = R^T R) ----------------
__device__ void cholesky(double* G, int n, int tid) {
  for (int j = 0; j < n; ++j) {
    __syncthreads();
    double piv = G[(size_t)j * n + j];
    double r = sqrt(piv > 1e-300 ? piv : 1e-300);
    double inv = 1.0 / r;
    __syncthreads();
    for (int i = j + tid; i < n; i += NT)
      G[(size_t)j * n + i] = (i == j) ? r : G[(size_t)j * n + i] * inv;
    __syncthreads();
    int w = n - j - 1;
    for (int idx = tid; idx < w * w; idx += NT) {
      int ii = idx / w, kk = idx - ii * w;
      int i = j + 1 + ii, k2 = j + 1 + kk;
      if (k2 >= i) G[(size_t)i * n + k2] -= G[(size_t)j * n + i] * G[(size_t)j * n + k2];
    }
  }
  __syncthreads();
}

// T = R^{-1} (upper), fp64 dense (lower zeroed)
__device__ void trinv(const double* G, int n, double* T, int tid) {
  for (int c = tid; c < n; c += NT) {
    T[(size_t)c * n + c] = 1.0 / G[(size_t)c * n + c];
    for (int r = c - 1; r >= 0; --r) {
      double s = 0.0;
      for (int k = r + 1; k <= c; ++k) s += G[(size_t)r * n + k] * T[(size_t)k * n + c];
      T[(size_t)r * n + c] = -s / G[(size_t)r * n + r];
    }
    for (int r = c + 1; r < n; ++r) T[(size_t)r * n + c] = 0.0;
  }
  __syncthreads();
}

__device__ void copyR(const double* G, int n, double* Rw, int tid) {
  for (int idx = tid; idx < n * n; idx += NT) {
    int i = idx / n, k = idx - i * n;
    Rw[idx] = (k >= i) ? G[idx] : 0.0;
  }
  __syncthreads();
}

// tall CholQR: A (Mr x Nc), Mr >= Nc
__device__ void tallQR(const double* A, int Mr, int Nc, double* Q, double* Rw,
                       double* G, double* T, int tid) {
  mm_tn(A, Nc, A, Nc, G, Nc, Nc, Nc, Mr, tid);
  cholesky(G, Nc, tid);
  trinv(G, Nc, T, tid);
  if (Q)  mm_nn(A, Nc, T, Nc, Q, Nc, Mr, Nc, Nc, tid);
  if (Rw) copyR(G, Nc, Rw, tid);
}

// wide QR (Mr < Nc): QR of first Mr cols, Rw = Q^T A (Mr x Nc)
__device__ void wideQR(const double* A, int Mr, int Nc, double* Q, double* Rw,
                       double* G, double* T, int tid) {
  mm_tn(A, Nc, A, Nc, G, Mr, Mr, Mr, Mr, tid);
  cholesky(G, Mr, tid);
  trinv(G, Mr, T, tid);
  mm_nn(A, Nc, T, Mr, Q, Mr, Mr, Mr, Mr, tid);
  mm_tn(Q, Mr, A, Nc, Rw, Nc, Mr, Nc, Mr, tid);
}

// ---------------- double-tensor build (fp64) ----------------
__device__ void build_D(const double* __restrict__ cand, int cl, int cr,
                        const double* __restrict__ rowS, int al, int ar,
                        double* __restrict__ D, int tid) {
  int mnext = cr * ar;
  int ncols = 6 * mnext;
  int n = cl * al * ncols;
  for (int idx = tid; idx < n; idx += NT) {
    int row = idx / ncols, col = idx - row * ncols;
    int l = row / al, L = row - l * al;
    int d = col / mnext, rem = col - d * mnext;
    int rr = rem / ar, R_ = rem - rr * ar;
    double acc = 0.0;
#pragma unroll
    for (int mu = 0; mu < 6; ++mu)
      acc += cand[(l * 6 + mu) * cr + rr] * rowS[((L * 6 + mu) * 6 + d) * ar + R_];
    D[idx] = acc;
  }
  __syncthreads();
}

// gather a physical row r into ROW buffer (fp64); dd = down-dim
__device__ void gather_row(const int* cfg, const float* tens, int b, int r, int dd,
                           double* ROW, const int* roff, int tid) {
  for (int j = 0; j < 6; ++j) {
    int al = (j == 0) ? 1 : 6, ar = (j == 5) ? 1 : 6;
    const float* base = tens + (size_t)(((r * 6 + j) * 2 + cfg[b * 36 + r * 6 + j])) * 1296;
    int n = al * 6 * dd * ar;
    double* dst = ROW + roff[j];
    for (int idx = tid; idx < n; idx += NT) {
      int R_ = idx % ar; int t2 = idx / ar;
      int d = t2 % dd; t2 /= dd;
      int mu = t2 % 6; int L = t2 / 6;
      dst[idx] = (double)base[L * 216 + mu * 36 + d * 6 + R_];
    }
  }
  __syncthreads();
}

// ---------------- f32 one-sided Jacobi (coarse subspace finder) ----------------
__device__ void jacobi36(float* B, int R, float* J, int* flag, int tid) {
  for (int i = tid; i < 36 * 36; i += NT) J[i] = ((i / 36) == (i % 36)) ? 1.f : 0.f;
  __syncthreads();
  for (int sw = 0; sw < 9; ++sw) {
    if (tid == 0) *flag = 0;
    __syncthreads();
    for (int t = 0; t < 35; ++t) {
      int s = tid >> 3, h = tid & 7;
      bool act = (tid < 144);
      int p = 0, q = 0; float c = 1.f, sn = 0.f; bool doit = false;
      if (act) {
        if (s == 0) { p = 35; q = t % 35; }
        else { p = (t + s) % 35; q = (t - s + 35) % 35; }
        float app = 0.f, aqq = 0.f, apq = 0.f;
        for (int r = h; r < R; r += 8) {
          float x = B[r * 36 + p], y = B[r * 36 + q];
          app += x * x; aqq += y * y; apq += x * y;
        }
        app += __shfl_xor(app, 1); aqq += __shfl_xor(aqq, 1); apq += __shfl_xor(apq, 1);
        app += __shfl_xor(app, 2); aqq += __shfl_xor(aqq, 2); apq += __shfl_xor(apq, 2);
        app += __shfl_xor(app, 4); aqq += __shfl_xor(aqq, 4); apq += __shfl_xor(apq, 4);
        double g = (double)apq, aa = (double)app, bb = (double)aqq;
        if (g * g > 1e-14 * aa * bb) {
          doit = true;
          if (h == 0) *flag = 1;
          double tau = (bb - aa) / (2.0 * g);
          double tt = (tau >= 0.0 ? 1.0 : -1.0) / (fabs(tau) + sqrt(1.0 + tau * tau));
          double cc = 1.0 / sqrt(1.0 + tt * tt);
          c = (float)cc; sn = (float)(tt * cc);
        }
      }
      if (doit) {
        for (int r = h; r < R; r += 8) {
          float x = B[r * 36 + p], y = B[r * 36 + q];
          B[r * 36 + p] = c * x - sn * y;
          B[r * 36 + q] = sn * x + c * y;
        }
        for (int r = h; r < 36; r += 8) {
          float x = J[r * 36 + p], y = J[r * 36 + q];
          J[r * 36 + p] = c * x - sn * y;
          J[r * 36 + q] = sn * x + c * y;
        }
      }
      __syncthreads();
    }
    int f = *flag;
    __syncthreads();
    if (!f) break;
  }
}

__device__ void jacobi144(float* B, int* flag, int tid) {
  for (int sw = 0; sw < 9; ++sw) {
    if (tid == 0) *flag = 0;
    __syncthreads();
    for (int t = 0; t < 143; ++t) {
      int s = tid >> 2, h = tid & 3;
      bool act = (tid < 288);
      float xp[36], xq[36];
      int p = 0, q = 0; float c = 1.f, sn = 0.f; bool doit = false;
      if (act) {
        if (s == 0) { p = 143; q = t % 143; }
        else { p = (t + s) % 143; q = (t - s + 143) % 143; }
        float app = 0.f, aqq = 0.f, apq = 0.f;
#pragma unroll
        for (int i = 0; i < 36; ++i) {
          int r = h + 4 * i;
          float x = B[r * 144 + p], y = B[r * 144 + q];
          xp[i] = x; xq[i] = y;
          app += x * x; aqq += y * y; apq += x * y;
        }
        app += __shfl_xor(app, 1); aqq += __shfl_xor(aqq, 1); apq += __shfl_xor(apq, 1);
        app += __shfl_xor(app, 2); aqq += __shfl_xor(aqq, 2); apq += __shfl_xor(apq, 2);
        double g = (double)apq, aa = (double)app, bb = (double)aqq;
        if (g * g > 1e-14 * aa * bb) {
          doit = true;
          if (h == 0) *flag = 1;
          double tau = (bb - aa) / (2.0 * g);
          double tt = (tau >= 0.0 ? 1.0 : -1.0) / (fabs(tau) + sqrt(1.0 + tau * tau));
          double cc = 1.0 / sqrt(1.0 + tt * tt);
          c = (float)cc; sn = (float)(tt * cc);
        }
      }
      if (doit) {
#pragma unroll
        for (int i = 0; i < 36; ++i) {
          int r = h + 4 * i;
          B[r * 144 + p] = c * xp[i] - sn * xq[i];
          B[r * 144 + q] = sn * xp[i] + c * xq[i];
        }
      }
      __syncthreads();
    }
    int f = *flag;
    __syncthreads();
    if (!f) break;
  }
}

// column norms (f32 B) + top-`keep` selection
__device__ void colnorms_sel(const float* B, int R, int C, int keep, char* lp, int tid) {
  double* NORM = L_NORM(lp); int* SEL = L_SEL(lp); double* S = L_S(lp);
  for (int c = tid; c < C; c += NT) {
    double a = 0.0;
    for (int r = 0; r < R; ++r) { float v = B[r * C + c]; a += (double)v * (double)v; }
    NORM[c] = a;
  }
  __syncthreads();
  if (tid == 0) {
    for (int i = 0; i < keep; ++i) {
      int bi = 0; double bv = -1.0;
      for (int x = 0; x < C; ++x) if (NORM[x] > bv) { bv = NORM[x]; bi = x; }
      SEL[i] = bi;
      S[i] = sqrt(bv > 1e-300 ? bv : 1e-300);
      NORM[bi] = -2.0;
    }
  }
  __syncthreads();
}

// ---------------- fp64 refinement ----------------
// one-sided fp64 Jacobi on Z (R x 24, LDS), with J24 (24x24) accumulation
__device__ void jacobi24d(double* Z, int R, double* J24, int* flag, int tid) {
  for (int i = tid; i < 576; i += NT) J24[i] = ((i / 24) == (i % 24)) ? 1.0 : 0.0;
  __syncthreads();
  for (int sw = 0; sw < 16; ++sw) {
    if (tid == 0) *flag = 0;
    __syncthreads();
    for (int t = 0; t < 23; ++t) {
      int s = tid >> 3, h = tid & 7;
      bool act = (tid < 96);
      int p = 0, q = 0; double c_ = 1.0, sn = 0.0; bool doit = false;
      if (act) {
        if (s == 0) { p = 23; q = t % 23; }
        else { p = (t + s) % 23; q = (t - s + 23) % 23; }
        double app = 0, aqq = 0, apq = 0;
        for (int r = h; r < R; r += 8) {
          double x = Z[r * 24 + p], y = Z[r * 24 + q];
          app += x * x; aqq += y * y; apq += x * y;
        }
        app += __shfl_xor(app, 1); aqq += __shfl_xor(aqq, 1); apq += __shfl_xor(apq, 1);
        app += __shfl_xor(app, 2); aqq += __shfl_xor(aqq, 2); apq += __shfl_xor(apq, 2);
        app += __shfl_xor(app, 4); aqq += __shfl_xor(aqq, 4); apq += __shfl_xor(apq, 4);
        if (apq * apq > 1e-28 * app * aqq) {
          doit = true;
          if (h == 0) *flag = 1;
          double tau = (aqq - app) / (2.0 * apq);
          double tt = (tau >= 0.0 ? 1.0 : -1.0) / (fabs(tau) + sqrt(1.0 + tau * tau));
          double cc = 1.0 / sqrt(1.0 + tt * tt);
          c_ = cc; sn = tt * cc;
        }
      }
      if (doit) {
        for (int r = h; r < R; r += 8) {
          double x = Z[r * 24 + p], y = Z[r * 24 + q];
          Z[r * 24 + p] = c_ * x - sn * y;
          Z[r * 24 + q] = sn * x + c_ * y;
        }
        for (int r = h; r < 24; r += 8) {
          double x = J24[r * 24 + p], y = J24[r * 24 + q];
          J24[r * 24 + p] = c_ * x - sn * y;
          J24[r * 24 + q] = sn * x + c_ * y;
        }
      }
      __syncthreads();
    }
    int f = *flag;
    __syncthreads();
    if (!f) break;
  }
}

// col norms of Z (R x 24) -> SEL order desc, S = sqrt
__device__ void sort24(const double* Z, int R, char* lp, int tid) {
  double* NORM = L_NORM(lp); int* SEL = L_SEL(lp); double* S = L_S(lp);
  for (int c = tid; c < 24; c += NT) {
    double a = 0.0;
    for (int r = 0; r < R; ++r) { double v = Z[r * 24 + c]; a += v * v; }
    NORM[c] = a;
  }
  __syncthreads();
  if (tid == 0) {
    for (int i = 0; i < 24; ++i) {
      int bi = 0; double bv = -1.0;
      for (int x = 0; x < 24; ++x) if (NORM[x] > bv) { bv = NORM[x]; bi = x; }
      SEL[i] = bi;
      S[i] = sqrt(bv > 1e-300 ? bv : 1e-300);
      NORM[bi] = -2.0;
    }
  }
  __syncthreads();
}

// Rayleigh-Ritz refinement. Y0 (global, My x 24) spans approx subspace.
// ucase=0 (right-side / svdV36): t (tR x tC=36=My): Z = t*YH (tR x 24);
//   site (24 x My) = (YH*W)^T ; X (tR x 24) = Z_rot[:,ord].
// ucase=1 (left-side / svdU36, stepJ3big): t (tR=My x tC): Z = t^T*YH (tC x 24);
//   X (My x 24) = (YH*W)*S ; site (24 x tC) = Z_rot[:,ord]^T / S.
__device__ void refine(const double* t, int tR, int tC, int My, int ucase,
                       double* site, double* X, double* Dd, char* lp, int tid) {
  double* G = Dd + M_G;   double* T24 = Dd + M_T;
  double* Y0 = Dd + M_Y0; double* YH = Dd + M_YH;
  double* W = Dd + M_W;   double* P = Dd + M_P;
  double* Zr = L_ZR(lp);  double* J24 = L_J24(lp);
  int Rz = ucase ? tC : tR;
  // orthonormalize Y0 -> YH
  mm_tn(Y0, 24, Y0, 24, G, 24, 24, 24, My, tid);
  cholesky(G, 24, tid);
  trinv(G, 24, T24, tid);
  mm_nn(Y0, 24, T24, 24, YH, 24, My, 24, 24, tid);
  // Z (into LDS)
  if (ucase) mm_tn(t, tC, YH, 24, Zr, 24, tC, 24, tR, tid);
  else       mm_nn(t, tC, YH, 24, Zr, 24, tR, 24, tC, tid);
  jacobi24d(Zr, Rz, J24, L_FLAG(lp), tid);
  sort24(Zr, Rz, lp, tid);
  int* SEL = L_SEL(lp); double* S = L_S(lp);
  // W = J24[:, ord]
  for (int i = tid; i < 576; i += NT) {
    int k = i / 24, c = i - k * 24;
    W[i] = J24[k * 24 + SEL[c]];
  }
  __syncthreads();
  mm_nn(YH, 24, W, 24, P, 24, My, 24, 24, tid);
  if (ucase) {
    for (int i = tid; i < My * 24; i += NT) {
      int k = i / 24, c = i - k * 24;
      X[i] = P[i] * S[c];
    }
    for (int i = tid; i < 24 * tC; i += NT) {
      int c = i / tC, x = i - c * tC;
      site[i] = Zr[x * 24 + SEL[c]] / S[c];
    }
  } else {
    for (int i = tid; i < 24 * My; i += NT) {
      int c = i / My, x = i - c * My;
      site[i] = P[x * 24 + c];
    }
    for (int i = tid; i < Rz * 24; i += NT) {
      int k = i / 24, c = i - k * 24;
      X[i] = Zr[k * 24 + SEL[c]];
    }
  }
  __syncthreads();
}

// SVD of t (R x 36), keep 24: site = Vh24 (24x36), X = U24*S24 (R x 24)
__device__ void svdV36d(const double* t, int R, double* site, double* X,
                        double* Dd, char* lp, int tid) {
  float* B = L_B(lp); float* J = L_J(lp);
  for (int i = tid; i < R * 36; i += NT) B[i] = (float)t[i];
  __syncthreads();
  jacobi36(B, R, J, L_FLAG(lp), tid);
  colnorms_sel(B, R, 36, 24, lp, tid);
  int* SEL = L_SEL(lp);
  double* Y0 = Dd + M_Y0;
  for (int i = tid; i < 36 * 24; i += NT) {
    int x = i / 24, c = i - x * 24;
    Y0[i] = (double)J[x * 36 + SEL[c]];        // approx V24 (36 x 24)
  }
  __syncthreads();
  refine(t, R, 36, 36, 0, site, X, Dd, lp, tid);
}

// SVD of t (36 x 144), keep 24: site = Vh24 (24x144), X = U24*S24 (36 x 24)
__device__ void svdU36d(const double* t, double* site, double* X,
                        double* Dd, char* lp, int tid) {
  float* B = L_B(lp); float* J = L_J(lp);
  for (int i = tid; i < 144 * 36; i += NT) {
    int x = i / 36, k = i - x * 36;
    B[i] = (float)t[k * 144 + x];              // B = t^T
  }
  __syncthreads();
  jacobi36(B, 144, J, L_FLAG(lp), tid);
  colnorms_sel(B, 144, 36, 24, lp, tid);
  int* SEL = L_SEL(lp);
  double* Y0 = Dd + M_Y0;
  for (int i = tid; i < 36 * 24; i += NT) {
    int x = i / 24, c = i - x * 24;
    Y0[i] = (double)J[x * 36 + SEL[c]];        // approx U24 (36 x 24)
  }
  __syncthreads();
  refine(t, 36, 144, 36, 1, site, X, Dd, lp, tid);
}

// SVD of t (144 x 144), keep 24
__device__ void stepJ3bigd(const double* t, double* site, double* X,
                           double* Dd, char* lp, int tid) {
  float* B = L_B(lp);
  for (int i = tid; i < 144 * 144; i += NT) B[i] = (float)t[i];
  __syncthreads();
  jacobi144(B, L_FLAG(lp), tid);
  colnorms_sel(B, 144, 144, 24, lp, tid);
  int* SEL = L_SEL(lp);
  double* Y0 = Dd + M_Y0;
  for (int i = tid; i < 144 * 24; i += NT) {
    int k = i / 24, c = i - k * 24;
    Y0[i] = (double)B[k * 144 + SEL[c]];       // approx U24*S (144 x 24)
  }
  __syncthreads();
  refine(t, 144, 144, 144, 1, site, X, Dd, lp, tid);
}

// LQ of t5 (36x6)
__device__ void stepJ5(const double* t5, double* G, double* T, double* Qp,
                       double* cand5, double* X5, int tid) {
  mm_nt(t5, 6, t5, 6, G, 6, 6, 6, 6, tid);
  cholesky(G, 6, tid);
  trinv(G, 6, T, tid);
  mm_tn(t5, 6, T, 6, Qp, 6, 6, 6, 6, tid);
  for (int i = tid; i < 36; i += NT) {
    int l = i / 6, mu = i - l * 6;
    cand5[i] = Qp[mu * 6 + l];
  }
  __syncthreads();
  mm_nn(t5, 6, Qp, 6, X5, 6, 36, 6, 6, tid);
}

// LQ of t1 (6x144)
__device__ void stepJ1(const double* t1, double* G, double* T,
                       double* cand1, double* X1, int tid) {
  mm_nt(t1, 144, t1, 144, G, 6, 6, 6, 144, tid);
  cholesky(G, 6, tid);
  trinv(G, 6, T, tid);
  mm_tn(T, 6, t1, 144, cand1, 144, 6, 144, 6, tid);
  for (int i = tid; i < 36; i += NT) {
    int r = i / 6, c = i - r * 6;
    X1[i] = (c <= r) ? G[c * 6 + r] : 0.0;
  }
  __syncthreads();
}

__device__ void rescale0(double* cout_, char* lp, int tid) {
  if (tid == 0) {
    double m = 0.0;
    for (int i = 0; i < 36; ++i) { double v = fabs(cout_[i]); if (v > m) m = v; }
    if (!(m > 1e-300)) m = 1.0;
    *L_SCALE(lp) = m;
    *L_LOG(lp) += log(m);
  }
  __syncthreads();
  double m = *L_SCALE(lp);
  for (int i = tid; i < 36; i += NT) cout_[i] /= m;
  __syncthreads();
}

// ---------------- one _bmps round (truncating compress to DC=24) ----------------
__device__ void run_round(int r, int b, const int* cfg, const float* tens,
                          const double* cin_, double* cout_, int tid) {
  char* lp = ldsp();
  double* Dd = g_m + (size_t)b * M_STRIDE;
  const int K  = (r == 1) ? 36 : 144;
  const int cK = (r == 1) ? 6 : 24;
  int cb[7] = {1, 6, cK, cK, cK, 6, 1};
  int co[6]; co[0] = 0;
  for (int j = 0; j < 5; ++j) co[j + 1] = co[j] + cb[j] * 6 * cb[j + 1];
  const int ob[7] = {1, 6, 24, 24, 24, 6, 1};
  int oo[6]; oo[0] = 0;
  for (int j = 0; j < 5; ++j) oo[j + 1] = oo[j] + ob[j] * 6 * ob[j + 1];
  const int roff6[6] = {0, 216, 1512, 2808, 4104, 5400};

  double* ROW = Dd + M_ROW;
  double* Dbuf = Dd + M_D;  double* Abuf = Dd + M_A;  double* A3 = Dd + M_A3;
  double* Q2 = Dd + M_Q2;   double* Q4 = Dd + M_Q4;   double* Q1 = Dd + M_Q1;  double* Q0 = Dd + M_Q0;
  double* TB = Dd + M_TB;   double* Rw = Dd + M_R;    double* Tw = Dd + M_T;   double* T3 = Dd + M_T3;
  double* G = Dd + M_G;     double* X = Dd + M_X;     double* Zp = Dd + M_Z;
  double* t5 = Dd + M_T5;   double* X5 = Dd + M_X5;   double* Qp = Dd + M_QP;
  double* X1 = Dd + M_X1;   double* t1 = Dd + M_T1;

  gather_row(cfg, tens, b, r, 6, ROW, roff6, tid);

  // ---- QR sweep (left-canonicalize) ----
  build_D(cin_ + co[0], 1, cb[1], ROW + roff6[0], 1, 6, Dbuf, tid);
  wideQR(Dbuf, 6, 36, Q0, Rw, G, Tw, tid);

  build_D(cin_ + co[1], 6, cb[2], ROW + roff6[1], 6, 6, Dbuf, tid);
  mm_nn(Rw, 36, Dbuf, 6 * K, Abuf, 6 * K, 6, 6 * K, 36, tid);
  if (K == 36) tallQR(Abuf, 36, 36, Q1, Rw, G, Tw, tid);
  else         wideQR(Abuf, 36, 144, Q1, Rw, G, Tw, tid);

  build_D(cin_ + co[2], cb[2], cb[3], ROW + roff6[2], 6, 6, Dbuf, tid);
  mm_nn(Rw, K, Dbuf, 6 * K, Abuf, 6 * K, 36, 6 * K, K, tid);
  tallQR(Abuf, 216, K, Q2, Rw, G, Tw, tid);

  build_D(cin_ + co[3], cb[3], cb[4], ROW + roff6[3], 6, 6, Dbuf, tid);
  mm_nn(Rw, K, Dbuf, 6 * K, A3, 6 * K, K, 6 * K, K, tid);
  tallQR(A3, 6 * K, K, nullptr, Rw, G, T3, tid);

  build_D(cin_ + co[4], cb[4], cb[5], ROW + roff6[4], 6, 6, Dbuf, tid);
  mm_nn(Rw, K, Dbuf, 216, Abuf, 216, K, 216, K, tid);
  tallQR(Abuf, 6 * K, 36, Q4, Rw, G, Tw, tid);

  build_D(cin_ + co[5], cb[5], 1, ROW + roff6[5], 6, 1, Dbuf, tid);
  mm_nn(Rw, 36, Dbuf, 6, t5, 6, 36, 6, 36, tid);

  // ---- SVD sweep (right-to-left, truncate at j=4,3,2) ----
  stepJ5(t5, G, Tw, Qp, cout_ + oo[5], X5, tid);
  mm_nn(Q4, 36, X5, 6, TB, 6, 6 * K, 6, 36, tid);                 // t4 (K x 36)
  svdV36d(TB, K, cout_ + oo[4], X, Dd, lp, tid);                  // X (K x 24)
  mm_nn(T3, K, X, 24, Zp, 24, K, 24, K, tid);                     // Z = T3 X4
  mm_nn(A3, K, Zp, 24, TB, 24, 6 * K, 24, K, tid);                // t3 (K x 144)
  if (K == 144) stepJ3bigd(TB, cout_ + oo[3], X, Dd, lp, tid);
  else          svdU36d(TB, cout_ + oo[3], X, Dd, lp, tid);       // X (K x 24)
  mm_nn(Q2, K, X, 24, TB, 24, 216, 24, K, tid);                   // t2 (36 x 144)
  svdU36d(TB, cout_ + oo[2], X, Dd, lp, tid);                     // X (36 x 24)
  mm_nn(Q1, 36, X, 24, t1, 24, 36, 24, 36, tid);                  // t1 (6 x 144)
  stepJ1(t1, G, Tw, cout_ + oo[1], X1, tid);
  mm_nn(Q0, 6, X1, 6, cout_ + oo[0], 6, 6, 6, 6, tid);            // site0
  rescale0(cout_, lp, tid);
}

// ---------------- kernel ----------------
extern "C" __global__ void __launch_bounds__(NT)
peps_kernel(const int* __restrict__ cfg, const float* __restrict__ tens, float* __restrict__ out) {
  const int b = blockIdx.x;
  const int tid = threadIdx.x;
  char* lp = ldsp();
  double* CA = g_m + (size_t)b * M_STRIDE + M_CA;
  double* CB = g_m + (size_t)b * M_STRIDE + M_CB;
  if (tid == 0) *L_LOG(lp) = 0.0;

  // init cand = row 0 (bonds 1,6,6,6,6,6,1 ; up=0)
  {
    const int c1off[6] = {0, 36, 252, 468, 684, 900};
    for (int j = 0; j < 6; ++j) {
      int al = (j == 0) ? 1 : 6, ar = (j == 5) ? 1 : 6;
      const float* base = tens + (size_t)((j * 2 + cfg[b * 36 + j])) * 1296;
      int n = al * 6 * ar;
      double* dst = CA + c1off[j];
      for (int idx = tid; idx < n; idx += NT) {
        int l = idx / (6 * ar); int rest = idx - l * (6 * ar);
        int mu = rest / ar; int rr = rest - mu * ar;
        dst[idx] = (double)base[l * 216 + mu * 6 + rr];
      }
    }
    __syncthreads();
  }

  run_round(1, b, cfg, tens, CA, CB, tid);
  run_round(2, b, cfg, tens, CB, CA, tid);
  run_round(3, b, cfg, tens, CA, CB, tid);
  run_round(4, b, cfg, tens, CB, CA, tid);

  // final exact contraction of cand (in CA) with row 5 (down dim = 1)
  {
    const int roff1[6] = {0, 36, 252, 468, 684, 900};
    double* ROW = g_m + (size_t)b * M_STRIDE + M_ROW;
    gather_row(cfg, tens, b, 5, 1, ROW, roff1, tid);
    double* E = L_E(lp); double* E2 = L_E2(lp);
    if (tid == 0) E[0] = 1.0;
    __syncthreads();
    const int ob[7] = {1, 6, 24, 24, 24, 6, 1};
    int oo[6]; oo[0] = 0;
    for (int j = 0; j < 5; ++j) oo[j + 1] = oo[j] + ob[j] * 6 * ob[j + 1];
    const double* candF = CA;
    double* src = E; double* dst = E2;
    for (int j = 0; j < 6; ++j) {
      int cl = ob[j], cr = ob[j + 1];
      int al = (j == 0) ? 1 : 6, ar = (j == 5) ? 1 : 6;
      int n = cr * ar;
      for (int idx = tid; idx < n; idx += NT) {
        int rr = idx / ar, R_ = idx - rr * ar;
        double acc = 0.0;
        for (int l = 0; l < cl; ++l) {
          for (int L = 0; L < al; ++L) {
            double e = src[l * al + L];
            double s2 = 0.0;
#pragma unroll
            for (int mu = 0; mu < 6; ++mu)
              s2 += candF[oo[j] + (l * 6 + mu) * cr + rr] * ROW[roff1[j] + (L * 6 + mu) * ar + R_];
            acc += e * s2;
          }
        }
        dst[idx] = acc;
      }
      __syncthreads();
      double* tmp = src; src = dst; dst = tmp;
    }
    if (tid == 0) out[b] = (float)(src[0] * exp(*L_LOG(lp)));
  }
}

// ---------------- launch ----------------
extern "C" void kernel_launch(void* const* d_in, const int* in_sizes, int n_in,
                              void* d_out, int out_size, void* d_ws, size_t ws_size,
                              hipStream_t stream) {
  (void)in_sizes; (void)n_in; (void)out_size; (void)d_ws; (void)ws_size;
  const int* cfg = (const int*)d_in[0];
  const float* tens = (const float*)d_in[1];
  float* out = (float*)d_out;
  (void)hipFuncSetAttribute((const void*)peps_kernel,
                            hipFuncAttributeMaxDynamicSharedMemorySize, LDS_BYTES);
  peps_kernel<<<dim3(NB), dim3(NT), LDS_BYTES, stream>>>(cfg, tens, out);
}

// Round 8
// 42593.909 us; speedup vs baseline: 1.5155x; 1.1485x over previous
//
#include <hip/hip_runtime.h>
#include <math.h>

#define NT 512
#define NB 32

// ---------------- unified fp64 arena (per-batch, element offsets) ----------------
#define M_D    0        // 124416 : double-tensor D_j (max 144 x 864)
#define M_A    124416   // 124416 : A1/A2/A4
#define M_A3   248832   // 124416 : A3 (kept through round)
#define M_Q2   373248   // 31104  : Q2 (216 x K)
#define M_Q4   404352   // 31104  : Q4 (6K x 36)
#define M_TB   435456   // 20736  : t-matrix buffer (max 144x144)
#define M_Q1   456192   // 1296
#define M_Q0   457488   // 64
#define M_ROW  457552   // 5616   : gathered row tensors
#define M_R    463168   // 20736  : current R (dense)
#define M_T    483904   // 20736  : current T = R^-1 (also T24 in refine)
#define M_T3   504640   // 20736  : T3 kept
#define M_G    525392   // 20736  : Gram / chol workspace
#define M_CA   546128   // 8712   : cand buffer A
#define M_CB   554840   // 8712   : cand buffer B
#define M_X    563552   // 3456   : push factor X (max 144x24)
#define M_Z    567008   // 3456   : Z = T3*X4
#define M_T5   570464   // 216
#define M_X5   570680   // 216
#define M_QP   570896   // 64
#define M_X1   570960   // 64
#define M_T1   571024   // 864
#define M_Y0   571888   // 3456   : refine: approx subspace basis (My x 24)
#define M_YH   575344   // 3456   : refine: orthonormal basis
#define M_W    578800   // 576    : refine: sorted right-rotation
#define M_P    579376   // 3456   : refine: YH * W
#define M_STRIDE 582832

__device__ __align__(16) double g_m[(size_t)NB * M_STRIDE];

// ---------------- LDS layout (byte offsets) ----------------
// phase A (f32 Jacobi): B f32 [0, 82944), J f32 [82944, 88128)
// phase B (fp64 refine): Zr fp64 [0, 27648), J24 fp64 [27648, 32256)
// phase C (staged mm): panels at [0, 82944)
#define STAGE_CAP 82944
#define LO_J     82944
#define LO_NORM  88128   // double[144]
#define LO_S     89280   // double[24]
#define LO_E     89472   // double[144]
#define LO_E2    90624   // double[144]
#define LO_SEL   91776   // int[24]
#define LO_FLAG  91872   // int
#define LO_LOG   91880   // double
#define LO_SCALE 91888   // double
#define LDS_BYTES 92160

__device__ __forceinline__ char* ldsp() {
  extern __shared__ char lds_pool[];
  return lds_pool;
}
#define L_B(p)     ((float*)(p))
#define L_J(p)     ((float*)((p)+LO_J))
#define L_ZR(p)    ((double*)(p))
#define L_J24(p)   ((double*)((p)+27648))
#define L_NORM(p)  ((double*)((p)+LO_NORM))
#define L_S(p)     ((double*)((p)+LO_S))
#define L_E(p)     ((double*)((p)+LO_E))
#define L_E2(p)    ((double*)((p)+LO_E2))
#define L_SEL(p)   ((int*)((p)+LO_SEL))
#define L_FLAG(p)  ((int*)((p)+LO_FLAG))
#define L_LOG(p)   ((double*)((p)+LO_LOG))
#define L_SCALE(p) ((double*)((p)+LO_SCALE))

// ---------------- fp64 matmuls (4-wide strip when N%4==0) ----------------
__device__ void mm_nn(const double* __restrict__ A, int lda, const double* __restrict__ Bm, int ldb,
                      double* __restrict__ C, int ldc, int M, int N, int Kd, int tid) {
  if ((N & 3) == 0) {
    int nstrip = N >> 2;
    for (int u = tid; u < M * nstrip; u += NT) {
      int i = u / nstrip, j0 = (u - i * nstrip) << 2;
      const double* a = A + (size_t)i * lda;
      const double* b = Bm + j0;
      double d0 = 0, d1 = 0, d2 = 0, d3 = 0;
      for (int k = 0; k < Kd; ++k) {
        double av = a[k];
        const double* br = b + (size_t)k * ldb;
        d0 += av * br[0]; d1 += av * br[1]; d2 += av * br[2]; d3 += av * br[3];
      }
      size_t o = (size_t)i * ldc + j0;
      C[o] = d0; C[o + 1] = d1; C[o + 2] = d2; C[o + 3] = d3;
    }
  } else {
    for (int idx = tid; idx < M * N; idx += NT) {
      int i = idx / N, j = idx - i * N;
      const double* a = A + (size_t)i * lda;
      double acc = 0.0;
      for (int k = 0; k < Kd; ++k) acc += a[k] * Bm[(size_t)k * ldb + j];
      C[(size_t)i * ldc + j] = acc;
    }
  }
  __syncthreads();
}

__device__ void mm_tn(const double* __restrict__ A, int lda, const double* __restrict__ Bm, int ldb,
                      double* __restrict__ C, int ldc, int M, int N, int Kd, int tid) {
  if ((N & 3) == 0) {
    int nstrip = N >> 2;
    for (int u = tid; u < M * nstrip; u += NT) {
      int i = u / nstrip, j0 = (u - i * nstrip) << 2;
      double d0 = 0, d1 = 0, d2 = 0, d3 = 0;
      for (int k = 0; k < Kd; ++k) {
        double av = A[(size_t)k * lda + i];
        const double* br = Bm + (size_t)k * ldb + j0;
        d0 += av * br[0]; d1 += av * br[1]; d2 += av * br[2]; d3 += av * br[3];
      }
      size_t o = (size_t)i * ldc + j0;
      C[o] = d0; C[o + 1] = d1; C[o + 2] = d2; C[o + 3] = d3;
    }
  } else {
    for (int idx = tid; idx < M * N; idx += NT) {
      int i = idx / N, j = idx - i * N;
      double acc = 0.0;
      for (int k = 0; k < Kd; ++k) acc += A[(size_t)k * lda + i] * Bm[(size_t)k * ldb + j];
      C[(size_t)i * ldc + j] = acc;
    }
  }
  __syncthreads();
}

__device__ void mm_nt(const double* __restrict__ A, int lda, const double* __restrict__ Bm, int ldb,
                      double* __restrict__ C, int ldc, int M, int N, int Kd, int tid) {
  for (int idx = tid; idx < M * N; idx += NT) {
    int i = idx / N, j = idx - i * N;
    double acc = 0.0;
    for (int k = 0; k < Kd; ++k) acc += A[(size_t)i * lda + k] * Bm[(size_t)j * ldb + k];
    C[(size_t)i * ldc + j] = acc;
  }
  __syncthreads();
}

// ---------------- LDS-staged matmuls (fp64-reorder safe post-refine) ----------------
// C(M x N) = A(M x Kd, lda) * B(Kd x N, ldb). Stages B in 64-col panels in LDS;
// 2x4 register tiles. Requires N%4==0, M%2==0, Kd*64*8 <= STAGE_CAP (Kd<=162).
// C must NOT alias LDS.
__device__ void mm_nn_bs(const double* __restrict__ A, int lda,
                         const double* __restrict__ Bm, int ldb,
                         double* __restrict__ C, int ldc,
                         int M, int N, int Kd, char* lp, int tid) {
  double* SB = (double*)lp;
  for (int n0 = 0; n0 < N; n0 += 64) {
    int nb = N - n0; if (nb > 64) nb = 64;
    for (int x = tid; x < Kd * nb; x += NT) {
      int k = x / nb, j = x - k * nb;
      SB[x] = Bm[(size_t)k * ldb + n0 + j];
    }
    __syncthreads();
    int nstrip = nb >> 2;
    int items = (M >> 1) * nstrip;
    for (int u = tid; u < items; u += NT) {
      int iq = u / nstrip;
      int i = iq << 1;
      int jl = (u - iq * nstrip) << 2;
      const double* a0 = A + (size_t)i * lda;
      const double* a1 = a0 + lda;
      double c00 = 0, c01 = 0, c02 = 0, c03 = 0;
      double c10 = 0, c11 = 0, c12 = 0, c13 = 0;
      for (int k = 0; k < Kd; ++k) {
        double av0 = a0[k], av1 = a1[k];
        const double* bp = SB + k * nb + jl;
        double b0 = bp[0], b1 = bp[1], b2 = bp[2], b3 = bp[3];
        c00 += av0 * b0; c01 += av0 * b1; c02 += av0 * b2; c03 += av0 * b3;
        c10 += av1 * b0; c11 += av1 * b1; c12 += av1 * b2; c13 += av1 * b3;
      }
      size_t o0 = (size_t)i * ldc + n0 + jl, o1 = o0 + ldc;
      C[o0] = c00; C[o0 + 1] = c01; C[o0 + 2] = c02; C[o0 + 3] = c03;
      C[o1] = c10; C[o1 + 1] = c11; C[o1 + 2] = c12; C[o1 + 3] = c13;
    }
    __syncthreads();
  }
}

// G (n x n, upper triangle valid) = A^T A ; A (Kd x n, row stride lda).
// Stages A k-panels in LDS; per-chunk accumulate into global G.
__device__ void gram_s(const double* __restrict__ A, int lda, int n, int Kd,
                       double* __restrict__ G, char* lp, int tid) {
  double* P = (double*)lp;
  int KC = (STAGE_CAP / 8) / n; if (KC > Kd) KC = Kd;
  for (int idx = tid; idx < n * n; idx += NT) {
    int i = idx / n, j = idx - i * n;
    if (j >= i) G[idx] = 0.0;
  }
  __syncthreads();
  for (int k0 = 0; k0 < Kd; k0 += KC) {
    int kc = Kd - k0; if (kc > KC) kc = KC;
    for (int x = tid; x < kc * n; x += NT) {
      int kk = x / n, i = x - kk * n;
      P[x] = A[(size_t)(k0 + kk) * lda + i];
    }
    __syncthreads();
    for (int idx = tid; idx < n * n; idx += NT) {
      int i = idx / n, j = idx - i * n;
      if (j < i) continue;
      double s = 0.0;
      for (int kk = 0; kk < kc; ++kk) s += P[kk * n + i] * P[kk * n + j];
      G[idx] += s;
    }
    __syncthreads();
  }
}

// ---------------- Cholesky (fp64, in-place upper R, G = R^T R) ----------------
__device__ void cholesky(double* G, int n, int tid) {
  for (int j = 0; j < n; ++j) {
    __syncthreads();
    double piv = G[(size_t)j * n + j];
    double r = sqrt(piv > 1e-300 ? piv : 1e-300);
    double inv = 1.0 / r;
    __syncthreads();
    for (int i = j + tid; i < n; i += NT)
      G[(size_t)j * n + i] = (i == j) ? r : G[(size_t)j * n + i] * inv;
    __syncthreads();
    int w = n - j - 1;
    for (int idx = tid; idx < w * w; idx += NT) {
      int ii = idx / w, kk = idx - ii * w;
      int i = j + 1 + ii, k2 = j + 1 + kk;
      if (k2 >= i) G[(size_t)i * n + k2] -= G[(size_t)j * n + i] * G[(size_t)j * n + k2];
    }
  }
  __syncthreads();
}

// T = R^{-1} (upper), fp64 dense (lower zeroed)
__device__ void trinv(const double* G, int n, double* T, int tid) {
  for (int c = tid; c < n; c += NT) {
    T[(size_t)c * n + c] = 1.0 / G[(size_t)c * n + c];
    for (int r = c - 1; r >= 0; --r) {
      double s = 0.0;
      for (int k = r + 1; k <= c; ++k) s += G[(size_t)r * n + k] * T[(size_t)k * n + c];
      T[(size_t)r * n + c] = -s / G[(size_t)r * n + r];
    }
    for (int r = c + 1; r < n; ++r) T[(size_t)r * n + c] = 0.0;
  }
  __syncthreads();
}

__device__ void copyR(const double* G, int n, double* Rw, int tid) {
  for (int idx = tid; idx < n * n; idx += NT) {
    int i = idx / n, k = idx - i * n;
    Rw[idx] = (k >= i) ? G[idx] : 0.0;
  }
  __syncthreads();
}

// tall CholQR: A (Mr x Nc), Mr >= Nc
__device__ void tallQR(const double* A, int Mr, int Nc, double* Q, double* Rw,
                       double* G, double* T, char* lp, int tid) {
  if (Mr >= 128) gram_s(A, Nc, Nc, Mr, G, lp, tid);
  else           mm_tn(A, Nc, A, Nc, G, Nc, Nc, Nc, Mr, tid);
  cholesky(G, Nc, tid);
  trinv(G, Nc, T, tid);
  if (Q) {
    if (Nc >= 64) mm_nn_bs(A, Nc, T, Nc, Q, Nc, Mr, Nc, Nc, lp, tid);
    else          mm_nn(A, Nc, T, Nc, Q, Nc, Mr, Nc, Nc, tid);
  }
  if (Rw) copyR(G, Nc, Rw, tid);
}

// wide QR (Mr < Nc): QR of first Mr cols, Rw = Q^T A (Mr x Nc)
__device__ void wideQR(const double* A, int Mr, int Nc, double* Q, double* Rw,
                       double* G, double* T, int tid) {
  mm_tn(A, Nc, A, Nc, G, Mr, Mr, Mr, Mr, tid);
  cholesky(G, Mr, tid);
  trinv(G, Mr, T, tid);
  mm_nn(A, Nc, T, Mr, Q, Mr, Mr, Mr, Mr, tid);
  mm_tn(Q, Mr, A, Nc, Rw, Nc, Mr, Nc, Mr, tid);
}

// ---------------- double-tensor build (fp64) ----------------
__device__ void build_D(const double* __restrict__ cand, int cl, int cr,
                        const double* __restrict__ rowS, int al, int ar,
                        double* __restrict__ D, int tid) {
  int mnext = cr * ar;
  int ncols = 6 * mnext;
  int n = cl * al * ncols;
  for (int idx = tid; idx < n; idx += NT) {
    int row = idx / ncols, col = idx - row * ncols;
    int l = row / al, L = row - l * al;
    int d = col / mnext, rem = col - d * mnext;
    int rr = rem / ar, R_ = rem - rr * ar;
    double acc = 0.0;
#pragma unroll
    for (int mu = 0; mu < 6; ++mu)
      acc += cand[(l * 6 + mu) * cr + rr] * rowS[((L * 6 + mu) * 6 + d) * ar + R_];
    D[idx] = acc;
  }
  __syncthreads();
}

// gather a physical row r into ROW buffer (fp64); dd = down-dim
__device__ void gather_row(const int* cfg, const float* tens, int b, int r, int dd,
                           double* ROW, const int* roff, int tid) {
  for (int j = 0; j < 6; ++j) {
    int al = (j == 0) ? 1 : 6, ar = (j == 5) ? 1 : 6;
    const float* base = tens + (size_t)(((r * 6 + j) * 2 + cfg[b * 36 + r * 6 + j])) * 1296;
    int n = al * 6 * dd * ar;
    double* dst = ROW + roff[j];
    for (int idx = tid; idx < n; idx += NT) {
      int R_ = idx % ar; int t2 = idx / ar;
      int d = t2 % dd; t2 /= dd;
      int mu = t2 % 6; int L = t2 / 6;
      dst[idx] = (double)base[L * 216 + mu * 36 + d * 6 + R_];
    }
  }
  __syncthreads();
}

// ---------------- f32 one-sided Jacobi (coarse subspace finder) ----------------
__device__ void jacobi36(float* B, int R, float* J, int* flag, int tid) {
  for (int i = tid; i < 36 * 36; i += NT) J[i] = ((i / 36) == (i % 36)) ? 1.f : 0.f;
  __syncthreads();
  for (int sw = 0; sw < 9; ++sw) {
    if (tid == 0) *flag = 0;
    __syncthreads();
    for (int t = 0; t < 35; ++t) {
      int s = tid >> 3, h = tid & 7;
      bool act = (tid < 144);
      int p = 0, q = 0; float c = 1.f, sn = 0.f; bool doit = false;
      if (act) {
        if (s == 0) { p = 35; q = t % 35; }
        else { p = (t + s) % 35; q = (t - s + 35) % 35; }
        float app = 0.f, aqq = 0.f, apq = 0.f;
        for (int r = h; r < R; r += 8) {
          float x = B[r * 36 + p], y = B[r * 36 + q];
          app += x * x; aqq += y * y; apq += x * y;
        }
        app += __shfl_xor(app, 1); aqq += __shfl_xor(aqq, 1); apq += __shfl_xor(apq, 1);
        app += __shfl_xor(app, 2); aqq += __shfl_xor(aqq, 2); apq += __shfl_xor(apq, 2);
        app += __shfl_xor(app, 4); aqq += __shfl_xor(aqq, 4); apq += __shfl_xor(apq, 4);
        double g = (double)apq, aa = (double)app, bb = (double)aqq;
        if (g * g > 1e-14 * aa * bb) {
          doit = true;
          if (h == 0) *flag = 1;
          double tau = (bb - aa) / (2.0 * g);
          double tt = (tau >= 0.0 ? 1.0 : -1.0) / (fabs(tau) + sqrt(1.0 + tau * tau));
          double cc = 1.0 / sqrt(1.0 + tt * tt);
          c = (float)cc; sn = (float)(tt * cc);
        }
      }
      if (doit) {
        for (int r = h; r < R; r += 8) {
          float x = B[r * 36 + p], y = B[r * 36 + q];
          B[r * 36 + p] = c * x - sn * y;
          B[r * 36 + q] = sn * x + c * y;
        }
        for (int r = h; r < 36; r += 8) {
          float x = J[r * 36 + p], y = J[r * 36 + q];
          J[r * 36 + p] = c * x - sn * y;
          J[r * 36 + q] = sn * x + c * y;
        }
      }
      __syncthreads();
    }
    int f = *flag;
    __syncthreads();
    if (!f) break;
  }
}

__device__ void jacobi144(float* B, int* flag, int tid) {
  for (int sw = 0; sw < 9; ++sw) {
    if (tid == 0) *flag = 0;
    __syncthreads();
    for (int t = 0; t < 143; ++t) {
      int s = tid >> 2, h = tid & 3;
      bool act = (tid < 288);
      float xp[36], xq[36];
      int p = 0, q = 0; float c = 1.f, sn = 0.f; bool doit = false;
      if (act) {
        if (s == 0) { p = 143; q = t % 143; }
        else { p = (t + s) % 143; q = (t - s + 143) % 143; }
        float app = 0.f, aqq = 0.f, apq = 0.f;
#pragma unroll
        for (int i = 0; i < 36; ++i) {
          int r = h + 4 * i;
          float x = B[r * 144 + p], y = B[r * 144 + q];
          xp[i] = x; xq[i] = y;
          app += x * x; aqq += y * y; apq += x * y;
        }
        app += __shfl_xor(app, 1); aqq += __shfl_xor(aqq, 1); apq += __shfl_xor(apq, 1);
        app += __shfl_xor(app, 2); aqq += __shfl_xor(aqq, 2); apq += __shfl_xor(apq, 2);
        double g = (double)apq, aa = (double)app, bb = (double)aqq;
        if (g * g > 1e-14 * aa * bb) {
          doit = true;
          if (h == 0) *flag = 1;
          double tau = (bb - aa) / (2.0 * g);
          double tt = (tau >= 0.0 ? 1.0 : -1.0) / (fabs(tau) + sqrt(1.0 + tau * tau));
          double cc = 1.0 / sqrt(1.0 + tt * tt);
          c = (float)cc; sn = (float)(tt * cc);
        }
      }
      if (doit) {
#pragma unroll
        for (int i = 0; i < 36; ++i) {
          int r = h + 4 * i;
          B[r * 144 + p] = c * xp[i] - sn * xq[i];
          B[r * 144 + q] = sn * xp[i] + c * xq[i];
        }
      }
      __syncthreads();
    }
    int f = *flag;
    __syncthreads();
    if (!f) break;
  }
}

// column norms (f32 B) + top-`keep` selection
__device__ void colnorms_sel(const float* B, int R, int C, int keep, char* lp, int tid) {
  double* NORM = L_NORM(lp); int* SEL = L_SEL(lp); double* S = L_S(lp);
  for (int c = tid; c < C; c += NT) {
    double a = 0.0;
    for (int r = 0; r < R; ++r) { float v = B[r * C + c]; a += (double)v * (double)v; }
    NORM[c] = a;
  }
  __syncthreads();
  if (tid == 0) {
    for (int i = 0; i < keep; ++i) {
      int bi = 0; double bv = -1.0;
      for (int x = 0; x < C; ++x) if (NORM[x] > bv) { bv = NORM[x]; bi = x; }
      SEL[i] = bi;
      S[i] = sqrt(bv > 1e-300 ? bv : 1e-300);
      NORM[bi] = -2.0;
    }
  }
  __syncthreads();
}

// ---------------- fp64 refinement ----------------
__device__ void jacobi24d(double* Z, int R, double* J24, int* flag, int tid) {
  for (int i = tid; i < 576; i += NT) J24[i] = ((i / 24) == (i % 24)) ? 1.0 : 0.0;
  __syncthreads();
  for (int sw = 0; sw < 16; ++sw) {
    if (tid == 0) *flag = 0;
    __syncthreads();
    for (int t = 0; t < 23; ++t) {
      int s = tid >> 3, h = tid & 7;
      bool act = (tid < 96);
      int p = 0, q = 0; double c_ = 1.0, sn = 0.0; bool doit = false;
      if (act) {
        if (s == 0) { p = 23; q = t % 23; }
        else { p = (t + s) % 23; q = (t - s + 23) % 23; }
        double app = 0, aqq = 0, apq = 0;
        for (int r = h; r < R; r += 8) {
          double x = Z[r * 24 + p], y = Z[r * 24 + q];
          app += x * x; aqq += y * y; apq += x * y;
        }
        app += __shfl_xor(app, 1); aqq += __shfl_xor(aqq, 1); apq += __shfl_xor(apq, 1);
        app += __shfl_xor(app, 2); aqq += __shfl_xor(aqq, 2); apq += __shfl_xor(apq, 2);
        app += __shfl_xor(app, 4); aqq += __shfl_xor(aqq, 4); apq += __shfl_xor(apq, 4);
        if (apq * apq > 1e-28 * app * aqq) {
          doit = true;
          if (h == 0) *flag = 1;
          double tau = (aqq - app) / (2.0 * apq);
          double tt = (tau >= 0.0 ? 1.0 : -1.0) / (fabs(tau) + sqrt(1.0 + tau * tau));
          double cc = 1.0 / sqrt(1.0 + tt * tt);
          c_ = cc; sn = tt * cc;
        }
      }
      if (doit) {
        for (int r = h; r < R; r += 8) {
          double x = Z[r * 24 + p], y = Z[r * 24 + q];
          Z[r * 24 + p] = c_ * x - sn * y;
          Z[r * 24 + q] = sn * x + c_ * y;
        }
        for (int r = h; r < 24; r += 8) {
          double x = J24[r * 24 + p], y = J24[r * 24 + q];
          J24[r * 24 + p] = c_ * x - sn * y;
          J24[r * 24 + q] = sn * x + c_ * y;
        }
      }
      __syncthreads();
    }
    int f = *flag;
    __syncthreads();
    if (!f) break;
  }
}

__device__ void sort24(const double* Z, int R, char* lp, int tid) {
  double* NORM = L_NORM(lp); int* SEL = L_SEL(lp); double* S = L_S(lp);
  for (int c = tid; c < 24; c += NT) {
    double a = 0.0;
    for (int r = 0; r < R; ++r) { double v = Z[r * 24 + c]; a += v * v; }
    NORM[c] = a;
  }
  __syncthreads();
  if (tid == 0) {
    for (int i = 0; i < 24; ++i) {
      int bi = 0; double bv = -1.0;
      for (int x = 0; x < 24; ++x) if (NORM[x] > bv) { bv = NORM[x]; bi = x; }
      SEL[i] = bi;
      S[i] = sqrt(bv > 1e-300 ? bv : 1e-300);
      NORM[bi] = -2.0;
    }
  }
  __syncthreads();
}

// Rayleigh-Ritz refinement (see round-7 comments)
__device__ void refine(const double* t, int tR, int tC, int My, int ucase,
                       double* site, double* X, double* Dd, char* lp, int tid) {
  double* G = Dd + M_G;   double* T24 = Dd + M_T;
  double* Y0 = Dd + M_Y0; double* YH = Dd + M_YH;
  double* W = Dd + M_W;   double* P = Dd + M_P;
  double* Zr = L_ZR(lp);  double* J24 = L_J24(lp);
  int Rz = ucase ? tC : tR;
  mm_tn(Y0, 24, Y0, 24, G, 24, 24, 24, My, tid);
  cholesky(G, 24, tid);
  trinv(G, 24, T24, tid);
  mm_nn(Y0, 24, T24, 24, YH, 24, My, 24, 24, tid);
  if (ucase) mm_tn(t, tC, YH, 24, Zr, 24, tC, 24, tR, tid);
  else       mm_nn(t, tC, YH, 24, Zr, 24, tR, 24, tC, tid);
  jacobi24d(Zr, Rz, J24, L_FLAG(lp), tid);
  sort24(Zr, Rz, lp, tid);
  int* SEL = L_SEL(lp); double* S = L_S(lp);
  for (int i = tid; i < 576; i += NT) {
    int k = i / 24, c = i - k * 24;
    W[i] = J24[k * 24 + SEL[c]];
  }
  __syncthreads();
  mm_nn(YH, 24, W, 24, P, 24, My, 24, 24, tid);
  if (ucase) {
    for (int i = tid; i < My * 24; i += NT) {
      int k = i / 24, c = i - k * 24;
      X[i] = P[i] * S[c];
    }
    for (int i = tid; i < 24 * tC; i += NT) {
      int c = i / tC, x = i - c * tC;
      site[i] = Zr[x * 24 + SEL[c]] / S[c];
    }
  } else {
    for (int i = tid; i < 24 * My; i += NT) {
      int c = i / My, x = i - c * My;
      site[i] = P[x * 24 + c];
    }
    for (int i = tid; i < Rz * 24; i += NT) {
      int k = i / 24, c = i - k * 24;
      X[i] = Zr[k * 24 + SEL[c]];
    }
  }
  __syncthreads();
}

// SVD of t (R x 36), keep 24
__device__ void svdV36d(const double* t, int R, double* site, double* X,
                        double* Dd, char* lp, int tid) {
  float* B = L_B(lp); float* J = L_J(lp);
  for (int i = tid; i < R * 36; i += NT) B[i] = (float)t[i];
  __syncthreads();
  jacobi36(B, R, J, L_FLAG(lp), tid);
  colnorms_sel(B, R, 36, 24, lp, tid);
  int* SEL = L_SEL(lp);
  double* Y0 = Dd + M_Y0;
  for (int i = tid; i < 36 * 24; i += NT) {
    int x = i / 24, c = i - x * 24;
    Y0[i] = (double)J[x * 36 + SEL[c]];
  }
  __syncthreads();
  refine(t, R, 36, 36, 0, site, X, Dd, lp, tid);
}

// SVD of t (36 x 144), keep 24
__device__ void svdU36d(const double* t, double* site, double* X,
                        double* Dd, char* lp, int tid) {
  float* B = L_B(lp); float* J = L_J(lp);
  for (int i = tid; i < 144 * 36; i += NT) {
    int x = i / 36, k = i - x * 36;
    B[i] = (float)t[k * 144 + x];
  }
  __syncthreads();
  jacobi36(B, 144, J, L_FLAG(lp), tid);
  colnorms_sel(B, 144, 36, 24, lp, tid);
  int* SEL = L_SEL(lp);
  double* Y0 = Dd + M_Y0;
  for (int i = tid; i < 36 * 24; i += NT) {
    int x = i / 24, c = i - x * 24;
    Y0[i] = (double)J[x * 36 + SEL[c]];
  }
  __syncthreads();
  refine(t, 36, 144, 36, 1, site, X, Dd, lp, tid);
}

// SVD of t (144 x 144), keep 24
__device__ void stepJ3bigd(const double* t, double* site, double* X,
                           double* Dd, char* lp, int tid) {
  float* B = L_B(lp);
  for (int i = tid; i < 144 * 144; i += NT) B[i] = (float)t[i];
  __syncthreads();
  jacobi144(B, L_FLAG(lp), tid);
  colnorms_sel(B, 144, 144, 24, lp, tid);
  int* SEL = L_SEL(lp);
  double* Y0 = Dd + M_Y0;
  for (int i = tid; i < 144 * 24; i += NT) {
    int k = i / 24, c = i - k * 24;
    Y0[i] = (double)B[k * 144 + SEL[c]];
  }
  __syncthreads();
  refine(t, 144, 144, 144, 1, site, X, Dd, lp, tid);
}

// LQ of t5 (36x6)
__device__ void stepJ5(const double* t5, double* G, double* T, double* Qp,
                       double* cand5, double* X5, int tid) {
  mm_nt(t5, 6, t5, 6, G, 6, 6, 6, 6, tid);
  cholesky(G, 6, tid);
  trinv(G, 6, T, tid);
  mm_tn(t5, 6, T, 6, Qp, 6, 6, 6, 6, tid);
  for (int i = tid; i < 36; i += NT) {
    int l = i / 6, mu = i - l * 6;
    cand5[i] = Qp[mu * 6 + l];
  }
  __syncthreads();
  mm_nn(t5, 6, Qp, 6, X5, 6, 36, 6, 6, tid);
}

// LQ of t1 (6x144)
__device__ void stepJ1(const double* t1, double* G, double* T,
                       double* cand1, double* X1, int tid) {
  mm_nt(t1, 144, t1, 144, G, 6, 6, 6, 144, tid);
  cholesky(G, 6, tid);
  trinv(G, 6, T, tid);
  mm_tn(T, 6, t1, 144, cand1, 144, 6, 144, 6, tid);
  for (int i = tid; i < 36; i += NT) {
    int r = i / 6, c = i - r * 6;
    X1[i] = (c <= r) ? G[c * 6 + r] : 0.0;
  }
  __syncthreads();
}

__device__ void rescale0(double* cout_, char* lp, int tid) {
  if (tid == 0) {
    double m = 0.0;
    for (int i = 0; i < 36; ++i) { double v = fabs(cout_[i]); if (v > m) m = v; }
    if (!(m > 1e-300)) m = 1.0;
    *L_SCALE(lp) = m;
    *L_LOG(lp) += log(m);
  }
  __syncthreads();
  double m = *L_SCALE(lp);
  for (int i = tid; i < 36; i += NT) cout_[i] /= m;
  __syncthreads();
}

// ---------------- one _bmps round (truncating compress to DC=24) ----------------
__device__ void run_round(int r, int b, const int* cfg, const float* tens,
                          const double* cin_, double* cout_, int tid) {
  char* lp = ldsp();
  double* Dd = g_m + (size_t)b * M_STRIDE;
  const int K  = (r == 1) ? 36 : 144;
  const int cK = (r == 1) ? 6 : 24;
  int cb[7] = {1, 6, cK, cK, cK, 6, 1};
  int co[6]; co[0] = 0;
  for (int j = 0; j < 5; ++j) co[j + 1] = co[j] + cb[j] * 6 * cb[j + 1];
  const int ob[7] = {1, 6, 24, 24, 24, 6, 1};
  int oo[6]; oo[0] = 0;
  for (int j = 0; j < 5; ++j) oo[j + 1] = oo[j] + ob[j] * 6 * ob[j + 1];
  const int roff6[6] = {0, 216, 1512, 2808, 4104, 5400};

  double* ROW = Dd + M_ROW;
  double* Dbuf = Dd + M_D;  double* Abuf = Dd + M_A;  double* A3 = Dd + M_A3;
  double* Q2 = Dd + M_Q2;   double* Q4 = Dd + M_Q4;   double* Q1 = Dd + M_Q1;  double* Q0 = Dd + M_Q0;
  double* TB = Dd + M_TB;   double* Rw = Dd + M_R;    double* Tw = Dd + M_T;   double* T3 = Dd + M_T3;
  double* G = Dd + M_G;     double* X = Dd + M_X;     double* Zp = Dd + M_Z;
  double* t5 = Dd + M_T5;   double* X5 = Dd + M_X5;   double* Qp = Dd + M_QP;
  double* X1 = Dd + M_X1;   double* t1 = Dd + M_T1;

  gather_row(cfg, tens, b, r, 6, ROW, roff6, tid);

  // ---- QR sweep (left-canonicalize) ----
  build_D(cin_ + co[0], 1, cb[1], ROW + roff6[0], 1, 6, Dbuf, tid);
  wideQR(Dbuf, 6, 36, Q0, Rw, G, Tw, tid);

  build_D(cin_ + co[1], 6, cb[2], ROW + roff6[1], 6, 6, Dbuf, tid);
  mm_nn(Rw, 36, Dbuf, 6 * K, Abuf, 6 * K, 6, 6 * K, 36, tid);
  if (K == 36) tallQR(Abuf, 36, 36, Q1, Rw, G, Tw, lp, tid);
  else         wideQR(Abuf, 36, 144, Q1, Rw, G, Tw, tid);

  build_D(cin_ + co[2], cb[2], cb[3], ROW + roff6[2], 6, 6, Dbuf, tid);
  mm_nn_bs(Rw, K, Dbuf, 6 * K, Abuf, 6 * K, 36, 6 * K, K, lp, tid);
  tallQR(Abuf, 216, K, Q2, Rw, G, Tw, lp, tid);

  build_D(cin_ + co[3], cb[3], cb[4], ROW + roff6[3], 6, 6, Dbuf, tid);
  mm_nn_bs(Rw, K, Dbuf, 6 * K, A3, 6 * K, K, 6 * K, K, lp, tid);
  tallQR(A3, 6 * K, K, nullptr, Rw, G, T3, lp, tid);

  build_D(cin_ + co[4], cb[4], cb[5], ROW + roff6[4], 6, 6, Dbuf, tid);
  mm_nn_bs(Rw, K, Dbuf, 216, Abuf, 216, K, 216, K, lp, tid);
  tallQR(Abuf, 6 * K, 36, Q4, Rw, G, Tw, lp, tid);

  build_D(cin_ + co[5], cb[5], 1, ROW + roff6[5], 6, 1, Dbuf, tid);
  mm_nn(Rw, 36, Dbuf, 6, t5, 6, 36, 6, 36, tid);

  // ---- SVD sweep (right-to-left, truncate at j=4,3,2) ----
  stepJ5(t5, G, Tw, Qp, cout_ + oo[5], X5, tid);
  mm_nn(Q4, 36, X5, 6, TB, 6, 6 * K, 6, 36, tid);                 // t4 (K x 36)
  svdV36d(TB, K, cout_ + oo[4], X, Dd, lp, tid);                  // X (K x 24)
  mm_nn_bs(T3, K, X, 24, Zp, 24, K, 24, K, lp, tid);              // Z = T3 X4
  mm_nn_bs(A3, K, Zp, 24, TB, 24, 6 * K, 24, K, lp, tid);         // t3 (K x 144)
  if (K == 144) stepJ3bigd(TB, cout_ + oo[3], X, Dd, lp, tid);
  else          svdU36d(TB, cout_ + oo[3], X, Dd, lp, tid);       // X (K x 24)
  mm_nn_bs(Q2, K, X, 24, TB, 24, 216, 24, K, lp, tid);            // t2 (36 x 144)
  svdU36d(TB, cout_ + oo[2], X, Dd, lp, tid);                     // X (36 x 24)
  mm_nn(Q1, 36, X, 24, t1, 24, 36, 24, 36, tid);                  // t1 (6 x 144)
  stepJ1(t1, G, Tw, cout_ + oo[1], X1, tid);
  mm_nn(Q0, 6, X1, 6, cout_ + oo[0], 6, 6, 6, 6, tid);            // site0
  rescale0(cout_, lp, tid);
}

// ---------------- kernel ----------------
extern "C" __global__ void __launch_bounds__(NT)
peps_kernel(const int* __restrict__ cfg, const float* __restrict__ tens, float* __restrict__ out) {
  const int b = blockIdx.x;
  const int tid = threadIdx.x;
  char* lp = ldsp();
  double* CA = g_m + (size_t)b * M_STRIDE + M_CA;
  double* CB = g_m + (size_t)b * M_STRIDE + M_CB;
  if (tid == 0) *L_LOG(lp) = 0.0;

  // init cand = row 0 (bonds 1,6,6,6,6,6,1 ; up=0)
  {
    const int c1off[6] = {0, 36, 252, 468, 684, 900};
    for (int j = 0; j < 6; ++j) {
      int al = (j == 0) ? 1 : 6, ar = (j == 5) ? 1 : 6;
      const float* base = tens + (size_t)((j * 2 + cfg[b * 36 + j])) * 1296;
      int n = al * 6 * ar;
      double* dst = CA + c1off[j];
      for (int idx = tid; idx < n; idx += NT) {
        int l = idx / (6 * ar); int rest = idx - l * (6 * ar);
        int mu = rest / ar; int rr = rest - mu * ar;
        dst[idx] = (double)base[l * 216 + mu * 6 + rr];
      }
    }
    __syncthreads();
  }

  run_round(1, b, cfg, tens, CA, CB, tid);
  run_round(2, b, cfg, tens, CB, CA, tid);
  run_round(3, b, cfg, tens, CA, CB, tid);
  run_round(4, b, cfg, tens, CB, CA, tid);

  // final exact contraction of cand (in CA) with row 5 (down dim = 1)
  {
    const int roff1[6] = {0, 36, 252, 468, 684, 900};
    double* ROW = g_m + (size_t)b * M_STRIDE + M_ROW;
    gather_row(cfg, tens, b, 5, 1, ROW, roff1, tid);
    double* E = L_E(lp); double* E2 = L_E2(lp);
    if (tid == 0) E[0] = 1.0;
    __syncthreads();
    const int ob[7] = {1, 6, 24, 24, 24, 6, 1};
    int oo[6]; oo[0] = 0;
    for (int j = 0; j < 5; ++j) oo[j + 1] = oo[j] + ob[j] * 6 * ob[j + 1];
    const double* candF = CA;
    double* src = E; double* dst = E2;
    for (int j = 0; j < 6; ++j) {
      int cl = ob[j], cr = ob[j + 1];
      int al = (j == 0) ? 1 : 6, ar = (j == 5) ? 1 : 6;
      int n = cr * ar;
      for (int idx = tid; idx < n; idx += NT) {
        int rr = idx / ar, R_ = idx - rr * ar;
        double acc = 0.0;
        for (int l = 0; l < cl; ++l) {
          for (int L = 0; L < al; ++L) {
            double e = src[l * al + L];
            double s2 = 0.0;
#pragma unroll
            for (int mu = 0; mu < 6; ++mu)
              s2 += candF[oo[j] + (l * 6 + mu) * cr + rr] * ROW[roff1[j] + (L * 6 + mu) * ar + R_];
            acc += e * s2;
          }
        }
        dst[idx] = acc;
      }
      __syncthreads();
      double* tmp = src; src = dst; dst = tmp;
    }
    if (tid == 0) out[b] = (float)(src[0] * exp(*L_LOG(lp)));
  }
}

// ---------------- launch ----------------
extern "C" void kernel_launch(void* const* d_in, const int* in_sizes, int n_in,
                              void* d_out, int out_size, void* d_ws, size_t ws_size,
                              hipStream_t stream) {
  (void)in_sizes; (void)n_in; (void)out_size; (void)d_ws; (void)ws_size;
  const int* cfg = (const int*)d_in[0];
  const float* tens = (const float*)d_in[1];
  float* out = (float*)d_out;
  (void)hipFuncSetAttribute((const void*)peps_kernel,
                            hipFuncAttributeMaxDynamicSharedMemorySize, LDS_BYTES);
  peps_kernel<<<dim3(NB), dim3(NT), LDS_BYTES, stream>>>(cfg, tens, out);
}

// Round 9
// 41004.532 us; speedup vs baseline: 1.5742x; 1.0388x over previous
//
#include <hip/hip_runtime.h>
#include <math.h>

#define NT 1024
#define NB 32

// ---------------- unified fp64 arena (per-batch, element offsets) ----------------
#define M_D    0        // 124416 : double-tensor D_j (max 144 x 864)
#define M_A    124416   // 124416 : A1/A2/A4
#define M_A3   248832   // 124416 : A3 (kept through round)
#define M_Q2   373248   // 31104  : Q2 (216 x K)
#define M_Q4   404352   // 31104  : Q4 (6K x 36)
#define M_TB   435456   // 20736  : t-matrix buffer (max 144x144)
#define M_Q1   456192   // 1296
#define M_Q0   457488   // 64
#define M_ROW  457552   // 5616   : gathered row tensors
#define M_R    463168   // 20736  : current R (dense)
#define M_T    483904   // 20736  : current T = R^-1 (also T24 in refine)
#define M_T3   504640   // 20736  : T3 kept
#define M_G    525392   // 20736  : Gram / chol workspace
#define M_CA   546128   // 8712   : cand buffer A
#define M_CB   554840   // 8712   : cand buffer B
#define M_X    563552   // 3456   : push factor X (max 144x24)
#define M_Z    567008   // 3456   : Z = T3*X4
#define M_T5   570464   // 216
#define M_X5   570680   // 216
#define M_QP   570896   // 64
#define M_X1   570960   // 64
#define M_T1   571024   // 864
#define M_Y0   571888   // 3456   : refine: approx subspace basis (My x 24)
#define M_YH   575344   // 3456   : refine: orthonormal basis
#define M_W    578800   // 576    : refine: sorted right-rotation
#define M_P    579376   // 3456   : refine: YH * W
#define M_STRIDE 582832

__device__ __align__(16) double g_m[(size_t)NB * M_STRIDE];

// ---------------- LDS layout (byte offsets) ----------------
#define STAGE_CAP 82944
#define LO_J     82944
#define LO_NORM  88128   // double[144]
#define LO_S     89280   // double[24]
#define LO_E     89472   // double[144]
#define LO_E2    90624   // double[144]
#define LO_SEL   91776   // int[24]
#define LO_FLAG  91872   // int
#define LO_LOG   91880   // double
#define LO_SCALE 91888   // double
#define LDS_BYTES 92160

__device__ __forceinline__ char* ldsp() {
  extern __shared__ char lds_pool[];
  return lds_pool;
}
#define L_B(p)     ((float*)(p))
#define L_J(p)     ((float*)((p)+LO_J))
#define L_ZR(p)    ((double*)(p))
#define L_J24(p)   ((double*)((p)+27648))
#define L_NORM(p)  ((double*)((p)+LO_NORM))
#define L_S(p)     ((double*)((p)+LO_S))
#define L_E(p)     ((double*)((p)+LO_E))
#define L_E2(p)    ((double*)((p)+LO_E2))
#define L_SEL(p)   ((int*)((p)+LO_SEL))
#define L_FLAG(p)  ((int*)((p)+LO_FLAG))
#define L_LOG(p)   ((double*)((p)+LO_LOG))
#define L_SCALE(p) ((double*)((p)+LO_SCALE))

// ---------------- fp64 matmuls (4-wide strip when N%4==0) ----------------
__device__ void mm_nn(const double* __restrict__ A, int lda, const double* __restrict__ Bm, int ldb,
                      double* __restrict__ C, int ldc, int M, int N, int Kd, int tid) {
  if ((N & 3) == 0) {
    int nstrip = N >> 2;
    for (int u = tid; u < M * nstrip; u += NT) {
      int i = u / nstrip, j0 = (u - i * nstrip) << 2;
      const double* a = A + (size_t)i * lda;
      const double* b = Bm + j0;
      double d0 = 0, d1 = 0, d2 = 0, d3 = 0;
      for (int k = 0; k < Kd; ++k) {
        double av = a[k];
        const double* br = b + (size_t)k * ldb;
        d0 += av * br[0]; d1 += av * br[1]; d2 += av * br[2]; d3 += av * br[3];
      }
      size_t o = (size_t)i * ldc + j0;
      C[o] = d0; C[o + 1] = d1; C[o + 2] = d2; C[o + 3] = d3;
    }
  } else {
    for (int idx = tid; idx < M * N; idx += NT) {
      int i = idx / N, j = idx - i * N;
      const double* a = A + (size_t)i * lda;
      double acc = 0.0;
      for (int k = 0; k < Kd; ++k) acc += a[k] * Bm[(size_t)k * ldb + j];
      C[(size_t)i * ldc + j] = acc;
    }
  }
  __syncthreads();
}

__device__ void mm_tn(const double* __restrict__ A, int lda, const double* __restrict__ Bm, int ldb,
                      double* __restrict__ C, int ldc, int M, int N, int Kd, int tid) {
  if ((N & 3) == 0) {
    int nstrip = N >> 2;
    for (int u = tid; u < M * nstrip; u += NT) {
      int i = u / nstrip, j0 = (u - i * nstrip) << 2;
      double d0 = 0, d1 = 0, d2 = 0, d3 = 0;
      for (int k = 0; k < Kd; ++k) {
        double av = A[(size_t)k * lda + i];
        const double* br = Bm + (size_t)k * ldb + j0;
        d0 += av * br[0]; d1 += av * br[1]; d2 += av * br[2]; d3 += av * br[3];
      }
      size_t o = (size_t)i * ldc + j0;
      C[o] = d0; C[o + 1] = d1; C[o + 2] = d2; C[o + 3] = d3;
    }
  } else {
    for (int idx = tid; idx < M * N; idx += NT) {
      int i = idx / N, j = idx - i * N;
      double acc = 0.0;
      for (int k = 0; k < Kd; ++k) acc += A[(size_t)k * lda + i] * Bm[(size_t)k * ldb + j];
      C[(size_t)i * ldc + j] = acc;
    }
  }
  __syncthreads();
}

__device__ void mm_nt(const double* __restrict__ A, int lda, const double* __restrict__ Bm, int ldb,
                      double* __restrict__ C, int ldc, int M, int N, int Kd, int tid) {
  for (int idx = tid; idx < M * N; idx += NT) {
    int i = idx / N, j = idx - i * N;
    double acc = 0.0;
    for (int k = 0; k < Kd; ++k) acc += A[(size_t)i * lda + k] * Bm[(size_t)j * ldb + k];
    C[(size_t)i * ldc + j] = acc;
  }
  __syncthreads();
}

// ---------------- LDS-staged matmuls ----------------
// C(M x N) = A(M x Kd) * B(Kd x N). B staged in 64-col LDS panels; 2x4 reg tiles.
__device__ void mm_nn_bs(const double* __restrict__ A, int lda,
                         const double* __restrict__ Bm, int ldb,
                         double* __restrict__ C, int ldc,
                         int M, int N, int Kd, char* lp, int tid) {
  double* SB = (double*)lp;
  for (int n0 = 0; n0 < N; n0 += 64) {
    int nb = N - n0; if (nb > 64) nb = 64;
    for (int x = tid; x < Kd * nb; x += NT) {
      int k = x / nb, j = x - k * nb;
      SB[x] = Bm[(size_t)k * ldb + n0 + j];
    }
    __syncthreads();
    int nstrip = nb >> 2;
    int items = (M >> 1) * nstrip;
    for (int u = tid; u < items; u += NT) {
      int iq = u / nstrip;
      int i = iq << 1;
      int jl = (u - iq * nstrip) << 2;
      const double* a0 = A + (size_t)i * lda;
      const double* a1 = a0 + lda;
      double c00 = 0, c01 = 0, c02 = 0, c03 = 0;
      double c10 = 0, c11 = 0, c12 = 0, c13 = 0;
      for (int k = 0; k < Kd; ++k) {
        double av0 = a0[k], av1 = a1[k];
        const double* bp = SB + k * nb + jl;
        double b0 = bp[0], b1 = bp[1], b2 = bp[2], b3 = bp[3];
        c00 += av0 * b0; c01 += av0 * b1; c02 += av0 * b2; c03 += av0 * b3;
        c10 += av1 * b0; c11 += av1 * b1; c12 += av1 * b2; c13 += av1 * b3;
      }
      size_t o0 = (size_t)i * ldc + n0 + jl, o1 = o0 + ldc;
      C[o0] = c00; C[o0 + 1] = c01; C[o0 + 2] = c02; C[o0 + 3] = c03;
      C[o1] = c10; C[o1 + 1] = c11; C[o1 + 2] = c12; C[o1 + 3] = c13;
    }
    __syncthreads();
  }
}

// G (n x n, upper valid) = A^T A ; A (Kd x n). A k-panels staged in LDS.
__device__ void gram_s(const double* __restrict__ A, int lda, int n, int Kd,
                       double* __restrict__ G, char* lp, int tid) {
  double* P = (double*)lp;
  int KC = (STAGE_CAP / 8) / n; if (KC > Kd) KC = Kd;
  for (int idx = tid; idx < n * n; idx += NT) {
    int i = idx / n, j = idx - i * n;
    if (j >= i) G[idx] = 0.0;
  }
  __syncthreads();
  for (int k0 = 0; k0 < Kd; k0 += KC) {
    int kc = Kd - k0; if (kc > KC) kc = KC;
    for (int x = tid; x < kc * n; x += NT) {
      int kk = x / n, i = x - kk * n;
      P[x] = A[(size_t)(k0 + kk) * lda + i];
    }
    __syncthreads();
    for (int idx = tid; idx < n * n; idx += NT) {
      int i = idx / n, j = idx - i * n;
      if (j < i) continue;
      double s = 0.0;
      for (int kk = 0; kk < kc; ++kk) s += P[kk * n + i] * P[kk * n + j];
      G[idx] += s;
    }
    __syncthreads();
  }
}

// ---------------- Cholesky (fp64, in-place upper R, G = R^T R) ----------------
__device__ void cholesky(double* G, int n, int tid) {
  for (int j = 0; j < n; ++j) {
    __syncthreads();
    double piv = G[(size_t)j * n + j];
    double r = sqrt(piv > 1e-300 ? piv : 1e-300);
    double inv = 1.0 / r;
    __syncthreads();
    for (int i = j + tid; i < n; i += NT)
      G[(size_t)j * n + i] = (i == j) ? r : G[(size_t)j * n + i] * inv;
    __syncthreads();
    int w = n - j - 1;
    for (int idx = tid; idx < w * w; idx += NT) {
      int ii = idx / w, kk = idx - ii * w;
      int i = j + 1 + ii, k2 = j + 1 + kk;
      if (k2 >= i) G[(size_t)i * n + k2] -= G[(size_t)j * n + i] * G[(size_t)j * n + k2];
    }
  }
  __syncthreads();
}

// T = R^{-1} (upper), fp64 dense (lower zeroed)
__device__ void trinv(const double* G, int n, double* T, int tid) {
  for (int c = tid; c < n; c += NT) {
    T[(size_t)c * n + c] = 1.0 / G[(size_t)c * n + c];
    for (int r = c - 1; r >= 0; --r) {
      double s = 0.0;
      for (int k = r + 1; k <= c; ++k) s += G[(size_t)r * n + k] * T[(size_t)k * n + c];
      T[(size_t)r * n + c] = -s / G[(size_t)r * n + r];
    }
    for (int r = c + 1; r < n; ++r) T[(size_t)r * n + c] = 0.0;
  }
  __syncthreads();
}

__device__ void copyR(const double* G, int n, double* Rw, int tid) {
  for (int idx = tid; idx < n * n; idx += NT) {
    int i = idx / n, k = idx - i * n;
    Rw[idx] = (k >= i) ? G[idx] : 0.0;
  }
  __syncthreads();
}

// tall CholQR: A (Mr x Nc), Mr >= Nc
__device__ void tallQR(const double* A, int Mr, int Nc, double* Q, double* Rw,
                       double* G, double* T, char* lp, int tid) {
  if (Mr >= 128) gram_s(A, Nc, Nc, Mr, G, lp, tid);
  else           mm_tn(A, Nc, A, Nc, G, Nc, Nc, Nc, Mr, tid);
  cholesky(G, Nc, tid);
  trinv(G, Nc, T, tid);
  if (Q) {
    if (Nc >= 64) mm_nn_bs(A, Nc, T, Nc, Q, Nc, Mr, Nc, Nc, lp, tid);
    else          mm_nn(A, Nc, T, Nc, Q, Nc, Mr, Nc, Nc, tid);
  }
  if (Rw) copyR(G, Nc, Rw, tid);
}

// wide QR (Mr < Nc): QR of first Mr cols, Rw = Q^T A (Mr x Nc)
__device__ void wideQR(const double* A, int Mr, int Nc, double* Q, double* Rw,
                       double* G, double* T, int tid) {
  mm_tn(A, Nc, A, Nc, G, Mr, Mr, Mr, Mr, tid);
  cholesky(G, Mr, tid);
  trinv(G, Mr, T, tid);
  mm_nn(A, Nc, T, Mr, Q, Mr, Mr, Mr, Mr, tid);
  mm_tn(Q, Mr, A, Nc, Rw, Nc, Mr, Nc, Mr, tid);
}

// ---------------- double-tensor build (fp64) ----------------
__device__ void build_D(const double* __restrict__ cand, int cl, int cr,
                        const double* __restrict__ rowS, int al, int ar,
                        double* __restrict__ D, int tid) {
  int mnext = cr * ar;
  int ncols = 6 * mnext;
  int n = cl * al * ncols;
  for (int idx = tid; idx < n; idx += NT) {
    int row = idx / ncols, col = idx - row * ncols;
    int l = row / al, L = row - l * al;
    int d = col / mnext, rem = col - d * mnext;
    int rr = rem / ar, R_ = rem - rr * ar;
    double acc = 0.0;
#pragma unroll
    for (int mu = 0; mu < 6; ++mu)
      acc += cand[(l * 6 + mu) * cr + rr] * rowS[((L * 6 + mu) * 6 + d) * ar + R_];
    D[idx] = acc;
  }
  __syncthreads();
}

// gather a physical row r into ROW buffer (fp64); dd = down-dim
__device__ void gather_row(const int* cfg, const float* tens, int b, int r, int dd,
                           double* ROW, const int* roff, int tid) {
  for (int j = 0; j < 6; ++j) {
    int al = (j == 0) ? 1 : 6, ar = (j == 5) ? 1 : 6;
    const float* base = tens + (size_t)(((r * 6 + j) * 2 + cfg[b * 36 + r * 6 + j])) * 1296;
    int n = al * 6 * dd * ar;
    double* dst = ROW + roff[j];
    for (int idx = tid; idx < n; idx += NT) {
      int R_ = idx % ar; int t2 = idx / ar;
      int d = t2 % dd; t2 /= dd;
      int mu = t2 % 6; int L = t2 / 6;
      dst[idx] = (double)base[L * 216 + mu * 36 + d * 6 + R_];
    }
  }
  __syncthreads();
}

// ---------------- f32 one-sided Jacobi (coarse subspace finder) ----------------
// 16 threads/pair (reduction order changed vs r8 — safe: refine corrects coarse noise)
__device__ void jacobi36(float* B, int R, float* J, int* flag, int tid) {
  for (int i = tid; i < 36 * 36; i += NT) J[i] = ((i / 36) == (i % 36)) ? 1.f : 0.f;
  __syncthreads();
  for (int sw = 0; sw < 9; ++sw) {
    if (tid == 0) *flag = 0;
    __syncthreads();
    for (int t = 0; t < 35; ++t) {
      int s = tid >> 4, h = tid & 15;
      bool act = (tid < 288);
      int p = 0, q = 0; float c = 1.f, sn = 0.f; bool doit = false;
      if (act) {
        if (s == 0) { p = 35; q = t % 35; }
        else { p = (t + s) % 35; q = (t - s + 35) % 35; }
        float app = 0.f, aqq = 0.f, apq = 0.f;
        for (int r = h; r < R; r += 16) {
          float x = B[r * 36 + p], y = B[r * 36 + q];
          app += x * x; aqq += y * y; apq += x * y;
        }
        app += __shfl_xor(app, 1); aqq += __shfl_xor(aqq, 1); apq += __shfl_xor(apq, 1);
        app += __shfl_xor(app, 2); aqq += __shfl_xor(aqq, 2); apq += __shfl_xor(apq, 2);
        app += __shfl_xor(app, 4); aqq += __shfl_xor(aqq, 4); apq += __shfl_xor(apq, 4);
        app += __shfl_xor(app, 8); aqq += __shfl_xor(aqq, 8); apq += __shfl_xor(apq, 8);
        double g = (double)apq, aa = (double)app, bb = (double)aqq;
        if (g * g > 1e-14 * aa * bb) {
          doit = true;
          if (h == 0) *flag = 1;
          double tau = (bb - aa) / (2.0 * g);
          double tt = (tau >= 0.0 ? 1.0 : -1.0) / (fabs(tau) + sqrt(1.0 + tau * tau));
          double cc = 1.0 / sqrt(1.0 + tt * tt);
          c = (float)cc; sn = (float)(tt * cc);
        }
      }
      if (doit) {
        for (int r = h; r < R; r += 16) {
          float x = B[r * 36 + p], y = B[r * 36 + q];
          B[r * 36 + p] = c * x - sn * y;
          B[r * 36 + q] = sn * x + c * y;
        }
        for (int r = h; r < 36; r += 16) {
          float x = J[r * 36 + p], y = J[r * 36 + q];
          J[r * 36 + p] = c * x - sn * y;
          J[r * 36 + q] = sn * x + c * y;
        }
      }
      __syncthreads();
    }
    int f = *flag;
    __syncthreads();
    if (!f) break;
  }
}

// 8 threads/pair, 18 rows per thread in registers
__device__ void jacobi144(float* B, int* flag, int tid) {
  for (int sw = 0; sw < 9; ++sw) {
    if (tid == 0) *flag = 0;
    __syncthreads();
    for (int t = 0; t < 143; ++t) {
      int s = tid >> 3, h = tid & 7;
      bool act = (tid < 576);
      float xp[18], xq[18];
      int p = 0, q = 0; float c = 1.f, sn = 0.f; bool doit = false;
      if (act) {
        if (s == 0) { p = 143; q = t % 143; }
        else { p = (t + s) % 143; q = (t - s + 143) % 143; }
        float app = 0.f, aqq = 0.f, apq = 0.f;
#pragma unroll
        for (int i = 0; i < 18; ++i) {
          int r = h + 8 * i;
          float x = B[r * 144 + p], y = B[r * 144 + q];
          xp[i] = x; xq[i] = y;
          app += x * x; aqq += y * y; apq += x * y;
        }
        app += __shfl_xor(app, 1); aqq += __shfl_xor(aqq, 1); apq += __shfl_xor(apq, 1);
        app += __shfl_xor(app, 2); aqq += __shfl_xor(aqq, 2); apq += __shfl_xor(apq, 2);
        app += __shfl_xor(app, 4); aqq += __shfl_xor(aqq, 4); apq += __shfl_xor(apq, 4);
        double g = (double)apq, aa = (double)app, bb = (double)aqq;
        if (g * g > 1e-14 * aa * bb) {
          doit = true;
          if (h == 0) *flag = 1;
          double tau = (bb - aa) / (2.0 * g);
          double tt = (tau >= 0.0 ? 1.0 : -1.0) / (fabs(tau) + sqrt(1.0 + tau * tau));
          double cc = 1.0 / sqrt(1.0 + tt * tt);
          c = (float)cc; sn = (float)(tt * cc);
        }
      }
      if (doit) {
#pragma unroll
        for (int i = 0; i < 18; ++i) {
          int r = h + 8 * i;
          B[r * 144 + p] = c * xp[i] - sn * xq[i];
          B[r * 144 + q] = sn * xp[i] + c * xq[i];
        }
      }
      __syncthreads();
    }
    int f = *flag;
    __syncthreads();
    if (!f) break;
  }
}

// column norms (f32 B) + top-`keep` selection
__device__ void colnorms_sel(const float* B, int R, int C, int keep, char* lp, int tid) {
  double* NORM = L_NORM(lp); int* SEL = L_SEL(lp); double* S = L_S(lp);
  for (int c = tid; c < C; c += NT) {
    double a = 0.0;
    for (int r = 0; r < R; ++r) { float v = B[r * C + c]; a += (double)v * (double)v; }
    NORM[c] = a;
  }
  __syncthreads();
  if (tid == 0) {
    for (int i = 0; i < keep; ++i) {
      int bi = 0; double bv = -1.0;
      for (int x = 0; x < C; ++x) if (NORM[x] > bv) { bv = NORM[x]; bi = x; }
      SEL[i] = bi;
      S[i] = sqrt(bv > 1e-300 ? bv : 1e-300);
      NORM[bi] = -2.0;
    }
  }
  __syncthreads();
}

// ---------------- fp64 refinement ----------------
// 16 threads/pair
__device__ void jacobi24d(double* Z, int R, double* J24, int* flag, int tid) {
  for (int i = tid; i < 576; i += NT) J24[i] = ((i / 24) == (i % 24)) ? 1.0 : 0.0;
  __syncthreads();
  for (int sw = 0; sw < 16; ++sw) {
    if (tid == 0) *flag = 0;
    __syncthreads();
    for (int t = 0; t < 23; ++t) {
      int s = tid >> 4, h = tid & 15;
      bool act = (tid < 192);
      int p = 0, q = 0; double c_ = 1.0, sn = 0.0; bool doit = false;
      if (act) {
        if (s == 0) { p = 23; q = t % 23; }
        else { p = (t + s) % 23; q = (t - s + 23) % 23; }
        double app = 0, aqq = 0, apq = 0;
        for (int r = h; r < R; r += 16) {
          double x = Z[r * 24 + p], y = Z[r * 24 + q];
          app += x * x; aqq += y * y; apq += x * y;
        }
        app += __shfl_xor(app, 1); aqq += __shfl_xor(aqq, 1); apq += __shfl_xor(apq, 1);
        app += __shfl_xor(app, 2); aqq += __shfl_xor(aqq, 2); apq += __shfl_xor(apq, 2);
        app += __shfl_xor(app, 4); aqq += __shfl_xor(aqq, 4); apq += __shfl_xor(apq, 4);
        app += __shfl_xor(app, 8); aqq += __shfl_xor(aqq, 8); apq += __shfl_xor(apq, 8);
        if (apq * apq > 1e-28 * app * aqq) {
          doit = true;
          if (h == 0) *flag = 1;
          double tau = (aqq - app) / (2.0 * apq);
          double tt = (tau >= 0.0 ? 1.0 : -1.0) / (fabs(tau) + sqrt(1.0 + tau * tau));
          double cc = 1.0 / sqrt(1.0 + tt * tt);
          c_ = cc; sn = tt * cc;
        }
      }
      if (doit) {
        for (int r = h; r < R; r += 16) {
          double x = Z[r * 24 + p], y = Z[r * 24 + q];
          Z[r * 24 + p] = c_ * x - sn * y;
          Z[r * 24 + q] = sn * x + c_ * y;
        }
        for (int r = h; r < 24; r += 16) {
          double x = J24[r * 24 + p], y = J24[r * 24 + q];
          J24[r * 24 + p] = c_ * x - sn * y;
          J24[r * 24 + q] = sn * x + c_ * y;
        }
      }
      __syncthreads();
    }
    int f = *flag;
    __syncthreads();
    if (!f) break;
  }
}

__device__ void sort24(const double* Z, int R, char* lp, int tid) {
  double* NORM = L_NORM(lp); int* SEL = L_SEL(lp); double* S = L_S(lp);
  for (int c = tid; c < 24; c += NT) {
    double a = 0.0;
    for (int r = 0; r < R; ++r) { double v = Z[r * 24 + c]; a += v * v; }
    NORM[c] = a;
  }
  __syncthreads();
  if (tid == 0) {
    for (int i = 0; i < 24; ++i) {
      int bi = 0; double bv = -1.0;
      for (int x = 0; x < 24; ++x) if (NORM[x] > bv) { bv = NORM[x]; bi = x; }
      SEL[i] = bi;
      S[i] = sqrt(bv > 1e-300 ? bv : 1e-300);
      NORM[bi] = -2.0;
    }
  }
  __syncthreads();
}

// Rayleigh-Ritz refinement (see round-7 comments)
__device__ void refine(const double* t, int tR, int tC, int My, int ucase,
                       double* site, double* X, double* Dd, char* lp, int tid) {
  double* G = Dd + M_G;   double* T24 = Dd + M_T;
  double* Y0 = Dd + M_Y0; double* YH = Dd + M_YH;
  double* W = Dd + M_W;   double* P = Dd + M_P;
  double* Zr = L_ZR(lp);  double* J24 = L_J24(lp);
  int Rz = ucase ? tC : tR;
  mm_tn(Y0, 24, Y0, 24, G, 24, 24, 24, My, tid);
  cholesky(G, 24, tid);
  trinv(G, 24, T24, tid);
  mm_nn(Y0, 24, T24, 24, YH, 24, My, 24, 24, tid);
  if (ucase) mm_tn(t, tC, YH, 24, Zr, 24, tC, 24, tR, tid);
  else       mm_nn(t, tC, YH, 24, Zr, 24, tR, 24, tC, tid);
  jacobi24d(Zr, Rz, J24, L_FLAG(lp), tid);
  sort24(Zr, Rz, lp, tid);
  int* SEL = L_SEL(lp); double* S = L_S(lp);
  for (int i = tid; i < 576; i += NT) {
    int k = i / 24, c = i - k * 24;
    W[i] = J24[k * 24 + SEL[c]];
  }
  __syncthreads();
  mm_nn(YH, 24, W, 24, P, 24, My, 24, 24, tid);
  if (ucase) {
    for (int i = tid; i < My * 24; i += NT) {
      int k = i / 24, c = i - k * 24;
      X[i] = P[i] * S[c];
    }
    for (int i = tid; i < 24 * tC; i += NT) {
      int c = i / tC, x = i - c * tC;
      site[i] = Zr[x * 24 + SEL[c]] / S[c];
    }
  } else {
    for (int i = tid; i < 24 * My; i += NT) {
      int c = i / My, x = i - c * My;
      site[i] = P[x * 24 + c];
    }
    for (int i = tid; i < Rz * 24; i += NT) {
      int k = i / 24, c = i - k * 24;
      X[i] = Zr[k * 24 + SEL[c]];
    }
  }
  __syncthreads();
}

// SVD of t (R x 36), keep 24
__device__ void svdV36d(const double* t, int R, double* site, double* X,
                        double* Dd, char* lp, int tid) {
  float* B = L_B(lp); float* J = L_J(lp);
  for (int i = tid; i < R * 36; i += NT) B[i] = (float)t[i];
  __syncthreads();
  jacobi36(B, R, J, L_FLAG(lp), tid);
  colnorms_sel(B, R, 36, 24, lp, tid);
  int* SEL = L_SEL(lp);
  double* Y0 = Dd + M_Y0;
  for (int i = tid; i < 36 * 24; i += NT) {
    int x = i / 24, c = i - x * 24;
    Y0[i] = (double)J[x * 36 + SEL[c]];
  }
  __syncthreads();
  refine(t, R, 36, 36, 0, site, X, Dd, lp, tid);
}

// SVD of t (36 x 144), keep 24
__device__ void svdU36d(const double* t, double* site, double* X,
                        double* Dd, char* lp, int tid) {
  float* B = L_B(lp); float* J = L_J(lp);
  for (int i = tid; i < 144 * 36; i += NT) {
    int x = i / 36, k = i - x * 36;
    B[i] = (float)t[k * 144 + x];
  }
  __syncthreads();
  jacobi36(B, 144, J, L_FLAG(lp), tid);
  colnorms_sel(B, 144, 36, 24, lp, tid);
  int* SEL = L_SEL(lp);
  double* Y0 = Dd + M_Y0;
  for (int i = tid; i < 36 * 24; i += NT) {
    int x = i / 24, c = i - x * 24;
    Y0[i] = (double)J[x * 36 + SEL[c]];
  }
  __syncthreads();
  refine(t, 36, 144, 36, 1, site, X, Dd, lp, tid);
}

// SVD of t (144 x 144), keep 24
__device__ void stepJ3bigd(const double* t, double* site, double* X,
                           double* Dd, char* lp, int tid) {
  float* B = L_B(lp);
  for (int i = tid; i < 144 * 144; i += NT) B[i] = (float)t[i];
  __syncthreads();
  jacobi144(B, L_FLAG(lp), tid);
  colnorms_sel(B, 144, 144, 24, lp, tid);
  int* SEL = L_SEL(lp);
  double* Y0 = Dd + M_Y0;
  for (int i = tid; i < 144 * 24; i += NT) {
    int k = i / 24, c = i - k * 24;
    Y0[i] = (double)B[k * 144 + SEL[c]];
  }
  __syncthreads();
  refine(t, 144, 144, 144, 1, site, X, Dd, lp, tid);
}

// LQ of t5 (36x6)
__device__ void stepJ5(const double* t5, double* G, double* T, double* Qp,
                       double* cand5, double* X5, int tid) {
  mm_nt(t5, 6, t5, 6, G, 6, 6, 6, 6, tid);
  cholesky(G, 6, tid);
  trinv(G, 6, T, tid);
  mm_tn(t5, 6, T, 6, Qp, 6, 6, 6, 6, tid);
  for (int i = tid; i < 36; i += NT) {
    int l = i / 6, mu = i - l * 6;
    cand5[i] = Qp[mu * 6 + l];
  }
  __syncthreads();
  mm_nn(t5, 6, Qp, 6, X5, 6, 36, 6, 6, tid);
}

// LQ of t1 (6x144)
__device__ void stepJ1(const double* t1, double* G, double* T,
                       double* cand1, double* X1, int tid) {
  mm_nt(t1, 144, t1, 144, G, 6, 6, 6, 144, tid);
  cholesky(G, 6, tid);
  trinv(G, 6, T, tid);
  mm_tn(T, 6, t1, 144, cand1, 144, 6, 144, 6, tid);
  for (int i = tid; i < 36; i += NT) {
    int r = i / 6, c = i - r * 6;
    X1[i] = (c <= r) ? G[c * 6 + r] : 0.0;
  }
  __syncthreads();
}

__device__ void rescale0(double* cout_, char* lp, int tid) {
  if (tid == 0) {
    double m = 0.0;
    for (int i = 0; i < 36; ++i) { double v = fabs(cout_[i]); if (v > m) m = v; }
    if (!(m > 1e-300)) m = 1.0;
    *L_SCALE(lp) = m;
    *L_LOG(lp) += log(m);
  }
  __syncthreads();
  double m = *L_SCALE(lp);
  for (int i = tid; i < 36; i += NT) cout_[i] /= m;
  __syncthreads();
}

// ---------------- one _bmps round (truncating compress to DC=24) ----------------
__device__ void run_round(int r, int b, const int* cfg, const float* tens,
                          const double* cin_, double* cout_, int tid) {
  char* lp = ldsp();
  double* Dd = g_m + (size_t)b * M_STRIDE;
  const int K  = (r == 1) ? 36 : 144;
  const int cK = (r == 1) ? 6 : 24;
  int cb[7] = {1, 6, cK, cK, cK, 6, 1};
  int co[6]; co[0] = 0;
  for (int j = 0; j < 5; ++j) co[j + 1] = co[j] + cb[j] * 6 * cb[j + 1];
  const int ob[7] = {1, 6, 24, 24, 24, 6, 1};
  int oo[6]; oo[0] = 0;
  for (int j = 0; j < 5; ++j) oo[j + 1] = oo[j] + ob[j] * 6 * ob[j + 1];
  const int roff6[6] = {0, 216, 1512, 2808, 4104, 5400};

  double* ROW = Dd + M_ROW;
  double* Dbuf = Dd + M_D;  double* Abuf = Dd + M_A;  double* A3 = Dd + M_A3;
  double* Q2 = Dd + M_Q2;   double* Q4 = Dd + M_Q4;   double* Q1 = Dd + M_Q1;  double* Q0 = Dd + M_Q0;
  double* TB = Dd + M_TB;   double* Rw = Dd + M_R;    double* Tw = Dd + M_T;   double* T3 = Dd + M_T3;
  double* G = Dd + M_G;     double* X = Dd + M_X;     double* Zp = Dd + M_Z;
  double* t5 = Dd + M_T5;   double* X5 = Dd + M_X5;   double* Qp = Dd + M_QP;
  double* X1 = Dd + M_X1;   double* t1 = Dd + M_T1;

  gather_row(cfg, tens, b, r, 6, ROW, roff6, tid);

  // ---- QR sweep (left-canonicalize) ----
  build_D(cin_ + co[0], 1, cb[1], ROW + roff6[0], 1, 6, Dbuf, tid);
  wideQR(Dbuf, 6, 36, Q0, Rw, G, Tw, tid);

  build_D(cin_ + co[1], 6, cb[2], ROW + roff6[1], 6, 6, Dbuf, tid);
  mm_nn(Rw, 36, Dbuf, 6 * K, Abuf, 6 * K, 6, 6 * K, 36, tid);
  if (K == 36) tallQR(Abuf, 36, 36, Q1, Rw, G, Tw, lp, tid);
  else         wideQR(Abuf, 36, 144, Q1, Rw, G, Tw, tid);

  build_D(cin_ + co[2], cb[2], cb[3], ROW + roff6[2], 6, 6, Dbuf, tid);
  mm_nn_bs(Rw, K, Dbuf, 6 * K, Abuf, 6 * K, 36, 6 * K, K, lp, tid);
  tallQR(Abuf, 216, K, Q2, Rw, G, Tw, lp, tid);

  build_D(cin_ + co[3], cb[3], cb[4], ROW + roff6[3], 6, 6, Dbuf, tid);
  mm_nn_bs(Rw, K, Dbuf, 6 * K, A3, 6 * K, K, 6 * K, K, lp, tid);
  tallQR(A3, 6 * K, K, nullptr, Rw, G, T3, lp, tid);

  build_D(cin_ + co[4], cb[4], cb[5], ROW + roff6[4], 6, 6, Dbuf, tid);
  mm_nn_bs(Rw, K, Dbuf, 216, Abuf, 216, K, 216, K, lp, tid);
  tallQR(Abuf, 6 * K, 36, Q4, Rw, G, Tw, lp, tid);

  build_D(cin_ + co[5], cb[5], 1, ROW + roff6[5], 6, 1, Dbuf, tid);
  mm_nn(Rw, 36, Dbuf, 6, t5, 6, 36, 6, 36, tid);

  // ---- SVD sweep (right-to-left, truncate at j=4,3,2) ----
  stepJ5(t5, G, Tw, Qp, cout_ + oo[5], X5, tid);
  mm_nn(Q4, 36, X5, 6, TB, 6, 6 * K, 6, 36, tid);                 // t4 (K x 36)
  svdV36d(TB, K, cout_ + oo[4], X, Dd, lp, tid);                  // X (K x 24)
  mm_nn_bs(T3, K, X, 24, Zp, 24, K, 24, K, lp, tid);              // Z = T3 X4
  mm_nn_bs(A3, K, Zp, 24, TB, 24, 6 * K, 24, K, lp, tid);         // t3 (K x 144)
  if (K == 144) stepJ3bigd(TB, cout_ + oo[3], X, Dd, lp, tid);
  else          svdU36d(TB, cout_ + oo[3], X, Dd, lp, tid);       // X (K x 24)
  mm_nn_bs(Q2, K, X, 24, TB, 24, 216, 24, K, lp, tid);            // t2 (36 x 144)
  svdU36d(TB, cout_ + oo[2], X, Dd, lp, tid);                     // X (36 x 24)
  mm_nn(Q1, 36, X, 24, t1, 24, 36, 24, 36, tid);                  // t1 (6 x 144)
  stepJ1(t1, G, Tw, cout_ + oo[1], X1, tid);
  mm_nn(Q0, 6, X1, 6, cout_ + oo[0], 6, 6, 6, 6, tid);            // site0
  rescale0(cout_, lp, tid);
}

// ---------------- kernel ----------------
extern "C" __global__ void __launch_bounds__(NT, 4)
peps_kernel(const int* __restrict__ cfg, const float* __restrict__ tens, float* __restrict__ out) {
  const int b = blockIdx.x;
  const int tid = threadIdx.x;
  char* lp = ldsp();
  double* CA = g_m + (size_t)b * M_STRIDE + M_CA;
  double* CB = g_m + (size_t)b * M_STRIDE + M_CB;
  if (tid == 0) *L_LOG(lp) = 0.0;

  // init cand = row 0 (bonds 1,6,6,6,6,6,1 ; up=0)
  {
    const int c1off[6] = {0, 36, 252, 468, 684, 900};
    for (int j = 0; j < 6; ++j) {
      int al = (j == 0) ? 1 : 6, ar = (j == 5) ? 1 : 6;
      const float* base = tens + (size_t)((j * 2 + cfg[b * 36 + j])) * 1296;
      int n = al * 6 * ar;
      double* dst = CA + c1off[j];
      for (int idx = tid; idx < n; idx += NT) {
        int l = idx / (6 * ar); int rest = idx - l * (6 * ar);
        int mu = rest / ar; int rr = rest - mu * ar;
        dst[idx] = (double)base[l * 216 + mu * 6 + rr];
      }
    }
    __syncthreads();
  }

  run_round(1, b, cfg, tens, CA, CB, tid);
  run_round(2, b, cfg, tens, CB, CA, tid);
  run_round(3, b, cfg, tens, CA, CB, tid);
  run_round(4, b, cfg, tens, CB, CA, tid);

  // final exact contraction of cand (in CA) with row 5 (down dim = 1)
  {
    const int roff1[6] = {0, 36, 252, 468, 684, 900};
    double* ROW = g_m + (size_t)b * M_STRIDE + M_ROW;
    gather_row(cfg, tens, b, 5, 1, ROW, roff1, tid);
    double* E = L_E(lp); double* E2 = L_E2(lp);
    if (tid == 0) E[0] = 1.0;
    __syncthreads();
    const int ob[7] = {1, 6, 24, 24, 24, 6, 1};
    int oo[6]; oo[0] = 0;
    for (int j = 0; j < 5; ++j) oo[j + 1] = oo[j] + ob[j] * 6 * ob[j + 1];
    const double* candF = CA;
    double* src = E; double* dst = E2;
    for (int j = 0; j < 6; ++j) {
      int cl = ob[j], cr = ob[j + 1];
      int al = (j == 0) ? 1 : 6, ar = (j == 5) ? 1 : 6;
      int n = cr * ar;
      for (int idx = tid; idx < n; idx += NT) {
        int rr = idx / ar, R_ = idx - rr * ar;
        double acc = 0.0;
        for (int l = 0; l < cl; ++l) {
          for (int L = 0; L < al; ++L) {
            double e = src[l * al + L];
            double s2 = 0.0;
#pragma unroll
            for (int mu = 0; mu < 6; ++mu)
              s2 += candF[oo[j] + (l * 6 + mu) * cr + rr] * ROW[roff1[j] + (L * 6 + mu) * ar + R_];
            acc += e * s2;
          }
        }
        dst[idx] = acc;
      }
      __syncthreads();
      double* tmp = src; src = dst; dst = tmp;
    }
    if (tid == 0) out[b] = (float)(src[0] * exp(*L_LOG(lp)));
  }
}

// ---------------- launch ----------------
extern "C" void kernel_launch(void* const* d_in, const int* in_sizes, int n_in,
                              void* d_out, int out_size, void* d_ws, size_t ws_size,
                              hipStream_t stream) {
  (void)in_sizes; (void)n_in; (void)out_size; (void)d_ws; (void)ws_size;
  const int* cfg = (const int*)d_in[0];
  const float* tens = (const float*)d_in[1];
  float* out = (float*)d_out;
  (void)hipFuncSetAttribute((const void*)peps_kernel,
                            hipFuncAttributeMaxDynamicSharedMemorySize, LDS_BYTES);
  peps_kernel<<<dim3(NB), dim3(NT), LDS_BYTES, stream>>>(cfg, tens, out);
}

// Round 10
// 35006.345 us; speedup vs baseline: 1.8440x; 1.1713x over previous
//
#include <hip/hip_runtime.h>
#include <math.h>

#define NT 1024
#define NB 32

// ---------------- unified fp64 arena (per-batch, element offsets) ----------------
#define M_D    0        // 124416 : double-tensor D_j (max 144 x 864)
#define M_A    124416   // 124416 : A1/A2/A4
#define M_A3   248832   // 124416 : A3 (kept through round)
#define M_Q2   373248   // 31104  : Q2 (216 x K)
#define M_Q4   404352   // 31104  : Q4 (6K x 36)
#define M_TB   435456   // 20736  : t-matrix buffer (max 144x144)
#define M_Q1   456192   // 1296
#define M_Q0   457488   // 64
#define M_ROW  457552   // 5616   : gathered row tensors
#define M_R    463168   // 20736  : current R (dense)
#define M_T    483904   // 20736  : current T = R^-1 (also T24 in refine)
#define M_T3   504640   // 20736  : T3 kept
#define M_G    525392   // 20736  : Gram / chol workspace
#define M_CA   546128   // 8712   : cand buffer A
#define M_CB   554840   // 8712   : cand buffer B
#define M_X    563552   // 3456   : push factor X (max 144x24)
#define M_Z    567008   // 3456   : Z = T3*X4
#define M_T5   570464   // 216
#define M_X5   570680   // 216
#define M_QP   570896   // 64
#define M_X1   570960   // 64
#define M_T1   571024   // 864
#define M_Y0   571888   // 3456   : refine: approx subspace basis (My x 24)
#define M_YH   575344   // 3456   : refine: orthonormal basis
#define M_W    578800   // 576    : refine: sorted right-rotation
#define M_P    579376   // 3456   : refine: YH * W
#define M_STRIDE 582832

__device__ __align__(16) double g_m[(size_t)NB * M_STRIDE];

// ---------------- LDS layout (byte offsets) ----------------
// phase A (f32 Jacobi 36): B f32 stride36 [0, 20736), J f32 [82944, 88128)
// phase A'(f32 Jacobi 144): B f32 stride145 [0, 83520)   (J unused)
// phase B (fp64 refine): Zr fp64 stride25 [0, 28800), J24 fp64 [28800, 33408)
// phase C (staged mm): panels at [0, 82944)
#define STAGE_CAP 82944
#define LO_J     82944
#define LO_NORM  88128   // double[144]
#define LO_S     89280   // double[24]
#define LO_E     89472   // double[144]
#define LO_E2    90624   // double[144]
#define LO_SEL   91776   // int[24]
#define LO_FLAG  91872   // int
#define LO_LOG   91880   // double
#define LO_SCALE 91888   // double
#define LDS_BYTES 92160

__device__ __forceinline__ char* ldsp() {
  extern __shared__ char lds_pool[];
  return lds_pool;
}
#define L_B(p)     ((float*)(p))
#define L_J(p)     ((float*)((p)+LO_J))
#define L_ZR(p)    ((double*)(p))
#define L_J24(p)   ((double*)((p)+28800))
#define L_NORM(p)  ((double*)((p)+LO_NORM))
#define L_S(p)     ((double*)((p)+LO_S))
#define L_E(p)     ((double*)((p)+LO_E))
#define L_E2(p)    ((double*)((p)+LO_E2))
#define L_SEL(p)   ((int*)((p)+LO_SEL))
#define L_FLAG(p)  ((int*)((p)+LO_FLAG))
#define L_LOG(p)   ((double*)((p)+LO_LOG))
#define L_SCALE(p) ((double*)((p)+LO_SCALE))

// ---------------- fp64 matmuls (4-wide strip when N%4==0) ----------------
__device__ void mm_nn(const double* __restrict__ A, int lda, const double* __restrict__ Bm, int ldb,
                      double* __restrict__ C, int ldc, int M, int N, int Kd, int tid) {
  if ((N & 3) == 0) {
    int nstrip = N >> 2;
    for (int u = tid; u < M * nstrip; u += NT) {
      int i = u / nstrip, j0 = (u - i * nstrip) << 2;
      const double* a = A + (size_t)i * lda;
      const double* b = Bm + j0;
      double d0 = 0, d1 = 0, d2 = 0, d3 = 0;
      for (int k = 0; k < Kd; ++k) {
        double av = a[k];
        const double* br = b + (size_t)k * ldb;
        d0 += av * br[0]; d1 += av * br[1]; d2 += av * br[2]; d3 += av * br[3];
      }
      size_t o = (size_t)i * ldc + j0;
      C[o] = d0; C[o + 1] = d1; C[o + 2] = d2; C[o + 3] = d3;
    }
  } else {
    for (int idx = tid; idx < M * N; idx += NT) {
      int i = idx / N, j = idx - i * N;
      const double* a = A + (size_t)i * lda;
      double acc = 0.0;
      for (int k = 0; k < Kd; ++k) acc += a[k] * Bm[(size_t)k * ldb + j];
      C[(size_t)i * ldc + j] = acc;
    }
  }
  __syncthreads();
}

__device__ void mm_tn(const double* __restrict__ A, int lda, const double* __restrict__ Bm, int ldb,
                      double* __restrict__ C, int ldc, int M, int N, int Kd, int tid) {
  if ((N & 3) == 0) {
    int nstrip = N >> 2;
    for (int u = tid; u < M * nstrip; u += NT) {
      int i = u / nstrip, j0 = (u - i * nstrip) << 2;
      double d0 = 0, d1 = 0, d2 = 0, d3 = 0;
      for (int k = 0; k < Kd; ++k) {
        double av = A[(size_t)k * lda + i];
        const double* br = Bm + (size_t)k * ldb + j0;
        d0 += av * br[0]; d1 += av * br[1]; d2 += av * br[2]; d3 += av * br[3];
      }
      size_t o = (size_t)i * ldc + j0;
      C[o] = d0; C[o + 1] = d1; C[o + 2] = d2; C[o + 3] = d3;
    }
  } else {
    for (int idx = tid; idx < M * N; idx += NT) {
      int i = idx / N, j = idx - i * N;
      double acc = 0.0;
      for (int k = 0; k < Kd; ++k) acc += A[(size_t)k * lda + i] * Bm[(size_t)k * ldb + j];
      C[(size_t)i * ldc + j] = acc;
    }
  }
  __syncthreads();
}

__device__ void mm_nt(const double* __restrict__ A, int lda, const double* __restrict__ Bm, int ldb,
                      double* __restrict__ C, int ldc, int M, int N, int Kd, int tid) {
  for (int idx = tid; idx < M * N; idx += NT) {
    int i = idx / N, j = idx - i * N;
    double acc = 0.0;
    for (int k = 0; k < Kd; ++k) acc += A[(size_t)i * lda + k] * Bm[(size_t)j * ldb + k];
    C[(size_t)i * ldc + j] = acc;
  }
  __syncthreads();
}

// ---------------- LDS-staged matmuls ----------------
// C(M x N) = A(M x Kd) * B(Kd x N). B staged in 64-col LDS panels; 4x4 reg tiles.
// Requires M%4==0, N%4==0.
__device__ void mm_nn_bs(const double* __restrict__ A, int lda,
                         const double* __restrict__ Bm, int ldb,
                         double* __restrict__ C, int ldc,
                         int M, int N, int Kd, char* lp, int tid) {
  double* SB = (double*)lp;
  for (int n0 = 0; n0 < N; n0 += 64) {
    int nb = N - n0; if (nb > 64) nb = 64;
    for (int x = tid; x < Kd * nb; x += NT) {
      int k = x / nb, j = x - k * nb;
      SB[x] = Bm[(size_t)k * ldb + n0 + j];
    }
    __syncthreads();
    int nstrip = nb >> 2;
    int items = (M >> 2) * nstrip;
    for (int u = tid; u < items; u += NT) {
      int iq = u / nstrip;
      int i = iq << 2;
      int jl = (u - iq * nstrip) << 2;
      const double* a0 = A + (size_t)i * lda;
      const double* a1 = a0 + lda;
      const double* a2 = a1 + lda;
      const double* a3 = a2 + lda;
      double c00=0,c01=0,c02=0,c03=0, c10=0,c11=0,c12=0,c13=0;
      double c20=0,c21=0,c22=0,c23=0, c30=0,c31=0,c32=0,c33=0;
      for (int k = 0; k < Kd; ++k) {
        const double* bp = SB + k * nb + jl;
        double b0 = bp[0], b1 = bp[1], b2 = bp[2], b3 = bp[3];
        double av0 = a0[k], av1 = a1[k], av2 = a2[k], av3 = a3[k];
        c00 += av0*b0; c01 += av0*b1; c02 += av0*b2; c03 += av0*b3;
        c10 += av1*b0; c11 += av1*b1; c12 += av1*b2; c13 += av1*b3;
        c20 += av2*b0; c21 += av2*b1; c22 += av2*b2; c23 += av2*b3;
        c30 += av3*b0; c31 += av3*b1; c32 += av3*b2; c33 += av3*b3;
      }
      size_t o0 = (size_t)i * ldc + n0 + jl;
      size_t o1 = o0 + ldc, o2 = o1 + ldc, o3 = o2 + ldc;
      C[o0]=c00; C[o0+1]=c01; C[o0+2]=c02; C[o0+3]=c03;
      C[o1]=c10; C[o1+1]=c11; C[o1+2]=c12; C[o1+3]=c13;
      C[o2]=c20; C[o2+1]=c21; C[o2+2]=c22; C[o2+3]=c23;
      C[o3]=c30; C[o3+1]=c31; C[o3+2]=c32; C[o3+3]=c33;
    }
    __syncthreads();
  }
}

// G (n x n, upper valid) = A^T A ; A (Kd x n). A k-panels staged in LDS.
__device__ void gram_s(const double* __restrict__ A, int lda, int n, int Kd,
                       double* __restrict__ G, char* lp, int tid) {
  double* P = (double*)lp;
  int KC = (STAGE_CAP / 8) / n; if (KC > Kd) KC = Kd;
  for (int idx = tid; idx < n * n; idx += NT) {
    int i = idx / n, j = idx - i * n;
    if (j >= i) G[idx] = 0.0;
  }
  __syncthreads();
  for (int k0 = 0; k0 < Kd; k0 += KC) {
    int kc = Kd - k0; if (kc > KC) kc = KC;
    for (int x = tid; x < kc * n; x += NT) {
      int kk = x / n, i = x - kk * n;
      P[x] = A[(size_t)(k0 + kk) * lda + i];
    }
    __syncthreads();
    for (int idx = tid; idx < n * n; idx += NT) {
      int i = idx / n, j = idx - i * n;
      if (j < i) continue;
      double s = 0.0;
      for (int kk = 0; kk < kc; ++kk) s += P[kk * n + i] * P[kk * n + j];
      G[idx] += s;
    }
    __syncthreads();
  }
}

// ---------------- Cholesky (fp64, in-place upper R, G = R^T R) ----------------
__device__ void cholesky(double* G, int n, int tid) {
  for (int j = 0; j < n; ++j) {
    __syncthreads();
    double piv = G[(size_t)j * n + j];
    double r = sqrt(piv > 1e-300 ? piv : 1e-300);
    double inv = 1.0 / r;
    __syncthreads();
    for (int i = j + tid; i < n; i += NT)
      G[(size_t)j * n + i] = (i == j) ? r : G[(size_t)j * n + i] * inv;
    __syncthreads();
    int w = n - j - 1;
    for (int idx = tid; idx < w * w; idx += NT) {
      int ii = idx / w, kk = idx - ii * w;
      int i = j + 1 + ii, k2 = j + 1 + kk;
      if (k2 >= i) G[(size_t)i * n + k2] -= G[(size_t)j * n + i] * G[(size_t)j * n + k2];
    }
  }
  __syncthreads();
}

// T = R^{-1} (upper), fp64 dense (lower zeroed)
__device__ void trinv(const double* G, int n, double* T, int tid) {
  for (int c = tid; c < n; c += NT) {
    T[(size_t)c * n + c] = 1.0 / G[(size_t)c * n + c];
    for (int r = c - 1; r >= 0; --r) {
      double s = 0.0;
      for (int k = r + 1; k <= c; ++k) s += G[(size_t)r * n + k] * T[(size_t)k * n + c];
      T[(size_t)r * n + c] = -s / G[(size_t)r * n + r];
    }
    for (int r = c + 1; r < n; ++r) T[(size_t)r * n + c] = 0.0;
  }
  __syncthreads();
}

__device__ void copyR(const double* G, int n, double* Rw, int tid) {
  for (int idx = tid; idx < n * n; idx += NT) {
    int i = idx / n, k = idx - i * n;
    Rw[idx] = (k >= i) ? G[idx] : 0.0;
  }
  __syncthreads();
}

// tall CholQR: A (Mr x Nc), Mr >= Nc
__device__ void tallQR(const double* A, int Mr, int Nc, double* Q, double* Rw,
                       double* G, double* T, char* lp, int tid) {
  if (Mr >= 128) gram_s(A, Nc, Nc, Mr, G, lp, tid);
  else           mm_tn(A, Nc, A, Nc, G, Nc, Nc, Nc, Mr, tid);
  cholesky(G, Nc, tid);
  trinv(G, Nc, T, tid);
  if (Q) {
    if (Nc >= 64) mm_nn_bs(A, Nc, T, Nc, Q, Nc, Mr, Nc, Nc, lp, tid);
    else          mm_nn(A, Nc, T, Nc, Q, Nc, Mr, Nc, Nc, tid);
  }
  if (Rw) copyR(G, Nc, Rw, tid);
}

// wide QR (Mr < Nc): QR of first Mr cols, Rw = Q^T A (Mr x Nc)
__device__ void wideQR(const double* A, int Mr, int Nc, double* Q, double* Rw,
                       double* G, double* T, int tid) {
  mm_tn(A, Nc, A, Nc, G, Mr, Mr, Mr, Mr, tid);
  cholesky(G, Mr, tid);
  trinv(G, Mr, T, tid);
  mm_nn(A, Nc, T, Mr, Q, Mr, Mr, Mr, Mr, tid);
  mm_tn(Q, Mr, A, Nc, Rw, Nc, Mr, Nc, Mr, tid);
}

// ---------------- double-tensor build (fp64) ----------------
__device__ void build_D(const double* __restrict__ cand, int cl, int cr,
                        const double* __restrict__ rowS, int al, int ar,
                        double* __restrict__ D, int tid) {
  int mnext = cr * ar;
  int ncols = 6 * mnext;
  int n = cl * al * ncols;
  for (int idx = tid; idx < n; idx += NT) {
    int row = idx / ncols, col = idx - row * ncols;
    int l = row / al, L = row - l * al;
    int d = col / mnext, rem = col - d * mnext;
    int rr = rem / ar, R_ = rem - rr * ar;
    double acc = 0.0;
#pragma unroll
    for (int mu = 0; mu < 6; ++mu)
      acc += cand[(l * 6 + mu) * cr + rr] * rowS[((L * 6 + mu) * 6 + d) * ar + R_];
    D[idx] = acc;
  }
  __syncthreads();
}

// gather a physical row r into ROW buffer (fp64); dd = down-dim
__device__ void gather_row(const int* cfg, const float* tens, int b, int r, int dd,
                           double* ROW, const int* roff, int tid) {
  for (int j = 0; j < 6; ++j) {
    int al = (j == 0) ? 1 : 6, ar = (j == 5) ? 1 : 6;
    const float* base = tens + (size_t)(((r * 6 + j) * 2 + cfg[b * 36 + r * 6 + j])) * 1296;
    int n = al * 6 * dd * ar;
    double* dst = ROW + roff[j];
    for (int idx = tid; idx < n; idx += NT) {
      int R_ = idx % ar; int t2 = idx / ar;
      int d = t2 % dd; t2 /= dd;
      int mu = t2 % 6; int L = t2 / 6;
      dst[idx] = (double)base[L * 216 + mu * 36 + d * 6 + R_];
    }
  }
  __syncthreads();
}

// ---------------- f32 one-sided Jacobi (coarse subspace finder) ----------------
// 16 threads/pair, stride 36 (2-way aliasing — free)
__device__ void jacobi36(float* B, int R, float* J, int* flag, int tid) {
  for (int i = tid; i < 36 * 36; i += NT) J[i] = ((i / 36) == (i % 36)) ? 1.f : 0.f;
  __syncthreads();
  for (int sw = 0; sw < 9; ++sw) {
    if (tid == 0) *flag = 0;
    __syncthreads();
    for (int t = 0; t < 35; ++t) {
      int s = tid >> 4, h = tid & 15;
      bool act = (tid < 288);
      int p = 0, q = 0; float c = 1.f, sn = 0.f; bool doit = false;
      if (act) {
        if (s == 0) { p = 35; q = t % 35; }
        else { p = (t + s) % 35; q = (t - s + 35) % 35; }
        float app = 0.f, aqq = 0.f, apq = 0.f;
        for (int r = h; r < R; r += 16) {
          float x = B[r * 36 + p], y = B[r * 36 + q];
          app += x * x; aqq += y * y; apq += x * y;
        }
        app += __shfl_xor(app, 1); aqq += __shfl_xor(aqq, 1); apq += __shfl_xor(apq, 1);
        app += __shfl_xor(app, 2); aqq += __shfl_xor(aqq, 2); apq += __shfl_xor(apq, 2);
        app += __shfl_xor(app, 4); aqq += __shfl_xor(aqq, 4); apq += __shfl_xor(apq, 4);
        app += __shfl_xor(app, 8); aqq += __shfl_xor(aqq, 8); apq += __shfl_xor(apq, 8);
        double g = (double)apq, aa = (double)app, bb = (double)aqq;
        if (g * g > 1e-14 * aa * bb) {
          doit = true;
          if (h == 0) *flag = 1;
          double tau = (bb - aa) / (2.0 * g);
          double tt = (tau >= 0.0 ? 1.0 : -1.0) / (fabs(tau) + sqrt(1.0 + tau * tau));
          double cc = 1.0 / sqrt(1.0 + tt * tt);
          c = (float)cc; sn = (float)(tt * cc);
        }
      }
      if (doit) {
        for (int r = h; r < R; r += 16) {
          float x = B[r * 36 + p], y = B[r * 36 + q];
          B[r * 36 + p] = c * x - sn * y;
          B[r * 36 + q] = sn * x + c * y;
        }
        for (int r = h; r < 36; r += 16) {
          float x = J[r * 36 + p], y = J[r * 36 + q];
          J[r * 36 + p] = c * x - sn * y;
          J[r * 36 + q] = sn * x + c * y;
        }
      }
      __syncthreads();
    }
    int f = *flag;
    __syncthreads();
    if (!f) break;
  }
}

// 8 threads/pair, 18 rows/thread in regs, B stride 145 (conflict-free: h*145%32 distinct)
#define J144LD 145
__device__ void jacobi144(float* B, int* flag, int tid) {
  for (int sw = 0; sw < 9; ++sw) {
    if (tid == 0) *flag = 0;
    __syncthreads();
    for (int t = 0; t < 143; ++t) {
      int s = tid >> 3, h = tid & 7;
      bool act = (tid < 576);
      float xp[18], xq[18];
      int p = 0, q = 0; float c = 1.f, sn = 0.f; bool doit = false;
      if (act) {
        if (s == 0) { p = 143; q = t % 143; }
        else { p = (t + s) % 143; q = (t - s + 143) % 143; }
        float app = 0.f, aqq = 0.f, apq = 0.f;
#pragma unroll
        for (int i = 0; i < 18; ++i) {
          int r = h + 8 * i;
          float x = B[r * J144LD + p], y = B[r * J144LD + q];
          xp[i] = x; xq[i] = y;
          app += x * x; aqq += y * y; apq += x * y;
        }
        app += __shfl_xor(app, 1); aqq += __shfl_xor(aqq, 1); apq += __shfl_xor(apq, 1);
        app += __shfl_xor(app, 2); aqq += __shfl_xor(aqq, 2); apq += __shfl_xor(apq, 2);
        app += __shfl_xor(app, 4); aqq += __shfl_xor(aqq, 4); apq += __shfl_xor(apq, 4);
        double g = (double)apq, aa = (double)app, bb = (double)aqq;
        if (g * g > 1e-14 * aa * bb) {
          doit = true;
          if (h == 0) *flag = 1;
          double tau = (bb - aa) / (2.0 * g);
          double tt = (tau >= 0.0 ? 1.0 : -1.0) / (fabs(tau) + sqrt(1.0 + tau * tau));
          double cc = 1.0 / sqrt(1.0 + tt * tt);
          c = (float)cc; sn = (float)(tt * cc);
        }
      }
      if (doit) {
#pragma unroll
        for (int i = 0; i < 18; ++i) {
          int r = h + 8 * i;
          B[r * J144LD + p] = c * xp[i] - sn * xq[i];
          B[r * J144LD + q] = sn * xp[i] + c * xq[i];
        }
      }
      __syncthreads();
    }
    int f = *flag;
    __syncthreads();
    if (!f) break;
  }
}

// column norms (f32 B, row stride ldb) + top-`keep` selection
__device__ void colnorms_sel(const float* B, int R, int C, int ldb, int keep, char* lp, int tid) {
  double* NORM = L_NORM(lp); int* SEL = L_SEL(lp); double* S = L_S(lp);
  for (int c = tid; c < C; c += NT) {
    double a = 0.0;
    for (int r = 0; r < R; ++r) { float v = B[r * ldb + c]; a += (double)v * (double)v; }
    NORM[c] = a;
  }
  __syncthreads();
  if (tid == 0) {
    for (int i = 0; i < keep; ++i) {
      int bi = 0; double bv = -1.0;
      for (int x = 0; x < C; ++x) if (NORM[x] > bv) { bv = NORM[x]; bi = x; }
      SEL[i] = bi;
      S[i] = sqrt(bv > 1e-300 ? bv : 1e-300);
      NORM[bi] = -2.0;
    }
  }
  __syncthreads();
}

// ---------------- fp64 refinement ----------------
// 16 threads/pair, Z stride 25 doubles (conflict-free: h*50%32 distinct)
#define ZLD 25
__device__ void jacobi24d(double* Z, int R, double* J24, int* flag, int tid) {
  for (int i = tid; i < 576; i += NT) J24[i] = ((i / 24) == (i % 24)) ? 1.0 : 0.0;
  __syncthreads();
  for (int sw = 0; sw < 16; ++sw) {
    if (tid == 0) *flag = 0;
    __syncthreads();
    for (int t = 0; t < 23; ++t) {
      int s = tid >> 4, h = tid & 15;
      bool act = (tid < 192);
      int p = 0, q = 0; double c_ = 1.0, sn = 0.0; bool doit = false;
      if (act) {
        if (s == 0) { p = 23; q = t % 23; }
        else { p = (t + s) % 23; q = (t - s + 23) % 23; }
        double app = 0, aqq = 0, apq = 0;
        for (int r = h; r < R; r += 16) {
          double x = Z[r * ZLD + p], y = Z[r * ZLD + q];
          app += x * x; aqq += y * y; apq += x * y;
        }
        app += __shfl_xor(app, 1); aqq += __shfl_xor(aqq, 1); apq += __shfl_xor(apq, 1);
        app += __shfl_xor(app, 2); aqq += __shfl_xor(aqq, 2); apq += __shfl_xor(apq, 2);
        app += __shfl_xor(app, 4); aqq += __shfl_xor(aqq, 4); apq += __shfl_xor(apq, 4);
        app += __shfl_xor(app, 8); aqq += __shfl_xor(aqq, 8); apq += __shfl_xor(apq, 8);
        if (apq * apq > 1e-28 * app * aqq) {
          doit = true;
          if (h == 0) *flag = 1;
          double tau = (aqq - app) / (2.0 * apq);
          double tt = (tau >= 0.0 ? 1.0 : -1.0) / (fabs(tau) + sqrt(1.0 + tau * tau));
          double cc = 1.0 / sqrt(1.0 + tt * tt);
          c_ = cc; sn = tt * cc;
        }
      }
      if (doit) {
        for (int r = h; r < R; r += 16) {
          double x = Z[r * ZLD + p], y = Z[r * ZLD + q];
          Z[r * ZLD + p] = c_ * x - sn * y;
          Z[r * ZLD + q] = sn * x + c_ * y;
        }
        for (int r = h; r < 24; r += 16) {
          double x = J24[r * 24 + p], y = J24[r * 24 + q];
          J24[r * 24 + p] = c_ * x - sn * y;
          J24[r * 24 + q] = sn * x + c_ * y;
        }
      }
      __syncthreads();
    }
    int f = *flag;
    __syncthreads();
    if (!f) break;
  }
}

__device__ void sort24(const double* Z, int R, char* lp, int tid) {
  double* NORM = L_NORM(lp); int* SEL = L_SEL(lp); double* S = L_S(lp);
  for (int c = tid; c < 24; c += NT) {
    double a = 0.0;
    for (int r = 0; r < R; ++r) { double v = Z[r * ZLD + c]; a += v * v; }
    NORM[c] = a;
  }
  __syncthreads();
  if (tid == 0) {
    for (int i = 0; i < 24; ++i) {
      int bi = 0; double bv = -1.0;
      for (int x = 0; x < 24; ++x) if (NORM[x] > bv) { bv = NORM[x]; bi = x; }
      SEL[i] = bi;
      S[i] = sqrt(bv > 1e-300 ? bv : 1e-300);
      NORM[bi] = -2.0;
    }
  }
  __syncthreads();
}

// Rayleigh-Ritz refinement (see round-7 comments)
__device__ void refine(const double* t, int tR, int tC, int My, int ucase,
                       double* site, double* X, double* Dd, char* lp, int tid) {
  double* G = Dd + M_G;   double* T24 = Dd + M_T;
  double* Y0 = Dd + M_Y0; double* YH = Dd + M_YH;
  double* W = Dd + M_W;   double* P = Dd + M_P;
  double* Zr = L_ZR(lp);  double* J24 = L_J24(lp);
  int Rz = ucase ? tC : tR;
  mm_tn(Y0, 24, Y0, 24, G, 24, 24, 24, My, tid);
  cholesky(G, 24, tid);
  trinv(G, 24, T24, tid);
  mm_nn(Y0, 24, T24, 24, YH, 24, My, 24, 24, tid);
  if (ucase) mm_tn(t, tC, YH, 24, Zr, ZLD, tC, 24, tR, tid);
  else       mm_nn(t, tC, YH, 24, Zr, ZLD, tR, 24, tC, tid);
  jacobi24d(Zr, Rz, J24, L_FLAG(lp), tid);
  sort24(Zr, Rz, lp, tid);
  int* SEL = L_SEL(lp); double* S = L_S(lp);
  for (int i = tid; i < 576; i += NT) {
    int k = i / 24, c = i - k * 24;
    W[i] = J24[k * 24 + SEL[c]];
  }
  __syncthreads();
  mm_nn(YH, 24, W, 24, P, 24, My, 24, 24, tid);
  if (ucase) {
    for (int i = tid; i < My * 24; i += NT) {
      int k = i / 24, c = i - k * 24;
      X[i] = P[i] * S[c];
    }
    for (int i = tid; i < 24 * tC; i += NT) {
      int c = i / tC, x = i - c * tC;
      site[i] = Zr[x * ZLD + SEL[c]] / S[c];
    }
  } else {
    for (int i = tid; i < 24 * My; i += NT) {
      int c = i / My, x = i - c * My;
      site[i] = P[x * 24 + c];
    }
    for (int i = tid; i < Rz * 24; i += NT) {
      int k = i / 24, c = i - k * 24;
      X[i] = Zr[k * ZLD + SEL[c]];
    }
  }
  __syncthreads();
}

// SVD of t (R x 36), keep 24
__device__ void svdV36d(const double* t, int R, double* site, double* X,
                        double* Dd, char* lp, int tid) {
  float* B = L_B(lp); float* J = L_J(lp);
  for (int i = tid; i < R * 36; i += NT) B[i] = (float)t[i];
  __syncthreads();
  jacobi36(B, R, J, L_FLAG(lp), tid);
  colnorms_sel(B, R, 36, 36, 24, lp, tid);
  int* SEL = L_SEL(lp);
  double* Y0 = Dd + M_Y0;
  for (int i = tid; i < 36 * 24; i += NT) {
    int x = i / 24, c = i - x * 24;
    Y0[i] = (double)J[x * 36 + SEL[c]];
  }
  __syncthreads();
  refine(t, R, 36, 36, 0, site, X, Dd, lp, tid);
}

// SVD of t (36 x 144), keep 24
__device__ void svdU36d(const double* t, double* site, double* X,
                        double* Dd, char* lp, int tid) {
  float* B = L_B(lp); float* J = L_J(lp);
  for (int i = tid; i < 144 * 36; i += NT) {
    int x = i / 36, k = i - x * 36;
    B[i] = (float)t[k * 144 + x];
  }
  __syncthreads();
  jacobi36(B, 144, J, L_FLAG(lp), tid);
  colnorms_sel(B, 144, 36, 36, 24, lp, tid);
  int* SEL = L_SEL(lp);
  double* Y0 = Dd + M_Y0;
  for (int i = tid; i < 36 * 24; i += NT) {
    int x = i / 24, c = i - x * 24;
    Y0[i] = (double)J[x * 36 + SEL[c]];
  }
  __syncthreads();
  refine(t, 36, 144, 36, 1, site, X, Dd, lp, tid);
}

// SVD of t (144 x 144), keep 24 — B at stride 145 (conflict-free Jacobi)
__device__ void stepJ3bigd(const double* t, double* site, double* X,
                           double* Dd, char* lp, int tid) {
  float* B = L_B(lp);
  for (int i = tid; i < 144 * 144; i += NT) {
    int r = i / 144, c = i - r * 144;
    B[r * J144LD + c] = (float)t[i];
  }
  __syncthreads();
  jacobi144(B, L_FLAG(lp), tid);
  colnorms_sel(B, 144, 144, J144LD, 24, lp, tid);
  int* SEL = L_SEL(lp);
  double* Y0 = Dd + M_Y0;
  for (int i = tid; i < 144 * 24; i += NT) {
    int k = i / 24, c = i - k * 24;
    Y0[i] = (double)B[k * J144LD + SEL[c]];
  }
  __syncthreads();
  refine(t, 144, 144, 144, 1, site, X, Dd, lp, tid);
}

// LQ of t5 (36x6)
__device__ void stepJ5(const double* t5, double* G, double* T, double* Qp,
                       double* cand5, double* X5, int tid) {
  mm_nt(t5, 6, t5, 6, G, 6, 6, 6, 6, tid);
  cholesky(G, 6, tid);
  trinv(G, 6, T, tid);
  mm_tn(t5, 6, T, 6, Qp, 6, 6, 6, 6, tid);
  for (int i = tid; i < 36; i += NT) {
    int l = i / 6, mu = i - l * 6;
    cand5[i] = Qp[mu * 6 + l];
  }
  __syncthreads();
  mm_nn(t5, 6, Qp, 6, X5, 6, 36, 6, 6, tid);
}

// LQ of t1 (6x144)
__device__ void stepJ1(const double* t1, double* G, double* T,
                       double* cand1, double* X1, int tid) {
  mm_nt(t1, 144, t1, 144, G, 6, 6, 6, 144, tid);
  cholesky(G, 6, tid);
  trinv(G, 6, T, tid);
  mm_tn(T, 6, t1, 144, cand1, 144, 6, 144, 6, tid);
  for (int i = tid; i < 36; i += NT) {
    int r = i / 6, c = i - r * 6;
    X1[i] = (c <= r) ? G[c * 6 + r] : 0.0;
  }
  __syncthreads();
}

__device__ void rescale0(double* cout_, char* lp, int tid) {
  if (tid == 0) {
    double m = 0.0;
    for (int i = 0; i < 36; ++i) { double v = fabs(cout_[i]); if (v > m) m = v; }
    if (!(m > 1e-300)) m = 1.0;
    *L_SCALE(lp) = m;
    *L_LOG(lp) += log(m);
  }
  __syncthreads();
  double m = *L_SCALE(lp);
  for (int i = tid; i < 36; i += NT) cout_[i] /= m;
  __syncthreads();
}

// ---------------- one _bmps round (truncating compress to DC=24) ----------------
__device__ void run_round(int r, int b, const int* cfg, const float* tens,
                          const double* cin_, double* cout_, int tid) {
  char* lp = ldsp();
  double* Dd = g_m + (size_t)b * M_STRIDE;
  const int K  = (r == 1) ? 36 : 144;
  const int cK = (r == 1) ? 6 : 24;
  int cb[7] = {1, 6, cK, cK, cK, 6, 1};
  int co[6]; co[0] = 0;
  for (int j = 0; j < 5; ++j) co[j + 1] = co[j] + cb[j] * 6 * cb[j + 1];
  const int ob[7] = {1, 6, 24, 24, 24, 6, 1};
  int oo[6]; oo[0] = 0;
  for (int j = 0; j < 5; ++j) oo[j + 1] = oo[j] + ob[j] * 6 * ob[j + 1];
  const int roff6[6] = {0, 216, 1512, 2808, 4104, 5400};

  double* ROW = Dd + M_ROW;
  double* Dbuf = Dd + M_D;  double* Abuf = Dd + M_A;  double* A3 = Dd + M_A3;
  double* Q2 = Dd + M_Q2;   double* Q4 = Dd + M_Q4;   double* Q1 = Dd + M_Q1;  double* Q0 = Dd + M_Q0;
  double* TB = Dd + M_TB;   double* Rw = Dd + M_R;    double* Tw = Dd + M_T;   double* T3 = Dd + M_T3;
  double* G = Dd + M_G;     double* X = Dd + M_X;     double* Zp = Dd + M_Z;
  double* t5 = Dd + M_T5;   double* X5 = Dd + M_X5;   double* Qp = Dd + M_QP;
  double* X1 = Dd + M_X1;   double* t1 = Dd + M_T1;

  gather_row(cfg, tens, b, r, 6, ROW, roff6, tid);

  // ---- QR sweep (left-canonicalize) ----
  build_D(cin_ + co[0], 1, cb[1], ROW + roff6[0], 1, 6, Dbuf, tid);
  wideQR(Dbuf, 6, 36, Q0, Rw, G, Tw, tid);

  build_D(cin_ + co[1], 6, cb[2], ROW + roff6[1], 6, 6, Dbuf, tid);
  mm_nn(Rw, 36, Dbuf, 6 * K, Abuf, 6 * K, 6, 6 * K, 36, tid);
  if (K == 36) tallQR(Abuf, 36, 36, Q1, Rw, G, Tw, lp, tid);
  else         wideQR(Abuf, 36, 144, Q1, Rw, G, Tw, tid);

  build_D(cin_ + co[2], cb[2], cb[3], ROW + roff6[2], 6, 6, Dbuf, tid);
  mm_nn_bs(Rw, K, Dbuf, 6 * K, Abuf, 6 * K, 36, 6 * K, K, lp, tid);
  tallQR(Abuf, 216, K, Q2, Rw, G, Tw, lp, tid);

  build_D(cin_ + co[3], cb[3], cb[4], ROW + roff6[3], 6, 6, Dbuf, tid);
  mm_nn_bs(Rw, K, Dbuf, 6 * K, A3, 6 * K, K, 6 * K, K, lp, tid);
  tallQR(A3, 6 * K, K, nullptr, Rw, G, T3, lp, tid);

  build_D(cin_ + co[4], cb[4], cb[5], ROW + roff6[4], 6, 6, Dbuf, tid);
  mm_nn_bs(Rw, K, Dbuf, 216, Abuf, 216, K, 216, K, lp, tid);
  tallQR(Abuf, 6 * K, 36, Q4, Rw, G, Tw, lp, tid);

  build_D(cin_ + co[5], cb[5], 1, ROW + roff6[5], 6, 1, Dbuf, tid);
  mm_nn(Rw, 36, Dbuf, 6, t5, 6, 36, 6, 36, tid);

  // ---- SVD sweep (right-to-left, truncate at j=4,3,2) ----
  stepJ5(t5, G, Tw, Qp, cout_ + oo[5], X5, tid);
  mm_nn(Q4, 36, X5, 6, TB, 6, 6 * K, 6, 36, tid);                 // t4 (K x 36)
  svdV36d(TB, K, cout_ + oo[4], X, Dd, lp, tid);                  // X (K x 24)
  mm_nn_bs(T3, K, X, 24, Zp, 24, K, 24, K, lp, tid);              // Z = T3 X4
  mm_nn_bs(A3, K, Zp, 24, TB, 24, 6 * K, 24, K, lp, tid);         // t3 (K x 144)
  if (K == 144) stepJ3bigd(TB, cout_ + oo[3], X, Dd, lp, tid);
  else          svdU36d(TB, cout_ + oo[3], X, Dd, lp, tid);       // X (K x 24)
  mm_nn_bs(Q2, K, X, 24, TB, 24, 216, 24, K, lp, tid);            // t2 (36 x 144)
  svdU36d(TB, cout_ + oo[2], X, Dd, lp, tid);                     // X (36 x 24)
  mm_nn(Q1, 36, X, 24, t1, 24, 36, 24, 36, tid);                  // t1 (6 x 144)
  stepJ1(t1, G, Tw, cout_ + oo[1], X1, tid);
  mm_nn(Q0, 6, X1, 6, cout_ + oo[0], 6, 6, 6, 6, tid);            // site0
  rescale0(cout_, lp, tid);
}

// ---------------- kernel ----------------
extern "C" __global__ void __launch_bounds__(NT, 4)
peps_kernel(const int* __restrict__ cfg, const float* __restrict__ tens, float* __restrict__ out) {
  const int b = blockIdx.x;
  const int tid = threadIdx.x;
  char* lp = ldsp();
  double* CA = g_m + (size_t)b * M_STRIDE + M_CA;
  double* CB = g_m + (size_t)b * M_STRIDE + M_CB;
  if (tid == 0) *L_LOG(lp) = 0.0;

  // init cand = row 0 (bonds 1,6,6,6,6,6,1 ; up=0)
  {
    const int c1off[6] = {0, 36, 252, 468, 684, 900};
    for (int j = 0; j < 6; ++j) {
      int al = (j == 0) ? 1 : 6, ar = (j == 5) ? 1 : 6;
      const float* base = tens + (size_t)((j * 2 + cfg[b * 36 + j])) * 1296;
      int n = al * 6 * ar;
      double* dst = CA + c1off[j];
      for (int idx = tid; idx < n; idx += NT) {
        int l = idx / (6 * ar); int rest = idx - l * (6 * ar);
        int mu = rest / ar; int rr = rest - mu * ar;
        dst[idx] = (double)base[l * 216 + mu * 6 + rr];
      }
    }
    __syncthreads();
  }

  run_round(1, b, cfg, tens, CA, CB, tid);
  run_round(2, b, cfg, tens, CB, CA, tid);
  run_round(3, b, cfg, tens, CA, CB, tid);
  run_round(4, b, cfg, tens, CB, CA, tid);

  // final exact contraction of cand (in CA) with row 5 (down dim = 1)
  {
    const int roff1[6] = {0, 36, 252, 468, 684, 900};
    double* ROW = g_m + (size_t)b * M_STRIDE + M_ROW;
    gather_row(cfg, tens, b, 5, 1, ROW, roff1, tid);
    double* E = L_E(lp); double* E2 = L_E2(lp);
    if (tid == 0) E[0] = 1.0;
    __syncthreads();
    const int ob[7] = {1, 6, 24, 24, 24, 6, 1};
    int oo[6]; oo[0] = 0;
    for (int j = 0; j < 5; ++j) oo[j + 1] = oo[j] + ob[j] * 6 * ob[j + 1];
    const double* candF = CA;
    double* src = E; double* dst = E2;
    for (int j = 0; j < 6; ++j) {
      int cl = ob[j], cr = ob[j + 1];
      int al = (j == 0) ? 1 : 6, ar = (j == 5) ? 1 : 6;
      int n = cr * ar;
      for (int idx = tid; idx < n; idx += NT) {
        int rr = idx / ar, R_ = idx - rr * ar;
        double acc = 0.0;
        for (int l = 0; l < cl; ++l) {
          for (int L = 0; L < al; ++L) {
            double e = src[l * al + L];
            double s2 = 0.0;
#pragma unroll
            for (int mu = 0; mu < 6; ++mu)
              s2 += candF[oo[j] + (l * 6 + mu) * cr + rr] * ROW[roff1[j] + (L * 6 + mu) * ar + R_];
            acc += e * s2;
          }
        }
        dst[idx] = acc;
      }
      __syncthreads();
      double* tmp = src; src = dst; dst = tmp;
    }
    if (tid == 0) out[b] = (float)(src[0] * exp(*L_LOG(lp)));
  }
}

// ---------------- launch ----------------
extern "C" void kernel_launch(void* const* d_in, const int* in_sizes, int n_in,
                              void* d_out, int out_size, void* d_ws, size_t ws_size,
                              hipStream_t stream) {
  (void)in_sizes; (void)n_in; (void)out_size; (void)d_ws; (void)ws_size;
  const int* cfg = (const int*)d_in[0];
  const float* tens = (const float*)d_in[1];
  float* out = (float*)d_out;
  (void)hipFuncSetAttribute((const void*)peps_kernel,
                            hipFuncAttributeMaxDynamicSharedMemorySize, LDS_BYTES);
  peps_kernel<<<dim3(NB), dim3(NT), LDS_BYTES, stream>>>(cfg, tens, out);
}

// Round 11
// 34559.033 us; speedup vs baseline: 1.8678x; 1.0129x over previous
//
#include <hip/hip_runtime.h>
#include <math.h>

#define NT 1024
#define NB 32

// ---------------- unified fp64 arena (per-batch, element offsets) ----------------
#define M_D    0        // 124416 : small D scratch (j0/j5 only now)
#define M_A    124416   // 124416 : A1/A2/A4
#define M_A3   248832   // 124416 : A3 (kept through round)
#define M_Q2   373248   // 31104  : Q2 (216 x K)
#define M_Q4   404352   // 31104  : Q4 (6K x 36)
#define M_TB   435456   // 20736  : t-matrix buffer (max 144x144)
#define M_Q1   456192   // 1296
#define M_Q0   457488   // 64
#define M_ROW  457552   // 5616   : gathered row tensors
#define M_R    463168   // 20736  : current R (dense)
#define M_T    483904   // 20736  : current T = R^-1 (also T24 in refine)
#define M_T3   504640   // 20736  : T3 kept
#define M_G    525392   // 20736  : Gram / chol workspace
#define M_CA   546128   // 8712   : cand buffer A
#define M_CB   554840   // 8712   : cand buffer B
#define M_X    563552   // 3456   : push factor X (max 144x24)
#define M_Z    567008   // 3456   : Z = T3*X4
#define M_T5   570464   // 216
#define M_X5   570680   // 216
#define M_QP   570896   // 64
#define M_X1   570960   // 64
#define M_T1   571024   // 864
#define M_Y0   571888   // 3456   : refine: approx subspace basis (My x 24)
#define M_YH   575344   // 3456   : refine: orthonormal basis
#define M_W    578800   // 576    : refine: sorted right-rotation
#define M_P    579376   // 3456   : refine: YH * W
#define M_STRIDE 582832

__device__ __align__(16) double g_m[(size_t)NB * M_STRIDE];

// ---------------- LDS layout (byte offsets) ----------------
#define STAGE_CAP 82944
#define LO_J     82944
#define LO_NORM  88128   // double[144]
#define LO_S     89280   // double[24]
#define LO_E     89472   // double[144]
#define LO_E2    90624   // double[144]
#define LO_SEL   91776   // int[24]
#define LO_FLAG  91872   // int
#define LO_LOG   91880   // double
#define LO_SCALE 91888   // double
#define LDS_BYTES 92160

__device__ __forceinline__ char* ldsp() {
  extern __shared__ char lds_pool[];
  return lds_pool;
}
#define L_B(p)     ((float*)(p))
#define L_J(p)     ((float*)((p)+LO_J))
#define L_ZR(p)    ((double*)(p))
#define L_J24(p)   ((double*)((p)+28800))
#define L_NORM(p)  ((double*)((p)+LO_NORM))
#define L_S(p)     ((double*)((p)+LO_S))
#define L_E(p)     ((double*)((p)+LO_E))
#define L_E2(p)    ((double*)((p)+LO_E2))
#define L_SEL(p)   ((int*)((p)+LO_SEL))
#define L_FLAG(p)  ((int*)((p)+LO_FLAG))
#define L_LOG(p)   ((double*)((p)+LO_LOG))
#define L_SCALE(p) ((double*)((p)+LO_SCALE))

// ---------------- fp64 matmuls (4-wide strip when N%4==0) ----------------
__device__ void mm_nn(const double* __restrict__ A, int lda, const double* __restrict__ Bm, int ldb,
                      double* __restrict__ C, int ldc, int M, int N, int Kd, int tid) {
  if ((N & 3) == 0) {
    int nstrip = N >> 2;
    for (int u = tid; u < M * nstrip; u += NT) {
      int i = u / nstrip, j0 = (u - i * nstrip) << 2;
      const double* a = A + (size_t)i * lda;
      const double* b = Bm + j0;
      double d0 = 0, d1 = 0, d2 = 0, d3 = 0;
      for (int k = 0; k < Kd; ++k) {
        double av = a[k];
        const double* br = b + (size_t)k * ldb;
        d0 += av * br[0]; d1 += av * br[1]; d2 += av * br[2]; d3 += av * br[3];
      }
      size_t o = (size_t)i * ldc + j0;
      C[o] = d0; C[o + 1] = d1; C[o + 2] = d2; C[o + 3] = d3;
    }
  } else {
    for (int idx = tid; idx < M * N; idx += NT) {
      int i = idx / N, j = idx - i * N;
      const double* a = A + (size_t)i * lda;
      double acc = 0.0;
      for (int k = 0; k < Kd; ++k) acc += a[k] * Bm[(size_t)k * ldb + j];
      C[(size_t)i * ldc + j] = acc;
    }
  }
  __syncthreads();
}

__device__ void mm_tn(const double* __restrict__ A, int lda, const double* __restrict__ Bm, int ldb,
                      double* __restrict__ C, int ldc, int M, int N, int Kd, int tid) {
  if ((N & 3) == 0) {
    int nstrip = N >> 2;
    for (int u = tid; u < M * nstrip; u += NT) {
      int i = u / nstrip, j0 = (u - i * nstrip) << 2;
      double d0 = 0, d1 = 0, d2 = 0, d3 = 0;
      for (int k = 0; k < Kd; ++k) {
        double av = A[(size_t)k * lda + i];
        const double* br = Bm + (size_t)k * ldb + j0;
        d0 += av * br[0]; d1 += av * br[1]; d2 += av * br[2]; d3 += av * br[3];
      }
      size_t o = (size_t)i * ldc + j0;
      C[o] = d0; C[o + 1] = d1; C[o + 2] = d2; C[o + 3] = d3;
    }
  } else {
    for (int idx = tid; idx < M * N; idx += NT) {
      int i = idx / N, j = idx - i * N;
      double acc = 0.0;
      for (int k = 0; k < Kd; ++k) acc += A[(size_t)k * lda + i] * Bm[(size_t)k * ldb + j];
      C[(size_t)i * ldc + j] = acc;
    }
  }
  __syncthreads();
}

__device__ void mm_nt(const double* __restrict__ A, int lda, const double* __restrict__ Bm, int ldb,
                      double* __restrict__ C, int ldc, int M, int N, int Kd, int tid) {
  for (int idx = tid; idx < M * N; idx += NT) {
    int i = idx / N, j = idx - i * N;
    double acc = 0.0;
    for (int k = 0; k < Kd; ++k) acc += A[(size_t)i * lda + k] * Bm[(size_t)j * ldb + k];
    C[(size_t)i * ldc + j] = acc;
  }
  __syncthreads();
}

// ---------------- core of panel-staged mm (compute phase) ----------------
__device__ __forceinline__ void mm_panel_compute(const double* __restrict__ A, int lda,
                                                 const double* __restrict__ SB,
                                                 double* __restrict__ C, int ldc,
                                                 int M, int n0, int nb, int Kd, int tid) {
  int nstrip = nb >> 2;
  if ((M & 3) == 0) {
    int items = (M >> 2) * nstrip;
    for (int u = tid; u < items; u += NT) {
      int iq = u / nstrip;
      int i = iq << 2;
      int jl = (u - iq * nstrip) << 2;
      const double* a0 = A + (size_t)i * lda;
      const double* a1 = a0 + lda;
      const double* a2 = a1 + lda;
      const double* a3 = a2 + lda;
      double c00=0,c01=0,c02=0,c03=0, c10=0,c11=0,c12=0,c13=0;
      double c20=0,c21=0,c22=0,c23=0, c30=0,c31=0,c32=0,c33=0;
      for (int k = 0; k < Kd; ++k) {
        const double* bp = SB + k * nb + jl;
        double b0 = bp[0], b1 = bp[1], b2 = bp[2], b3 = bp[3];
        double av0 = a0[k], av1 = a1[k], av2 = a2[k], av3 = a3[k];
        c00 += av0*b0; c01 += av0*b1; c02 += av0*b2; c03 += av0*b3;
        c10 += av1*b0; c11 += av1*b1; c12 += av1*b2; c13 += av1*b3;
        c20 += av2*b0; c21 += av2*b1; c22 += av2*b2; c23 += av2*b3;
        c30 += av3*b0; c31 += av3*b1; c32 += av3*b2; c33 += av3*b3;
      }
      size_t o0 = (size_t)i * ldc + n0 + jl;
      size_t o1 = o0 + ldc, o2 = o1 + ldc, o3 = o2 + ldc;
      C[o0]=c00; C[o0+1]=c01; C[o0+2]=c02; C[o0+3]=c03;
      C[o1]=c10; C[o1+1]=c11; C[o1+2]=c12; C[o1+3]=c13;
      C[o2]=c20; C[o2+1]=c21; C[o2+2]=c22; C[o2+3]=c23;
      C[o3]=c30; C[o3+1]=c31; C[o3+2]=c32; C[o3+3]=c33;
    }
  } else {
    int items = (M >> 1) * nstrip;
    for (int u = tid; u < items; u += NT) {
      int iq = u / nstrip;
      int i = iq << 1;
      int jl = (u - iq * nstrip) << 2;
      const double* a0 = A + (size_t)i * lda;
      const double* a1 = a0 + lda;
      double c00=0,c01=0,c02=0,c03=0, c10=0,c11=0,c12=0,c13=0;
      for (int k = 0; k < Kd; ++k) {
        const double* bp = SB + k * nb + jl;
        double b0 = bp[0], b1 = bp[1], b2 = bp[2], b3 = bp[3];
        double av0 = a0[k], av1 = a1[k];
        c00 += av0*b0; c01 += av0*b1; c02 += av0*b2; c03 += av0*b3;
        c10 += av1*b0; c11 += av1*b1; c12 += av1*b2; c13 += av1*b3;
      }
      size_t o0 = (size_t)i * ldc + n0 + jl, o1 = o0 + ldc;
      C[o0]=c00; C[o0+1]=c01; C[o0+2]=c02; C[o0+3]=c03;
      C[o1]=c10; C[o1+1]=c11; C[o1+2]=c12; C[o1+3]=c13;
    }
  }
}

// C(M x N) = A(M x Kd) * B(Kd x N). B staged from GLOBAL in 64-col LDS panels.
__device__ void mm_nn_bs(const double* __restrict__ A, int lda,
                         const double* __restrict__ Bm, int ldb,
                         double* __restrict__ C, int ldc,
                         int M, int N, int Kd, char* lp, int tid) {
  double* SB = (double*)lp;
  for (int n0 = 0; n0 < N; n0 += 64) {
    int nb = N - n0; if (nb > 64) nb = 64;
    for (int x = tid; x < Kd * nb; x += NT) {
      int k = x / nb, j = x - k * nb;
      SB[x] = Bm[(size_t)k * ldb + n0 + j];
    }
    __syncthreads();
    mm_panel_compute(A, lda, SB, C, ldc, M, n0, nb, Kd, tid);
    __syncthreads();
  }
}

// C(M x N) = A(M x Kd) * D(Kd x N), D built ON THE FLY into the LDS panel:
//   D[k, col] = sum_mu cand[(l*6+mu)*cr + rr] * rowS[((L*6+mu)*6 + d)*ar + R_]
//   k: l = k/al, L = k - l*al  (Kd = cl*al)
//   col: mnext = cr*ar; d = col/mnext; rem = col - d*mnext; rr = rem/ar; R_ = rem - rr*ar
//   N = 6*cr*ar. Eliminates the Dbuf global round-trip entirely.
__device__ void mm_nn_bsD(const double* __restrict__ A, int lda,
                          const double* __restrict__ cand, int cl, int cr,
                          const double* __restrict__ rowS, int al, int ar,
                          double* __restrict__ C, int ldc,
                          int M, int Kd, char* lp, int tid) {
  double* SB = (double*)lp;
  int mnext = cr * ar;
  int N = 6 * mnext;
  for (int n0 = 0; n0 < N; n0 += 64) {
    int nb = N - n0; if (nb > 64) nb = 64;
    for (int x = tid; x < Kd * nb; x += NT) {
      int k = x / nb, j = x - k * nb;
      int col = n0 + j;
      int l = k / al, L = k - l * al;
      int d = col / mnext, rem = col - d * mnext;
      int rr = rem / ar, R_ = rem - rr * ar;
      double acc = 0.0;
#pragma unroll
      for (int mu = 0; mu < 6; ++mu)
        acc += cand[(l * 6 + mu) * cr + rr] * rowS[((L * 6 + mu) * 6 + d) * ar + R_];
      SB[x] = acc;
    }
    __syncthreads();
    mm_panel_compute(A, lda, SB, C, ldc, M, n0, nb, Kd, tid);
    __syncthreads();
  }
}

// G (n x n, upper valid) = A^T A ; A (Kd x n). A k-panels staged in LDS.
__device__ void gram_s(const double* __restrict__ A, int lda, int n, int Kd,
                       double* __restrict__ G, char* lp, int tid) {
  double* P = (double*)lp;
  int KC = (STAGE_CAP / 8) / n; if (KC > Kd) KC = Kd;
  for (int idx = tid; idx < n * n; idx += NT) {
    int i = idx / n, j = idx - i * n;
    if (j >= i) G[idx] = 0.0;
  }
  __syncthreads();
  for (int k0 = 0; k0 < Kd; k0 += KC) {
    int kc = Kd - k0; if (kc > KC) kc = KC;
    for (int x = tid; x < kc * n; x += NT) {
      int kk = x / n, i = x - kk * n;
      P[x] = A[(size_t)(k0 + kk) * lda + i];
    }
    __syncthreads();
    for (int idx = tid; idx < n * n; idx += NT) {
      int i = idx / n, j = idx - i * n;
      if (j < i) continue;
      double s = 0.0;
      for (int kk = 0; kk < kc; ++kk) s += P[kk * n + i] * P[kk * n + j];
      G[idx] += s;
    }
    __syncthreads();
  }
}

// ---------------- Cholesky (fp64, in-place upper R, G = R^T R) ----------------
__device__ void cholesky(double* G, int n, int tid) {
  for (int j = 0; j < n; ++j) {
    __syncthreads();
    double piv = G[(size_t)j * n + j];
    double r = sqrt(piv > 1e-300 ? piv : 1e-300);
    double inv = 1.0 / r;
    __syncthreads();
    for (int i = j + tid; i < n; i += NT)
      G[(size_t)j * n + i] = (i == j) ? r : G[(size_t)j * n + i] * inv;
    __syncthreads();
    int w = n - j - 1;
    for (int idx = tid; idx < w * w; idx += NT) {
      int ii = idx / w, kk = idx - ii * w;
      int i = j + 1 + ii, k2 = j + 1 + kk;
      if (k2 >= i) G[(size_t)i * n + k2] -= G[(size_t)j * n + i] * G[(size_t)j * n + k2];
    }
  }
  __syncthreads();
}

// T = R^{-1} (upper), fp64 dense (lower zeroed)
__device__ void trinv(const double* G, int n, double* T, int tid) {
  for (int c = tid; c < n; c += NT) {
    T[(size_t)c * n + c] = 1.0 / G[(size_t)c * n + c];
    for (int r = c - 1; r >= 0; --r) {
      double s = 0.0;
      for (int k = r + 1; k <= c; ++k) s += G[(size_t)r * n + k] * T[(size_t)k * n + c];
      T[(size_t)r * n + c] = -s / G[(size_t)r * n + r];
    }
    for (int r = c + 1; r < n; ++r) T[(size_t)r * n + c] = 0.0;
  }
  __syncthreads();
}

__device__ void copyR(const double* G, int n, double* Rw, int tid) {
  for (int idx = tid; idx < n * n; idx += NT) {
    int i = idx / n, k = idx - i * n;
    Rw[idx] = (k >= i) ? G[idx] : 0.0;
  }
  __syncthreads();
}

// tall CholQR: A (Mr x Nc), Mr >= Nc
__device__ void tallQR(const double* A, int Mr, int Nc, double* Q, double* Rw,
                       double* G, double* T, char* lp, int tid) {
  if (Mr >= 128) gram_s(A, Nc, Nc, Mr, G, lp, tid);
  else           mm_tn(A, Nc, A, Nc, G, Nc, Nc, Nc, Mr, tid);
  cholesky(G, Nc, tid);
  trinv(G, Nc, T, tid);
  if (Q) {
    if (Nc >= 64) mm_nn_bs(A, Nc, T, Nc, Q, Nc, Mr, Nc, Nc, lp, tid);
    else          mm_nn(A, Nc, T, Nc, Q, Nc, Mr, Nc, Nc, tid);
  }
  if (Rw) copyR(G, Nc, Rw, tid);
}

// wide QR (Mr < Nc): QR of first Mr cols, Rw = Q^T A (Mr x Nc)
__device__ void wideQR(const double* A, int Mr, int Nc, double* Q, double* Rw,
                       double* G, double* T, int tid) {
  mm_tn(A, Nc, A, Nc, G, Mr, Mr, Mr, Mr, tid);
  cholesky(G, Mr, tid);
  trinv(G, Mr, T, tid);
  mm_nn(A, Nc, T, Mr, Q, Mr, Mr, Mr, Mr, tid);
  mm_tn(Q, Mr, A, Nc, Rw, Nc, Mr, Nc, Mr, tid);
}

// ---------------- double-tensor build (fp64; only j0/j5 tiny cases now) ----------------
__device__ void build_D(const double* __restrict__ cand, int cl, int cr,
                        const double* __restrict__ rowS, int al, int ar,
                        double* __restrict__ D, int tid) {
  int mnext = cr * ar;
  int ncols = 6 * mnext;
  int n = cl * al * ncols;
  for (int idx = tid; idx < n; idx += NT) {
    int row = idx / ncols, col = idx - row * ncols;
    int l = row / al, L = row - l * al;
    int d = col / mnext, rem = col - d * mnext;
    int rr = rem / ar, R_ = rem - rr * ar;
    double acc = 0.0;
#pragma unroll
    for (int mu = 0; mu < 6; ++mu)
      acc += cand[(l * 6 + mu) * cr + rr] * rowS[((L * 6 + mu) * 6 + d) * ar + R_];
    D[idx] = acc;
  }
  __syncthreads();
}

// gather a physical row r into ROW buffer (fp64); dd = down-dim
__device__ void gather_row(const int* cfg, const float* tens, int b, int r, int dd,
                           double* ROW, const int* roff, int tid) {
  for (int j = 0; j < 6; ++j) {
    int al = (j == 0) ? 1 : 6, ar = (j == 5) ? 1 : 6;
    const float* base = tens + (size_t)(((r * 6 + j) * 2 + cfg[b * 36 + r * 6 + j])) * 1296;
    int n = al * 6 * dd * ar;
    double* dst = ROW + roff[j];
    for (int idx = tid; idx < n; idx += NT) {
      int R_ = idx % ar; int t2 = idx / ar;
      int d = t2 % dd; t2 /= dd;
      int mu = t2 % 6; int L = t2 / 6;
      dst[idx] = (double)base[L * 216 + mu * 36 + d * 6 + R_];
    }
  }
  __syncthreads();
}

// ---------------- f32 one-sided Jacobi (coarse subspace finder) ----------------
// 16 threads/pair, stride 36 (2-way aliasing — free)
__device__ void jacobi36(float* B, int R, float* J, int* flag, int tid) {
  for (int i = tid; i < 36 * 36; i += NT) J[i] = ((i / 36) == (i % 36)) ? 1.f : 0.f;
  __syncthreads();
  for (int sw = 0; sw < 9; ++sw) {
    if (tid == 0) *flag = 0;
    __syncthreads();
    for (int t = 0; t < 35; ++t) {
      int s = tid >> 4, h = tid & 15;
      bool act = (tid < 288);
      int p = 0, q = 0; float c = 1.f, sn = 0.f; bool doit = false;
      if (act) {
        if (s == 0) { p = 35; q = t % 35; }
        else { p = (t + s) % 35; q = (t - s + 35) % 35; }
        float app = 0.f, aqq = 0.f, apq = 0.f;
        for (int r = h; r < R; r += 16) {
          float x = B[r * 36 + p], y = B[r * 36 + q];
          app += x * x; aqq += y * y; apq += x * y;
        }
        app += __shfl_xor(app, 1); aqq += __shfl_xor(aqq, 1); apq += __shfl_xor(apq, 1);
        app += __shfl_xor(app, 2); aqq += __shfl_xor(aqq, 2); apq += __shfl_xor(apq, 2);
        app += __shfl_xor(app, 4); aqq += __shfl_xor(aqq, 4); apq += __shfl_xor(apq, 4);
        app += __shfl_xor(app, 8); aqq += __shfl_xor(aqq, 8); apq += __shfl_xor(apq, 8);
        double g = (double)apq, aa = (double)app, bb = (double)aqq;
        if (g * g > 1e-14 * aa * bb) {
          doit = true;
          if (h == 0) *flag = 1;
          double tau = (bb - aa) / (2.0 * g);
          double tt = (tau >= 0.0 ? 1.0 : -1.0) / (fabs(tau) + sqrt(1.0 + tau * tau));
          double cc = 1.0 / sqrt(1.0 + tt * tt);
          c = (float)cc; sn = (float)(tt * cc);
        }
      }
      if (doit) {
        for (int r = h; r < R; r += 16) {
          float x = B[r * 36 + p], y = B[r * 36 + q];
          B[r * 36 + p] = c * x - sn * y;
          B[r * 36 + q] = sn * x + c * y;
        }
        for (int r = h; r < 36; r += 16) {
          float x = J[r * 36 + p], y = J[r * 36 + q];
          J[r * 36 + p] = c * x - sn * y;
          J[r * 36 + q] = sn * x + c * y;
        }
      }
      __syncthreads();
    }
    int f = *flag;
    __syncthreads();
    if (!f) break;
  }
}

// 8 threads/pair, 18 rows/thread in regs, B stride 145 (conflict-free)
#define J144LD 145
__device__ void jacobi144(float* B, int* flag, int tid) {
  for (int sw = 0; sw < 9; ++sw) {
    if (tid == 0) *flag = 0;
    __syncthreads();
    for (int t = 0; t < 143; ++t) {
      int s = tid >> 3, h = tid & 7;
      bool act = (tid < 576);
      float xp[18], xq[18];
      int p = 0, q = 0; float c = 1.f, sn = 0.f; bool doit = false;
      if (act) {
        if (s == 0) { p = 143; q = t % 143; }
        else { p = (t + s) % 143; q = (t - s + 143) % 143; }
        float app = 0.f, aqq = 0.f, apq = 0.f;
#pragma unroll
        for (int i = 0; i < 18; ++i) {
          int r = h + 8 * i;
          float x = B[r * J144LD + p], y = B[r * J144LD + q];
          xp[i] = x; xq[i] = y;
          app += x * x; aqq += y * y; apq += x * y;
        }
        app += __shfl_xor(app, 1); aqq += __shfl_xor(aqq, 1); apq += __shfl_xor(apq, 1);
        app += __shfl_xor(app, 2); aqq += __shfl_xor(aqq, 2); apq += __shfl_xor(apq, 2);
        app += __shfl_xor(app, 4); aqq += __shfl_xor(aqq, 4); apq += __shfl_xor(apq, 4);
        double g = (double)apq, aa = (double)app, bb = (double)aqq;
        if (g * g > 1e-14 * aa * bb) {
          doit = true;
          if (h == 0) *flag = 1;
          double tau = (bb - aa) / (2.0 * g);
          double tt = (tau >= 0.0 ? 1.0 : -1.0) / (fabs(tau) + sqrt(1.0 + tau * tau));
          double cc = 1.0 / sqrt(1.0 + tt * tt);
          c = (float)cc; sn = (float)(tt * cc);
        }
      }
      if (doit) {
#pragma unroll
        for (int i = 0; i < 18; ++i) {
          int r = h + 8 * i;
          B[r * J144LD + p] = c * xp[i] - sn * xq[i];
          B[r * J144LD + q] = sn * xp[i] + c * xq[i];
        }
      }
      __syncthreads();
    }
    int f = *flag;
    __syncthreads();
    if (!f) break;
  }
}

// column norms (f32 B, row stride ldb) + top-`keep` selection
__device__ void colnorms_sel(const float* B, int R, int C, int ldb, int keep, char* lp, int tid) {
  double* NORM = L_NORM(lp); int* SEL = L_SEL(lp); double* S = L_S(lp);
  for (int c = tid; c < C; c += NT) {
    double a = 0.0;
    for (int r = 0; r < R; ++r) { float v = B[r * ldb + c]; a += (double)v * (double)v; }
    NORM[c] = a;
  }
  __syncthreads();
  if (tid == 0) {
    for (int i = 0; i < keep; ++i) {
      int bi = 0; double bv = -1.0;
      for (int x = 0; x < C; ++x) if (NORM[x] > bv) { bv = NORM[x]; bi = x; }
      SEL[i] = bi;
      S[i] = sqrt(bv > 1e-300 ? bv : 1e-300);
      NORM[bi] = -2.0;
    }
  }
  __syncthreads();
}

// ---------------- fp64 refinement ----------------
// 16 threads/pair, Z stride 25 doubles (conflict-free)
#define ZLD 25
__device__ void jacobi24d(double* Z, int R, double* J24, int* flag, int tid) {
  for (int i = tid; i < 576; i += NT) J24[i] = ((i / 24) == (i % 24)) ? 1.0 : 0.0;
  __syncthreads();
  for (int sw = 0; sw < 16; ++sw) {
    if (tid == 0) *flag = 0;
    __syncthreads();
    for (int t = 0; t < 23; ++t) {
      int s = tid >> 4, h = tid & 15;
      bool act = (tid < 192);
      int p = 0, q = 0; double c_ = 1.0, sn = 0.0; bool doit = false;
      if (act) {
        if (s == 0) { p = 23; q = t % 23; }
        else { p = (t + s) % 23; q = (t - s + 23) % 23; }
        double app = 0, aqq = 0, apq = 0;
        for (int r = h; r < R; r += 16) {
          double x = Z[r * ZLD + p], y = Z[r * ZLD + q];
          app += x * x; aqq += y * y; apq += x * y;
        }
        app += __shfl_xor(app, 1); aqq += __shfl_xor(aqq, 1); apq += __shfl_xor(apq, 1);
        app += __shfl_xor(app, 2); aqq += __shfl_xor(aqq, 2); apq += __shfl_xor(apq, 2);
        app += __shfl_xor(app, 4); aqq += __shfl_xor(aqq, 4); apq += __shfl_xor(apq, 4);
        app += __shfl_xor(app, 8); aqq += __shfl_xor(aqq, 8); apq += __shfl_xor(apq, 8);
        if (apq * apq > 1e-28 * app * aqq) {
          doit = true;
          if (h == 0) *flag = 1;
          double tau = (aqq - app) / (2.0 * apq);
          double tt = (tau >= 0.0 ? 1.0 : -1.0) / (fabs(tau) + sqrt(1.0 + tau * tau));
          double cc = 1.0 / sqrt(1.0 + tt * tt);
          c_ = cc; sn = tt * cc;
        }
      }
      if (doit) {
        for (int r = h; r < R; r += 16) {
          double x = Z[r * ZLD + p], y = Z[r * ZLD + q];
          Z[r * ZLD + p] = c_ * x - sn * y;
          Z[r * ZLD + q] = sn * x + c_ * y;
        }
        for (int r = h; r < 24; r += 16) {
          double x = J24[r * 24 + p], y = J24[r * 24 + q];
          J24[r * 24 + p] = c_ * x - sn * y;
          J24[r * 24 + q] = sn * x + c_ * y;
        }
      }
      __syncthreads();
    }
    int f = *flag;
    __syncthreads();
    if (!f) break;
  }
}

__device__ void sort24(const double* Z, int R, char* lp, int tid) {
  double* NORM = L_NORM(lp); int* SEL = L_SEL(lp); double* S = L_S(lp);
  for (int c = tid; c < 24; c += NT) {
    double a = 0.0;
    for (int r = 0; r < R; ++r) { double v = Z[r * ZLD + c]; a += v * v; }
    NORM[c] = a;
  }
  __syncthreads();
  if (tid == 0) {
    for (int i = 0; i < 24; ++i) {
      int bi = 0; double bv = -1.0;
      for (int x = 0; x < 24; ++x) if (NORM[x] > bv) { bv = NORM[x]; bi = x; }
      SEL[i] = bi;
      S[i] = sqrt(bv > 1e-300 ? bv : 1e-300);
      NORM[bi] = -2.0;
    }
  }
  __syncthreads();
}

// Rayleigh-Ritz refinement
__device__ void refine(const double* t, int tR, int tC, int My, int ucase,
                       double* site, double* X, double* Dd, char* lp, int tid) {
  double* G = Dd + M_G;   double* T24 = Dd + M_T;
  double* Y0 = Dd + M_Y0; double* YH = Dd + M_YH;
  double* W = Dd + M_W;   double* P = Dd + M_P;
  double* Zr = L_ZR(lp);  double* J24 = L_J24(lp);
  int Rz = ucase ? tC : tR;
  mm_tn(Y0, 24, Y0, 24, G, 24, 24, 24, My, tid);
  cholesky(G, 24, tid);
  trinv(G, 24, T24, tid);
  mm_nn(Y0, 24, T24, 24, YH, 24, My, 24, 24, tid);
  if (ucase) mm_tn(t, tC, YH, 24, Zr, ZLD, tC, 24, tR, tid);
  else       mm_nn(t, tC, YH, 24, Zr, ZLD, tR, 24, tC, tid);
  jacobi24d(Zr, Rz, J24, L_FLAG(lp), tid);
  sort24(Zr, Rz, lp, tid);
  int* SEL = L_SEL(lp); double* S = L_S(lp);
  for (int i = tid; i < 576; i += NT) {
    int k = i / 24, c = i - k * 24;
    W[i] = J24[k * 24 + SEL[c]];
  }
  __syncthreads();
  mm_nn(YH, 24, W, 24, P, 24, My, 24, 24, tid);
  if (ucase) {
    for (int i = tid; i < My * 24; i += NT) {
      int k = i / 24, c = i - k * 24;
      X[i] = P[i] * S[c];
    }
    for (int i = tid; i < 24 * tC; i += NT) {
      int c = i / tC, x = i - c * tC;
      site[i] = Zr[x * ZLD + SEL[c]] / S[c];
    }
  } else {
    for (int i = tid; i < 24 * My; i += NT) {
      int c = i / My, x = i - c * My;
      site[i] = P[x * 24 + c];
    }
    for (int i = tid; i < Rz * 24; i += NT) {
      int k = i / 24, c = i - k * 24;
      X[i] = Zr[k * ZLD + SEL[c]];
    }
  }
  __syncthreads();
}

// SVD of t (R x 36), keep 24
__device__ void svdV36d(const double* t, int R, double* site, double* X,
                        double* Dd, char* lp, int tid) {
  float* B = L_B(lp); float* J = L_J(lp);
  for (int i = tid; i < R * 36; i += NT) B[i] = (float)t[i];
  __syncthreads();
  jacobi36(B, R, J, L_FLAG(lp), tid);
  colnorms_sel(B, R, 36, 36, 24, lp, tid);
  int* SEL = L_SEL(lp);
  double* Y0 = Dd + M_Y0;
  for (int i = tid; i < 36 * 24; i += NT) {
    int x = i / 24, c = i - x * 24;
    Y0[i] = (double)J[x * 36 + SEL[c]];
  }
  __syncthreads();
  refine(t, R, 36, 36, 0, site, X, Dd, lp, tid);
}

// SVD of t (36 x 144), keep 24
__device__ void svdU36d(const double* t, double* site, double* X,
                        double* Dd, char* lp, int tid) {
  float* B = L_B(lp); float* J = L_J(lp);
  for (int i = tid; i < 144 * 36; i += NT) {
    int x = i / 36, k = i - x * 36;
    B[i] = (float)t[k * 144 + x];
  }
  __syncthreads();
  jacobi36(B, 144, J, L_FLAG(lp), tid);
  colnorms_sel(B, 144, 36, 36, 24, lp, tid);
  int* SEL = L_SEL(lp);
  double* Y0 = Dd + M_Y0;
  for (int i = tid; i < 36 * 24; i += NT) {
    int x = i / 24, c = i - x * 24;
    Y0[i] = (double)J[x * 36 + SEL[c]];
  }
  __syncthreads();
  refine(t, 36, 144, 36, 1, site, X, Dd, lp, tid);
}

// SVD of t (144 x 144), keep 24 — B at stride 145
__device__ void stepJ3bigd(const double* t, double* site, double* X,
                           double* Dd, char* lp, int tid) {
  float* B = L_B(lp);
  for (int i = tid; i < 144 * 144; i += NT) {
    int r = i / 144, c = i - r * 144;
    B[r * J144LD + c] = (float)t[i];
  }
  __syncthreads();
  jacobi144(B, L_FLAG(lp), tid);
  colnorms_sel(B, 144, 144, J144LD, 24, lp, tid);
  int* SEL = L_SEL(lp);
  double* Y0 = Dd + M_Y0;
  for (int i = tid; i < 144 * 24; i += NT) {
    int k = i / 24, c = i - k * 24;
    Y0[i] = (double)B[k * J144LD + SEL[c]];
  }
  __syncthreads();
  refine(t, 144, 144, 144, 1, site, X, Dd, lp, tid);
}

// LQ of t5 (36x6)
__device__ void stepJ5(const double* t5, double* G, double* T, double* Qp,
                       double* cand5, double* X5, int tid) {
  mm_nt(t5, 6, t5, 6, G, 6, 6, 6, 6, tid);
  cholesky(G, 6, tid);
  trinv(G, 6, T, tid);
  mm_tn(t5, 6, T, 6, Qp, 6, 6, 6, 6, tid);
  for (int i = tid; i < 36; i += NT) {
    int l = i / 6, mu = i - l * 6;
    cand5[i] = Qp[mu * 6 + l];
  }
  __syncthreads();
  mm_nn(t5, 6, Qp, 6, X5, 6, 36, 6, 6, tid);
}

// LQ of t1 (6x144)
__device__ void stepJ1(const double* t1, double* G, double* T,
                       double* cand1, double* X1, int tid) {
  mm_nt(t1, 144, t1, 144, G, 6, 6, 6, 144, tid);
  cholesky(G, 6, tid);
  trinv(G, 6, T, tid);
  mm_tn(T, 6, t1, 144, cand1, 144, 6, 144, 6, tid);
  for (int i = tid; i < 36; i += NT) {
    int r = i / 6, c = i - r * 6;
    X1[i] = (c <= r) ? G[c * 6 + r] : 0.0;
  }
  __syncthreads();
}

__device__ void rescale0(double* cout_, char* lp, int tid) {
  if (tid == 0) {
    double m = 0.0;
    for (int i = 0; i < 36; ++i) { double v = fabs(cout_[i]); if (v > m) m = v; }
    if (!(m > 1e-300)) m = 1.0;
    *L_SCALE(lp) = m;
    *L_LOG(lp) += log(m);
  }
  __syncthreads();
  double m = *L_SCALE(lp);
  for (int i = tid; i < 36; i += NT) cout_[i] /= m;
  __syncthreads();
}

// ---------------- one _bmps round (truncating compress to DC=24) ----------------
__device__ void run_round(int r, int b, const int* cfg, const float* tens,
                          const double* cin_, double* cout_, int tid) {
  char* lp = ldsp();
  double* Dd = g_m + (size_t)b * M_STRIDE;
  const int K  = (r == 1) ? 36 : 144;
  const int cK = (r == 1) ? 6 : 24;
  int cb[7] = {1, 6, cK, cK, cK, 6, 1};
  int co[6]; co[0] = 0;
  for (int j = 0; j < 5; ++j) co[j + 1] = co[j] + cb[j] * 6 * cb[j + 1];
  const int ob[7] = {1, 6, 24, 24, 24, 6, 1};
  int oo[6]; oo[0] = 0;
  for (int j = 0; j < 5; ++j) oo[j + 1] = oo[j] + ob[j] * 6 * ob[j + 1];
  const int roff6[6] = {0, 216, 1512, 2808, 4104, 5400};

  double* ROW = Dd + M_ROW;
  double* Dbuf = Dd + M_D;  double* Abuf = Dd + M_A;  double* A3 = Dd + M_A3;
  double* Q2 = Dd + M_Q2;   double* Q4 = Dd + M_Q4;   double* Q1 = Dd + M_Q1;  double* Q0 = Dd + M_Q0;
  double* TB = Dd + M_TB;   double* Rw = Dd + M_R;    double* Tw = Dd + M_T;   double* T3 = Dd + M_T3;
  double* G = Dd + M_G;     double* X = Dd + M_X;     double* Zp = Dd + M_Z;
  double* t5 = Dd + M_T5;   double* X5 = Dd + M_X5;   double* Qp = Dd + M_QP;
  double* X1 = Dd + M_X1;   double* t1 = Dd + M_T1;

  gather_row(cfg, tens, b, r, 6, ROW, roff6, tid);

  // ---- QR sweep (left-canonicalize); build_D fused into B-staging for j1..j4 ----
  build_D(cin_ + co[0], 1, cb[1], ROW + roff6[0], 1, 6, Dbuf, tid);
  wideQR(Dbuf, 6, 36, Q0, Rw, G, Tw, tid);

  mm_nn_bsD(Rw, 36, cin_ + co[1], 6, cb[2], ROW + roff6[1], 6, 6,
            Abuf, 6 * K, 6, 36, lp, tid);                               // A1 (6 x 6K)
  if (K == 36) tallQR(Abuf, 36, 36, Q1, Rw, G, Tw, lp, tid);
  else         wideQR(Abuf, 36, 144, Q1, Rw, G, Tw, tid);

  mm_nn_bsD(Rw, K, cin_ + co[2], cb[2], cb[3], ROW + roff6[2], 6, 6,
            Abuf, 6 * K, 36, K, lp, tid);                               // A2 (36 x 6K)
  tallQR(Abuf, 216, K, Q2, Rw, G, Tw, lp, tid);

  mm_nn_bsD(Rw, K, cin_ + co[3], cb[3], cb[4], ROW + roff6[3], 6, 6,
            A3, 6 * K, K, K, lp, tid);                                  // A3 (K x 6K)
  tallQR(A3, 6 * K, K, nullptr, Rw, G, T3, lp, tid);

  mm_nn_bsD(Rw, K, cin_ + co[4], cb[4], cb[5], ROW + roff6[4], 6, 6,
            Abuf, 216, K, K, lp, tid);                                  // A4 (K x 216)
  tallQR(Abuf, 6 * K, 36, Q4, Rw, G, Tw, lp, tid);

  build_D(cin_ + co[5], cb[5], 1, ROW + roff6[5], 6, 1, Dbuf, tid);
  mm_nn(Rw, 36, Dbuf, 6, t5, 6, 36, 6, 36, tid);

  // ---- SVD sweep (right-to-left, truncate at j=4,3,2) ----
  stepJ5(t5, G, Tw, Qp, cout_ + oo[5], X5, tid);
  mm_nn(Q4, 36, X5, 6, TB, 6, 6 * K, 6, 36, tid);                 // t4 (K x 36)
  svdV36d(TB, K, cout_ + oo[4], X, Dd, lp, tid);                  // X (K x 24)
  mm_nn_bs(T3, K, X, 24, Zp, 24, K, 24, K, lp, tid);              // Z = T3 X4
  mm_nn_bs(A3, K, Zp, 24, TB, 24, 6 * K, 24, K, lp, tid);         // t3 (K x 144)
  if (K == 144) stepJ3bigd(TB, cout_ + oo[3], X, Dd, lp, tid);
  else          svdU36d(TB, cout_ + oo[3], X, Dd, lp, tid);       // X (K x 24)
  mm_nn_bs(Q2, K, X, 24, TB, 24, 216, 24, K, lp, tid);            // t2 (36 x 144)
  svdU36d(TB, cout_ + oo[2], X, Dd, lp, tid);                     // X (36 x 24)
  mm_nn(Q1, 36, X, 24, t1, 24, 36, 24, 36, tid);                  // t1 (6 x 144)
  stepJ1(t1, G, Tw, cout_ + oo[1], X1, tid);
  mm_nn(Q0, 6, X1, 6, cout_ + oo[0], 6, 6, 6, 6, tid);            // site0
  rescale0(cout_, lp, tid);
}

// ---------------- kernel ----------------
extern "C" __global__ void __launch_bounds__(NT, 4)
peps_kernel(const int* __restrict__ cfg, const float* __restrict__ tens, float* __restrict__ out) {
  const int b = blockIdx.x;
  const int tid = threadIdx.x;
  char* lp = ldsp();
  double* CA = g_m + (size_t)b * M_STRIDE + M_CA;
  double* CB = g_m + (size_t)b * M_STRIDE + M_CB;
  if (tid == 0) *L_LOG(lp) = 0.0;

  // init cand = row 0 (bonds 1,6,6,6,6,6,1 ; up=0)
  {
    const int c1off[6] = {0, 36, 252, 468, 684, 900};
    for (int j = 0; j < 6; ++j) {
      int al = (j == 0) ? 1 : 6, ar = (j == 5) ? 1 : 6;
      const float* base = tens + (size_t)((j * 2 + cfg[b * 36 + j])) * 1296;
      int n = al * 6 * ar;
      double* dst = CA + c1off[j];
      for (int idx = tid; idx < n; idx += NT) {
        int l = idx / (6 * ar); int rest = idx - l * (6 * ar);
        int mu = rest / ar; int rr = rest - mu * ar;
        dst[idx] = (double)base[l * 216 + mu * 6 + rr];
      }
    }
    __syncthreads();
  }

  run_round(1, b, cfg, tens, CA, CB, tid);
  run_round(2, b, cfg, tens, CB, CA, tid);
  run_round(3, b, cfg, tens, CA, CB, tid);
  run_round(4, b, cfg, tens, CB, CA, tid);

  // final exact contraction of cand (in CA) with row 5 (down dim = 1)
  {
    const int roff1[6] = {0, 36, 252, 468, 684, 900};
    double* ROW = g_m + (size_t)b * M_STRIDE + M_ROW;
    gather_row(cfg, tens, b, 5, 1, ROW, roff1, tid);
    double* E = L_E(lp); double* E2 = L_E2(lp);
    if (tid == 0) E[0] = 1.0;
    __syncthreads();
    const int ob[7] = {1, 6, 24, 24, 24, 6, 1};
    int oo[6]; oo[0] = 0;
    for (int j = 0; j < 5; ++j) oo[j + 1] = oo[j] + ob[j] * 6 * ob[j + 1];
    const double* candF = CA;
    double* src = E; double* dst = E2;
    for (int j = 0; j < 6; ++j) {
      int cl = ob[j], cr = ob[j + 1];
      int al = (j == 0) ? 1 : 6, ar = (j == 5) ? 1 : 6;
      int n = cr * ar;
      for (int idx = tid; idx < n; idx += NT) {
        int rr = idx / ar, R_ = idx - rr * ar;
        double acc = 0.0;
        for (int l = 0; l < cl; ++l) {
          for (int L = 0; L < al; ++L) {
            double e = src[l * al + L];
            double s2 = 0.0;
#pragma unroll
            for (int mu = 0; mu < 6; ++mu)
              s2 += candF[oo[j] + (l * 6 + mu) * cr + rr] * ROW[roff1[j] + (L * 6 + mu) * ar + R_];
            acc += e * s2;
          }
        }
        dst[idx] = acc;
      }
      __syncthreads();
      double* tmp = src; src = dst; dst = tmp;
    }
    if (tid == 0) out[b] = (float)(src[0] * exp(*L_LOG(lp)));
  }
}

// ---------------- launch ----------------
extern "C" void kernel_launch(void* const* d_in, const int* in_sizes, int n_in,
                              void* d_out, int out_size, void* d_ws, size_t ws_size,
                              hipStream_t stream) {
  (void)in_sizes; (void)n_in; (void)out_size; (void)d_ws; (void)ws_size;
  const int* cfg = (const int*)d_in[0];
  const float* tens = (const float*)d_in[1];
  float* out = (float*)d_out;
  (void)hipFuncSetAttribute((const void*)peps_kernel,
                            hipFuncAttributeMaxDynamicSharedMemorySize, LDS_BYTES);
  peps_kernel<<<dim3(NB), dim3(NT), LDS_BYTES, stream>>>(cfg, tens, out);
}

// Round 12
// 30190.839 us; speedup vs baseline: 2.1381x; 1.1447x over previous
//
#include <hip/hip_runtime.h>
#include <math.h>

#define NT 1024
#define NB 32

// ---------------- unified fp64 arena (per-batch, element offsets) ----------------
#define M_D    0        // small D scratch (j0/j5)
#define M_A    124416   // A1/A2/A4
#define M_A3   248832   // A3 (kept through round)
#define M_Q2   373248
#define M_Q4   404352
#define M_TB   435456
#define M_Q1   456192
#define M_Q0   457488
#define M_ROW  457552
#define M_R    463168   // current R
#define M_T    483904   // current T = R^-1 (also T24 in refine)
#define M_T3   504640
#define M_G    525392
#define M_CA   546128
#define M_CB   554840
#define M_X    563552
#define M_Z    567008
#define M_T5   570464
#define M_X5   570680
#define M_QP   570896
#define M_X1   570960
#define M_T1   571024
#define M_Y0   571888
#define M_YH   575344
#define M_W    578800
#define M_P    579376
#define M_STRIDE 582832

__device__ __align__(16) double g_m[(size_t)NB * M_STRIDE];
__device__ double g_log[NB];

// ---------------- LDS layout for k_svd (byte offsets) ----------------
#define LO_J     82944
#define LO_NORM  88128
#define LO_S     89280
#define LO_SEL   89472
#define LO_FLAG  89568
#define SVD_LDS  92160

__device__ __forceinline__ char* ldsp() {
  extern __shared__ char lds_pool[];
  return lds_pool;
}
#define L_B(p)     ((float*)(p))
#define L_J(p)     ((float*)((p)+LO_J))
#define L_ZR(p)    ((double*)(p))
#define L_J24(p)   ((double*)((p)+28800))
#define L_NORM(p)  ((double*)((p)+LO_NORM))
#define L_S(p)     ((double*)((p)+LO_S))
#define L_SEL(p)   ((int*)((p)+LO_SEL))
#define L_FLAG(p)  ((int*)((p)+LO_FLAG))

// ---------------- narrow fp64 matmuls (NT-stride, per-block) ----------------
__device__ void mm_nn(const double* __restrict__ A, int lda, const double* __restrict__ Bm, int ldb,
                      double* __restrict__ C, int ldc, int M, int N, int Kd, int tid) {
  if ((N & 3) == 0) {
    int nstrip = N >> 2;
    for (int u = tid; u < M * nstrip; u += NT) {
      int i = u / nstrip, j0 = (u - i * nstrip) << 2;
      const double* a = A + (size_t)i * lda;
      const double* b = Bm + j0;
      double d0 = 0, d1 = 0, d2 = 0, d3 = 0;
      for (int k = 0; k < Kd; ++k) {
        double av = a[k];
        const double* br = b + (size_t)k * ldb;
        d0 += av * br[0]; d1 += av * br[1]; d2 += av * br[2]; d3 += av * br[3];
      }
      size_t o = (size_t)i * ldc + j0;
      C[o] = d0; C[o + 1] = d1; C[o + 2] = d2; C[o + 3] = d3;
    }
  } else {
    for (int idx = tid; idx < M * N; idx += NT) {
      int i = idx / N, j = idx - i * N;
      const double* a = A + (size_t)i * lda;
      double acc = 0.0;
      for (int k = 0; k < Kd; ++k) acc += a[k] * Bm[(size_t)k * ldb + j];
      C[(size_t)i * ldc + j] = acc;
    }
  }
  __syncthreads();
}

__device__ void mm_tn(const double* __restrict__ A, int lda, const double* __restrict__ Bm, int ldb,
                      double* __restrict__ C, int ldc, int M, int N, int Kd, int tid) {
  if ((N & 3) == 0) {
    int nstrip = N >> 2;
    for (int u = tid; u < M * nstrip; u += NT) {
      int i = u / nstrip, j0 = (u - i * nstrip) << 2;
      double d0 = 0, d1 = 0, d2 = 0, d3 = 0;
      for (int k = 0; k < Kd; ++k) {
        double av = A[(size_t)k * lda + i];
        const double* br = Bm + (size_t)k * ldb + j0;
        d0 += av * br[0]; d1 += av * br[1]; d2 += av * br[2]; d3 += av * br[3];
      }
      size_t o = (size_t)i * ldc + j0;
      C[o] = d0; C[o + 1] = d1; C[o + 2] = d2; C[o + 3] = d3;
    }
  } else {
    for (int idx = tid; idx < M * N; idx += NT) {
      int i = idx / N, j = idx - i * N;
      double acc = 0.0;
      for (int k = 0; k < Kd; ++k) acc += A[(size_t)k * lda + i] * Bm[(size_t)k * ldb + j];
      C[(size_t)i * ldc + j] = acc;
    }
  }
  __syncthreads();
}

__device__ void mm_nt(const double* __restrict__ A, int lda, const double* __restrict__ Bm, int ldb,
                      double* __restrict__ C, int ldc, int M, int N, int Kd, int tid) {
  for (int idx = tid; idx < M * N; idx += NT) {
    int i = idx / N, j = idx - i * N;
    double acc = 0.0;
    for (int k = 0; k < Kd; ++k) acc += A[(size_t)i * lda + k] * Bm[(size_t)j * ldb + k];
    C[(size_t)i * ldc + j] = acc;
  }
  __syncthreads();
}

// ---------------- panel compute (per-block, 4x4 / 2x4 reg tiles) ----------------
__device__ __forceinline__ void mm_panel_compute(const double* __restrict__ A, int lda,
                                                 const double* __restrict__ SB,
                                                 double* __restrict__ C, int ldc,
                                                 int M, int n0, int nb, int Kd, int tid) {
  int nstrip = nb >> 2;
  if ((M & 3) == 0) {
    int items = (M >> 2) * nstrip;
    for (int u = tid; u < items; u += NT) {
      int iq = u / nstrip;
      int i = iq << 2;
      int jl = (u - iq * nstrip) << 2;
      const double* a0 = A + (size_t)i * lda;
      const double* a1 = a0 + lda;
      const double* a2 = a1 + lda;
      const double* a3 = a2 + lda;
      double c00=0,c01=0,c02=0,c03=0, c10=0,c11=0,c12=0,c13=0;
      double c20=0,c21=0,c22=0,c23=0, c30=0,c31=0,c32=0,c33=0;
      for (int k = 0; k < Kd; ++k) {
        const double* bp = SB + k * nb + jl;
        double b0 = bp[0], b1 = bp[1], b2 = bp[2], b3 = bp[3];
        double av0 = a0[k], av1 = a1[k], av2 = a2[k], av3 = a3[k];
        c00 += av0*b0; c01 += av0*b1; c02 += av0*b2; c03 += av0*b3;
        c10 += av1*b0; c11 += av1*b1; c12 += av1*b2; c13 += av1*b3;
        c20 += av2*b0; c21 += av2*b1; c22 += av2*b2; c23 += av2*b3;
        c30 += av3*b0; c31 += av3*b1; c32 += av3*b2; c33 += av3*b3;
      }
      size_t o0 = (size_t)i * ldc + n0 + jl;
      size_t o1 = o0 + ldc, o2 = o1 + ldc, o3 = o2 + ldc;
      C[o0]=c00; C[o0+1]=c01; C[o0+2]=c02; C[o0+3]=c03;
      C[o1]=c10; C[o1+1]=c11; C[o1+2]=c12; C[o1+3]=c13;
      C[o2]=c20; C[o2+1]=c21; C[o2+2]=c22; C[o2+3]=c23;
      C[o3]=c30; C[o3+1]=c31; C[o3+2]=c32; C[o3+3]=c33;
    }
  } else {
    int items = (M >> 1) * nstrip;
    for (int u = tid; u < items; u += NT) {
      int iq = u / nstrip;
      int i = iq << 1;
      int jl = (u - iq * nstrip) << 2;
      const double* a0 = A + (size_t)i * lda;
      const double* a1 = a0 + lda;
      double c00=0,c01=0,c02=0,c03=0, c10=0,c11=0,c12=0,c13=0;
      for (int k = 0; k < Kd; ++k) {
        const double* bp = SB + k * nb + jl;
        double b0 = bp[0], b1 = bp[1], b2 = bp[2], b3 = bp[3];
        double av0 = a0[k], av1 = a1[k];
        c00 += av0*b0; c01 += av0*b1; c02 += av0*b2; c03 += av0*b3;
        c10 += av1*b0; c11 += av1*b1; c12 += av1*b2; c13 += av1*b3;
      }
      size_t o0 = (size_t)i * ldc + n0 + jl, o1 = o0 + ldc;
      C[o0]=c00; C[o0+1]=c01; C[o0+2]=c02; C[o0+3]=c03;
      C[o1]=c10; C[o1+1]=c11; C[o1+2]=c12; C[o1+3]=c13;
    }
  }
}

// narrow bsD (used by k_pre j1 only): all panels in one block
__device__ void mm_nn_bsD(const double* __restrict__ A, int lda,
                          const double* __restrict__ cand, int cl, int cr,
                          const double* __restrict__ rowS, int al, int ar,
                          double* __restrict__ C, int ldc,
                          int M, int Kd, char* lp, int tid) {
  double* SB = (double*)lp;
  int mnext = cr * ar;
  int N = 6 * mnext;
  for (int n0 = 0; n0 < N; n0 += 64) {
    int nb = N - n0; if (nb > 64) nb = 64;
    for (int x = tid; x < Kd * nb; x += NT) {
      int k = x / nb, j = x - k * nb;
      int col = n0 + j;
      int l = k / al, L = k - l * al;
      int d = col / mnext, rem = col - d * mnext;
      int rr = rem / ar, R_ = rem - rr * ar;
      double acc = 0.0;
#pragma unroll
      for (int mu = 0; mu < 6; ++mu)
        acc += cand[(l * 6 + mu) * cr + rr] * rowS[((L * 6 + mu) * 6 + d) * ar + R_];
      SB[x] = acc;
    }
    __syncthreads();
    mm_panel_compute(A, lda, SB, C, ldc, M, n0, nb, Kd, tid);
    __syncthreads();
  }
}

// ---------------- Cholesky / trinv / copyR (narrow) ----------------
__device__ void cholesky(double* G, int n, int tid) {
  for (int j = 0; j < n; ++j) {
    __syncthreads();
    double piv = G[(size_t)j * n + j];
    double r = sqrt(piv > 1e-300 ? piv : 1e-300);
    double inv = 1.0 / r;
    __syncthreads();
    for (int i = j + tid; i < n; i += NT)
      G[(size_t)j * n + i] = (i == j) ? r : G[(size_t)j * n + i] * inv;
    __syncthreads();
    int w = n - j - 1;
    for (int idx = tid; idx < w * w; idx += NT) {
      int ii = idx / w, kk = idx - ii * w;
      int i = j + 1 + ii, k2 = j + 1 + kk;
      if (k2 >= i) G[(size_t)i * n + k2] -= G[(size_t)j * n + i] * G[(size_t)j * n + k2];
    }
  }
  __syncthreads();
}

__device__ void trinv(const double* G, int n, double* T, int tid) {
  for (int c = tid; c < n; c += NT) {
    T[(size_t)c * n + c] = 1.0 / G[(size_t)c * n + c];
    for (int r = c - 1; r >= 0; --r) {
      double s = 0.0;
      for (int k = r + 1; k <= c; ++k) s += G[(size_t)r * n + k] * T[(size_t)k * n + c];
      T[(size_t)r * n + c] = -s / G[(size_t)r * n + r];
    }
    for (int r = c + 1; r < n; ++r) T[(size_t)r * n + c] = 0.0;
  }
  __syncthreads();
}

__device__ void copyR(const double* G, int n, double* Rw, int tid) {
  for (int idx = tid; idx < n * n; idx += NT) {
    int i = idx / n, k = idx - i * n;
    Rw[idx] = (k >= i) ? G[idx] : 0.0;
  }
  __syncthreads();
}

// small tall QR (Mr<128, Nc<=36) — narrow
__device__ void tallQR_small(const double* A, int Mr, int Nc, double* Q, double* Rw,
                             double* G, double* T, int tid) {
  mm_tn(A, Nc, A, Nc, G, Nc, Nc, Nc, Mr, tid);
  cholesky(G, Nc, tid);
  trinv(G, Nc, T, tid);
  mm_nn(A, Nc, T, Nc, Q, Nc, Mr, Nc, Nc, tid);
  copyR(G, Nc, Rw, tid);
}

__device__ void wideQR(const double* A, int Mr, int Nc, double* Q, double* Rw,
                       double* G, double* T, int tid) {
  mm_tn(A, Nc, A, Nc, G, Mr, Mr, Mr, Mr, tid);
  cholesky(G, Mr, tid);
  trinv(G, Mr, T, tid);
  mm_nn(A, Nc, T, Mr, Q, Mr, Mr, Mr, Mr, tid);
  mm_tn(Q, Mr, A, Nc, Rw, Nc, Mr, Nc, Mr, tid);
}

// ---------------- double-tensor build (narrow small) ----------------
__device__ void build_D(const double* __restrict__ cand, int cl, int cr,
                        const double* __restrict__ rowS, int al, int ar,
                        double* __restrict__ D, int tid) {
  int mnext = cr * ar;
  int ncols = 6 * mnext;
  int n = cl * al * ncols;
  for (int idx = tid; idx < n; idx += NT) {
    int row = idx / ncols, col = idx - row * ncols;
    int l = row / al, L = row - l * al;
    int d = col / mnext, rem = col - d * mnext;
    int rr = rem / ar, R_ = rem - rr * ar;
    double acc = 0.0;
#pragma unroll
    for (int mu = 0; mu < 6; ++mu)
      acc += cand[(l * 6 + mu) * cr + rr] * rowS[((L * 6 + mu) * 6 + d) * ar + R_];
    D[idx] = acc;
  }
  __syncthreads();
}

__device__ void gather_row(const int* cfg, const float* tens, int b, int r, int dd,
                           double* ROW, const int* roff, int tid) {
  for (int j = 0; j < 6; ++j) {
    int al = (j == 0) ? 1 : 6, ar = (j == 5) ? 1 : 6;
    const float* base = tens + (size_t)(((r * 6 + j) * 2 + cfg[b * 36 + r * 6 + j])) * 1296;
    int n = al * 6 * dd * ar;
    double* dst = ROW + roff[j];
    for (int idx = tid; idx < n; idx += NT) {
      int R_ = idx % ar; int t2 = idx / ar;
      int d = t2 % dd; t2 /= dd;
      int mu = t2 % 6; int L = t2 / 6;
      dst[idx] = (double)base[L * 216 + mu * 36 + d * 6 + R_];
    }
  }
  __syncthreads();
}

// ---------------- f32 Jacobi (coarse) ----------------
__device__ void jacobi36(float* B, int R, float* J, int* flag, int tid) {
  for (int i = tid; i < 36 * 36; i += NT) J[i] = ((i / 36) == (i % 36)) ? 1.f : 0.f;
  __syncthreads();
  for (int sw = 0; sw < 9; ++sw) {
    if (tid == 0) *flag = 0;
    __syncthreads();
    for (int t = 0; t < 35; ++t) {
      int s = tid >> 4, h = tid & 15;
      bool act = (tid < 288);
      int p = 0, q = 0; float c = 1.f, sn = 0.f; bool doit = false;
      if (act) {
        if (s == 0) { p = 35; q = t % 35; }
        else { p = (t + s) % 35; q = (t - s + 35) % 35; }
        float app = 0.f, aqq = 0.f, apq = 0.f;
        for (int r = h; r < R; r += 16) {
          float x = B[r * 36 + p], y = B[r * 36 + q];
          app += x * x; aqq += y * y; apq += x * y;
        }
        app += __shfl_xor(app, 1); aqq += __shfl_xor(aqq, 1); apq += __shfl_xor(apq, 1);
        app += __shfl_xor(app, 2); aqq += __shfl_xor(aqq, 2); apq += __shfl_xor(apq, 2);
        app += __shfl_xor(app, 4); aqq += __shfl_xor(aqq, 4); apq += __shfl_xor(apq, 4);
        app += __shfl_xor(app, 8); aqq += __shfl_xor(aqq, 8); apq += __shfl_xor(apq, 8);
        double g = (double)apq, aa = (double)app, bb = (double)aqq;
        if (g * g > 1e-14 * aa * bb) {
          doit = true;
          if (h == 0) *flag = 1;
          double tau = (bb - aa) / (2.0 * g);
          double tt = (tau >= 0.0 ? 1.0 : -1.0) / (fabs(tau) + sqrt(1.0 + tau * tau));
          double cc = 1.0 / sqrt(1.0 + tt * tt);
          c = (float)cc; sn = (float)(tt * cc);
        }
      }
      if (doit) {
        for (int r = h; r < R; r += 16) {
          float x = B[r * 36 + p], y = B[r * 36 + q];
          B[r * 36 + p] = c * x - sn * y;
          B[r * 36 + q] = sn * x + c * y;
        }
        for (int r = h; r < 36; r += 16) {
          float x = J[r * 36 + p], y = J[r * 36 + q];
          J[r * 36 + p] = c * x - sn * y;
          J[r * 36 + q] = sn * x + c * y;
        }
      }
      __syncthreads();
    }
    int f = *flag;
    __syncthreads();
    if (!f) break;
  }
}

#define J144LD 145
__device__ void jacobi144(float* B, int* flag, int tid) {
  for (int sw = 0; sw < 9; ++sw) {
    if (tid == 0) *flag = 0;
    __syncthreads();
    for (int t = 0; t < 143; ++t) {
      int s = tid >> 3, h = tid & 7;
      bool act = (tid < 576);
      float xp[18], xq[18];
      int p = 0, q = 0; float c = 1.f, sn = 0.f; bool doit = false;
      if (act) {
        if (s == 0) { p = 143; q = t % 143; }
        else { p = (t + s) % 143; q = (t - s + 143) % 143; }
        float app = 0.f, aqq = 0.f, apq = 0.f;
#pragma unroll
        for (int i = 0; i < 18; ++i) {
          int r = h + 8 * i;
          float x = B[r * J144LD + p], y = B[r * J144LD + q];
          xp[i] = x; xq[i] = y;
          app += x * x; aqq += y * y; apq += x * y;
        }
        app += __shfl_xor(app, 1); aqq += __shfl_xor(aqq, 1); apq += __shfl_xor(apq, 1);
        app += __shfl_xor(app, 2); aqq += __shfl_xor(aqq, 2); apq += __shfl_xor(apq, 2);
        app += __shfl_xor(app, 4); aqq += __shfl_xor(aqq, 4); apq += __shfl_xor(apq, 4);
        double g = (double)apq, aa = (double)app, bb = (double)aqq;
        if (g * g > 1e-14 * aa * bb) {
          doit = true;
          if (h == 0) *flag = 1;
          double tau = (bb - aa) / (2.0 * g);
          double tt = (tau >= 0.0 ? 1.0 : -1.0) / (fabs(tau) + sqrt(1.0 + tau * tau));
          double cc = 1.0 / sqrt(1.0 + tt * tt);
          c = (float)cc; sn = (float)(tt * cc);
        }
      }
      if (doit) {
#pragma unroll
        for (int i = 0; i < 18; ++i) {
          int r = h + 8 * i;
          B[r * J144LD + p] = c * xp[i] - sn * xq[i];
          B[r * J144LD + q] = sn * xp[i] + c * xq[i];
        }
      }
      __syncthreads();
    }
    int f = *flag;
    __syncthreads();
    if (!f) break;
  }
}

__device__ void colnorms_sel(const float* B, int R, int C, int ldb, int keep, char* lp, int tid) {
  double* NORM = L_NORM(lp); int* SEL = L_SEL(lp); double* S = L_S(lp);
  for (int c = tid; c < C; c += NT) {
    double a = 0.0;
    for (int r = 0; r < R; ++r) { float v = B[r * ldb + c]; a += (double)v * (double)v; }
    NORM[c] = a;
  }
  __syncthreads();
  if (tid == 0) {
    for (int i = 0; i < keep; ++i) {
      int bi = 0; double bv = -1.0;
      for (int x = 0; x < C; ++x) if (NORM[x] > bv) { bv = NORM[x]; bi = x; }
      SEL[i] = bi;
      S[i] = sqrt(bv > 1e-300 ? bv : 1e-300);
      NORM[bi] = -2.0;
    }
  }
  __syncthreads();
}

// ---------------- fp64 refinement ----------------
#define ZLD 25
__device__ void jacobi24d(double* Z, int R, double* J24, int* flag, int tid) {
  for (int i = tid; i < 576; i += NT) J24[i] = ((i / 24) == (i % 24)) ? 1.0 : 0.0;
  __syncthreads();
  for (int sw = 0; sw < 16; ++sw) {
    if (tid == 0) *flag = 0;
    __syncthreads();
    for (int t = 0; t < 23; ++t) {
      int s = tid >> 4, h = tid & 15;
      bool act = (tid < 192);
      int p = 0, q = 0; double c_ = 1.0, sn = 0.0; bool doit = false;
      if (act) {
        if (s == 0) { p = 23; q = t % 23; }
        else { p = (t + s) % 23; q = (t - s + 23) % 23; }
        double app = 0, aqq = 0, apq = 0;
        for (int r = h; r < R; r += 16) {
          double x = Z[r * ZLD + p], y = Z[r * ZLD + q];
          app += x * x; aqq += y * y; apq += x * y;
        }
        app += __shfl_xor(app, 1); aqq += __shfl_xor(aqq, 1); apq += __shfl_xor(apq, 1);
        app += __shfl_xor(app, 2); aqq += __shfl_xor(aqq, 2); apq += __shfl_xor(apq, 2);
        app += __shfl_xor(app, 4); aqq += __shfl_xor(aqq, 4); apq += __shfl_xor(apq, 4);
        app += __shfl_xor(app, 8); aqq += __shfl_xor(aqq, 8); apq += __shfl_xor(apq, 8);
        if (apq * apq > 1e-28 * app * aqq) {
          doit = true;
          if (h == 0) *flag = 1;
          double tau = (aqq - app) / (2.0 * apq);
          double tt = (tau >= 0.0 ? 1.0 : -1.0) / (fabs(tau) + sqrt(1.0 + tau * tau));
          double cc = 1.0 / sqrt(1.0 + tt * tt);
          c_ = cc; sn = tt * cc;
        }
      }
      if (doit) {
        for (int r = h; r < R; r += 16) {
          double x = Z[r * ZLD + p], y = Z[r * ZLD + q];
          Z[r * ZLD + p] = c_ * x - sn * y;
          Z[r * ZLD + q] = sn * x + c_ * y;
        }
        for (int r = h; r < 24; r += 16) {
          double x = J24[r * 24 + p], y = J24[r * 24 + q];
          J24[r * 24 + p] = c_ * x - sn * y;
          J24[r * 24 + q] = sn * x + c_ * y;
        }
      }
      __syncthreads();
    }
    int f = *flag;
    __syncthreads();
    if (!f) break;
  }
}

__device__ void sort24(const double* Z, int R, char* lp, int tid) {
  double* NORM = L_NORM(lp); int* SEL = L_SEL(lp); double* S = L_S(lp);
  for (int c = tid; c < 24; c += NT) {
    double a = 0.0;
    for (int r = 0; r < R; ++r) { double v = Z[r * ZLD + c]; a += v * v; }
    NORM[c] = a;
  }
  __syncthreads();
  if (tid == 0) {
    for (int i = 0; i < 24; ++i) {
      int bi = 0; double bv = -1.0;
      for (int x = 0; x < 24; ++x) if (NORM[x] > bv) { bv = NORM[x]; bi = x; }
      SEL[i] = bi;
      S[i] = sqrt(bv > 1e-300 ? bv : 1e-300);
      NORM[bi] = -2.0;
    }
  }
  __syncthreads();
}

__device__ void refine(const double* t, int tR, int tC, int My, int ucase,
                       double* site, double* X, double* Dd, char* lp, int tid) {
  double* G = Dd + M_G;   double* T24 = Dd + M_T;
  double* Y0 = Dd + M_Y0; double* YH = Dd + M_YH;
  double* W = Dd + M_W;   double* P = Dd + M_P;
  double* Zr = L_ZR(lp);  double* J24 = L_J24(lp);
  int Rz = ucase ? tC : tR;
  mm_tn(Y0, 24, Y0, 24, G, 24, 24, 24, My, tid);
  cholesky(G, 24, tid);
  trinv(G, 24, T24, tid);
  mm_nn(Y0, 24, T24, 24, YH, 24, My, 24, 24, tid);
  if (ucase) mm_tn(t, tC, YH, 24, Zr, ZLD, tC, 24, tR, tid);
  else       mm_nn(t, tC, YH, 24, Zr, ZLD, tR, 24, tC, tid);
  jacobi24d(Zr, Rz, J24, L_FLAG(lp), tid);
  sort24(Zr, Rz, lp, tid);
  int* SEL = L_SEL(lp); double* S = L_S(lp);
  for (int i = tid; i < 576; i += NT) {
    int k = i / 24, c = i - k * 24;
    W[i] = J24[k * 24 + SEL[c]];
  }
  __syncthreads();
  mm_nn(YH, 24, W, 24, P, 24, My, 24, 24, tid);
  if (ucase) {
    for (int i = tid; i < My * 24; i += NT) {
      int k = i / 24, c = i - k * 24;
      X[i] = P[i] * S[c];
    }
    for (int i = tid; i < 24 * tC; i += NT) {
      int c = i / tC, x = i - c * tC;
      site[i] = Zr[x * ZLD + SEL[c]] / S[c];
    }
  } else {
    for (int i = tid; i < 24 * My; i += NT) {
      int c = i / My, x = i - c * My;
      site[i] = P[x * 24 + c];
    }
    for (int i = tid; i < Rz * 24; i += NT) {
      int k = i / 24, c = i - k * 24;
      X[i] = Zr[k * ZLD + SEL[c]];
    }
  }
  __syncthreads();
}

__device__ void svdV36d(const double* t, int R, double* site, double* X,
                        double* Dd, char* lp, int tid) {
  float* B = L_B(lp); float* J = L_J(lp);
  for (int i = tid; i < R * 36; i += NT) B[i] = (float)t[i];
  __syncthreads();
  jacobi36(B, R, J, L_FLAG(lp), tid);
  colnorms_sel(B, R, 36, 36, 24, lp, tid);
  int* SEL = L_SEL(lp);
  double* Y0 = Dd + M_Y0;
  for (int i = tid; i < 36 * 24; i += NT) {
    int x = i / 24, c = i - x * 24;
    Y0[i] = (double)J[x * 36 + SEL[c]];
  }
  __syncthreads();
  refine(t, R, 36, 36, 0, site, X, Dd, lp, tid);
}

__device__ void svdU36d(const double* t, double* site, double* X,
                        double* Dd, char* lp, int tid) {
  float* B = L_B(lp); float* J = L_J(lp);
  for (int i = tid; i < 144 * 36; i += NT) {
    int x = i / 36, k = i - x * 36;
    B[i] = (float)t[k * 144 + x];
  }
  __syncthreads();
  jacobi36(B, 144, J, L_FLAG(lp), tid);
  colnorms_sel(B, 144, 36, 36, 24, lp, tid);
  int* SEL = L_SEL(lp);
  double* Y0 = Dd + M_Y0;
  for (int i = tid; i < 36 * 24; i += NT) {
    int x = i / 24, c = i - x * 24;
    Y0[i] = (double)J[x * 36 + SEL[c]];
  }
  __syncthreads();
  refine(t, 36, 144, 36, 1, site, X, Dd, lp, tid);
}

__device__ void stepJ3bigd(const double* t, double* site, double* X,
                           double* Dd, char* lp, int tid) {
  float* B = L_B(lp);
  for (int i = tid; i < 144 * 144; i += NT) {
    int r = i / 144, c = i - r * 144;
    B[r * J144LD + c] = (float)t[i];
  }
  __syncthreads();
  jacobi144(B, L_FLAG(lp), tid);
  colnorms_sel(B, 144, 144, J144LD, 24, lp, tid);
  int* SEL = L_SEL(lp);
  double* Y0 = Dd + M_Y0;
  for (int i = tid; i < 144 * 24; i += NT) {
    int k = i / 24, c = i - k * 24;
    Y0[i] = (double)B[k * J144LD + SEL[c]];
  }
  __syncthreads();
  refine(t, 144, 144, 144, 1, site, X, Dd, lp, tid);
}

__device__ void stepJ5(const double* t5, double* G, double* T, double* Qp,
                       double* cand5, double* X5, int tid) {
  mm_nt(t5, 6, t5, 6, G, 6, 6, 6, 6, tid);
  cholesky(G, 6, tid);
  trinv(G, 6, T, tid);
  mm_tn(t5, 6, T, 6, Qp, 6, 6, 6, 6, tid);
  for (int i = tid; i < 36; i += NT) {
    int l = i / 6, mu = i - l * 6;
    cand5[i] = Qp[mu * 6 + l];
  }
  __syncthreads();
  mm_nn(t5, 6, Qp, 6, X5, 6, 36, 6, 6, tid);
}

__device__ void stepJ1(const double* t1, double* G, double* T,
                       double* cand1, double* X1, int tid) {
  mm_nt(t1, 144, t1, 144, G, 6, 6, 6, 144, tid);
  cholesky(G, 6, tid);
  trinv(G, 6, T, tid);
  mm_tn(T, 6, t1, 144, cand1, 144, 6, 144, 6, tid);
  for (int i = tid; i < 36; i += NT) {
    int r = i / 6, c = i - r * 6;
    X1[i] = (c <= r) ? G[c * 6 + r] : 0.0;
  }
  __syncthreads();
}

// ============================ GLOBAL KERNELS ============================

extern "C" __global__ void __launch_bounds__(NT)
k_init(const int* __restrict__ cfg, const float* __restrict__ tens) {
  int b = blockIdx.x, tid = threadIdx.x;
  double* CA = g_m + (size_t)b * M_STRIDE + M_CA;
  if (tid == 0) g_log[b] = 0.0;
  const int c1off[6] = {0, 36, 252, 468, 684, 900};
  for (int j = 0; j < 6; ++j) {
    int al = (j == 0) ? 1 : 6, ar = (j == 5) ? 1 : 6;
    const float* base = tens + (size_t)((j * 2 + cfg[b * 36 + j])) * 1296;
    int n = al * 6 * ar;
    double* dst = CA + c1off[j];
    for (int idx = tid; idx < n; idx += NT) {
      int l = idx / (6 * ar); int rest = idx - l * (6 * ar);
      int mu = rest / ar; int rr = rest - mu * ar;
      dst[idx] = (double)base[l * 216 + mu * 6 + rr];
    }
  }
}

// gather row, j0 QR, j1 build+QR
extern "C" __global__ void __launch_bounds__(NT)
k_pre(const int* __restrict__ cfg, const float* __restrict__ tens,
      int r, int K, int cin_off, int co1) {
  int b = blockIdx.x, tid = threadIdx.x;
  char* lp = ldsp();
  double* Dd = g_m + (size_t)b * M_STRIDE;
  const double* cin_ = Dd + cin_off;
  const int roff6[6] = {0, 216, 1512, 2808, 4104, 5400};
  int cK = (K == 36) ? 6 : 24;
  double* ROW = Dd + M_ROW; double* Dbuf = Dd + M_D; double* Abuf = Dd + M_A;
  double* Q0 = Dd + M_Q0; double* Q1 = Dd + M_Q1;
  double* Rw = Dd + M_R;  double* Tw = Dd + M_T; double* G = Dd + M_G;
  gather_row(cfg, tens, b, r, 6, ROW, roff6, tid);
  build_D(cin_, 1, 6, ROW, 1, 6, Dbuf, tid);
  wideQR(Dbuf, 6, 36, Q0, Rw, G, Tw, tid);
  mm_nn_bsD(Rw, 36, cin_ + co1, 6, cK, ROW + 216, 6, 6, Abuf, 6 * K, 6, 36, lp, tid);
  if (K == 36) tallQR_small(Abuf, 36, 36, Q1, Rw, G, Tw, tid);
  else         wideQR(Abuf, 36, 144, Q1, Rw, G, Tw, tid);
}

// wide bsD: one panel per block; A = Rw (lda=Kd); al=ar=6
extern "C" __global__ void __launch_bounds__(NT)
k_bsD(int NP, int cin_off, int coj, int cl, int cr, int rowoff,
      int dst_off, int ldc, int M, int Kd) {
  int b = blockIdx.x / NP, p = blockIdx.x % NP;
  int tid = threadIdx.x;
  double* Dd = g_m + (size_t)b * M_STRIDE;
  const double* cand = Dd + cin_off + coj;
  const double* rowS = Dd + M_ROW + rowoff;
  const double* A = Dd + M_R;
  double* C = Dd + dst_off;
  double* SB = (double*)ldsp();
  int mnext = cr * 6;
  int N = 6 * mnext;
  int n0 = p * 64;
  int nb = N - n0; if (nb > 64) nb = 64;
  for (int x = tid; x < Kd * nb; x += NT) {
    int k = x / nb, j = x - k * nb;
    int col = n0 + j;
    int l = k / 6, L = k - l * 6;
    int d = col / mnext, rem = col - d * mnext;
    int rr = rem / 6, R_ = rem - rr * 6;
    double acc = 0.0;
#pragma unroll
    for (int mu = 0; mu < 6; ++mu)
      acc += cand[(l * 6 + mu) * cr + rr] * rowS[((L * 6 + mu) * 6 + d) * 6 + R_];
    SB[x] = acc;
  }
  __syncthreads();
  mm_panel_compute(A, Kd, SB, C, ldc, M, n0, nb, Kd, tid);
}

// wide gram: G upper = A^T A, direct global reads (L2-resident A)
extern "C" __global__ void __launch_bounds__(NT)
k_gram(int NG, int src_off, int nc, int Mr) {
  int b = blockIdx.x / NG, w = blockIdx.x % NG;
  int gt = w * NT + threadIdx.x, gs = NG * NT;
  const double* A = g_m + (size_t)b * M_STRIDE + src_off;
  double* G = g_m + (size_t)b * M_STRIDE + M_G;
  int nstrip = nc >> 2;
  for (int u = gt; u < nc * nstrip; u += gs) {
    int i = u / nstrip, j0 = (u - i * nstrip) << 2;
    if (j0 + 3 < i) continue;
    double d0 = 0, d1 = 0, d2 = 0, d3 = 0;
    for (int k = 0; k < Mr; ++k) {
      double a = A[(size_t)k * nc + i];
      const double* br = A + (size_t)k * nc + j0;
      d0 += a * br[0]; d1 += a * br[1]; d2 += a * br[2]; d3 += a * br[3];
    }
    if (j0 >= i)     G[(size_t)i * nc + j0]     = d0;
    if (j0 + 1 >= i) G[(size_t)i * nc + j0 + 1] = d1;
    if (j0 + 2 >= i) G[(size_t)i * nc + j0 + 2] = d2;
    G[(size_t)i * nc + j0 + 3] = d3;
  }
}

extern "C" __global__ void __launch_bounds__(NT)
k_choltrinv(int n, int T_off) {
  int b = blockIdx.x, tid = threadIdx.x;
  double* G = g_m + (size_t)b * M_STRIDE + M_G;
  double* T = g_m + (size_t)b * M_STRIDE + T_off;
  double* Rw = g_m + (size_t)b * M_STRIDE + M_R;
  cholesky(G, n, tid);
  trinv(G, n, T, tid);
  copyR(G, n, Rw, tid);
}

// wide qmult (panel): Q = A(Mxn)*T(nxn)
extern "C" __global__ void __launch_bounds__(NT)
k_qmultp(int NP, int A_off, int T_off, int Q_off, int M, int n) {
  int b = blockIdx.x / NP, p = blockIdx.x % NP;
  int tid = threadIdx.x;
  double* Dd = g_m + (size_t)b * M_STRIDE;
  const double* A = Dd + A_off;
  const double* T = Dd + T_off;
  double* Q = Dd + Q_off;
  double* SB = (double*)ldsp();
  int n0 = p * 64, nb = n - n0; if (nb > 64) nb = 64;
  for (int x = tid; x < n * nb; x += NT) {
    int k = x / nb, j = x - k * nb;
    SB[x] = T[(size_t)k * n + n0 + j];
  }
  __syncthreads();
  mm_panel_compute(A, n, SB, Q, n, M, n0, nb, n, tid);
}

// wide flat mm: C = A*B (direct global B)
extern "C" __global__ void __launch_bounds__(NT)
k_mmflat(int NW, int A_off, int lda, int B_off, int ldb, int C_off, int ldc,
         int M, int N, int Kd) {
  int b = blockIdx.x / NW, w = blockIdx.x % NW;
  int gt = w * NT + threadIdx.x, gs = NW * NT;
  double* Dd = g_m + (size_t)b * M_STRIDE;
  const double* A = Dd + A_off;
  const double* Bm = Dd + B_off;
  double* C = Dd + C_off;
  if ((N & 3) == 0) {
    int nstrip = N >> 2;
    for (int u = gt; u < M * nstrip; u += gs) {
      int i = u / nstrip, j0 = (u - i * nstrip) << 2;
      const double* a = A + (size_t)i * lda;
      const double* bp = Bm + j0;
      double d0 = 0, d1 = 0, d2 = 0, d3 = 0;
      for (int k = 0; k < Kd; ++k) {
        double av = a[k];
        const double* br = bp + (size_t)k * ldb;
        d0 += av * br[0]; d1 += av * br[1]; d2 += av * br[2]; d3 += av * br[3];
      }
      size_t o = (size_t)i * ldc + j0;
      C[o] = d0; C[o + 1] = d1; C[o + 2] = d2; C[o + 3] = d3;
    }
  } else {
    for (int idx = gt; idx < M * N; idx += gs) {
      int i = idx / N, j = idx - i * N;
      const double* a = A + (size_t)i * lda;
      double acc = 0.0;
      for (int k = 0; k < Kd; ++k) acc += a[k] * Bm[(size_t)k * ldb + j];
      C[(size_t)i * ldc + j] = acc;
    }
  }
}

extern "C" __global__ void __launch_bounds__(NT)
k_j5(int cin_off, int co5, int cout_off) {
  int b = blockIdx.x, tid = threadIdx.x;
  double* Dd = g_m + (size_t)b * M_STRIDE;
  build_D(Dd + cin_off + co5, 6, 1, Dd + M_ROW + 5400, 6, 1, Dd + M_D, tid);
  mm_nn(Dd + M_R, 36, Dd + M_D, 6, Dd + M_T5, 6, 36, 6, 36, tid);
  stepJ5(Dd + M_T5, Dd + M_G, Dd + M_T, Dd + M_QP, Dd + cout_off + 8676, Dd + M_X5, tid);
}

extern "C" __global__ void __launch_bounds__(NT)
k_svd(int mode, int K, int site_off, int X_off) {
  int b = blockIdx.x, tid = threadIdx.x;
  char* lp = ldsp();
  double* Dd = g_m + (size_t)b * M_STRIDE;
  const double* t = Dd + M_TB;
  double* site = Dd + site_off;
  double* X = Dd + X_off;
  if (mode == 0) {
    svdV36d(t, K, site, X, Dd, lp, tid);
  } else if (mode == 1) {
    if (K == 144) stepJ3bigd(t, site, X, Dd, lp, tid);
    else          svdU36d(t, site, X, Dd, lp, tid);
  } else {
    svdU36d(t, site, X, Dd, lp, tid);
  }
}

extern "C" __global__ void __launch_bounds__(NT)
k_tail(int cout_off) {
  int b = blockIdx.x, tid = threadIdx.x;
  double* Dd = g_m + (size_t)b * M_STRIDE;
  mm_nn(Dd + M_Q1, 36, Dd + M_X, 24, Dd + M_T1, 24, 36, 24, 36, tid);   // t1
  stepJ1(Dd + M_T1, Dd + M_G, Dd + M_T, Dd + cout_off + 36, Dd + M_X1, tid);
  mm_nn(Dd + M_Q0, 6, Dd + M_X1, 6, Dd + cout_off, 6, 6, 6, 6, tid);    // site0
  __shared__ double sc;
  double* cout_ = Dd + cout_off;
  if (tid == 0) {
    double m = 0.0;
    for (int i = 0; i < 36; ++i) { double v = fabs(cout_[i]); if (v > m) m = v; }
    if (!(m > 1e-300)) m = 1.0;
    sc = m;
    g_log[b] += log(m);
  }
  __syncthreads();
  double m = sc;
  for (int i = tid; i < 36; i += NT) cout_[i] /= m;
}

extern "C" __global__ void __launch_bounds__(NT)
k_final(const int* __restrict__ cfg, const float* __restrict__ tens, float* __restrict__ out) {
  int b = blockIdx.x, tid = threadIdx.x;
  __shared__ double E[144], E2[144];
  double* Dd = g_m + (size_t)b * M_STRIDE;
  const int roff1[6] = {0, 36, 252, 468, 684, 900};
  double* ROW = Dd + M_ROW;
  gather_row(cfg, tens, b, 5, 1, ROW, roff1, tid);
  if (tid == 0) E[0] = 1.0;
  __syncthreads();
  const int ob[7] = {1, 6, 24, 24, 24, 6, 1};
  int oo[6]; oo[0] = 0;
  for (int j = 0; j < 5; ++j) oo[j + 1] = oo[j] + ob[j] * 6 * ob[j + 1];
  const double* candF = Dd + M_CA;
  double* src = E; double* dst = E2;
  for (int j = 0; j < 6; ++j) {
    int cl = ob[j], cr = ob[j + 1];
    int al = (j == 0) ? 1 : 6, ar = (j == 5) ? 1 : 6;
    int n = cr * ar;
    for (int idx = tid; idx < n; idx += NT) {
      int rr = idx / ar, R_ = idx - rr * ar;
      double acc = 0.0;
      for (int l = 0; l < cl; ++l) {
        for (int L = 0; L < al; ++L) {
          double e = src[l * al + L];
          double s2 = 0.0;
#pragma unroll
          for (int mu = 0; mu < 6; ++mu)
            s2 += candF[oo[j] + (l * 6 + mu) * cr + rr] * ROW[roff1[j] + (L * 6 + mu) * ar + R_];
          acc += e * s2;
        }
      }
      dst[idx] = acc;
    }
    __syncthreads();
    double* tmp = src; src = dst; dst = tmp;
  }
  if (tid == 0) out[b] = (float)(src[0] * exp(g_log[b]));
}

// ---------------- launch ----------------
extern "C" void kernel_launch(void* const* d_in, const int* in_sizes, int n_in,
                              void* d_out, int out_size, void* d_ws, size_t ws_size,
                              hipStream_t stream) {
  (void)in_sizes; (void)n_in; (void)out_size; (void)d_ws; (void)ws_size;
  const int* cfg = (const int*)d_in[0];
  const float* tens = (const float*)d_in[1];
  float* out = (float*)d_out;

  (void)hipFuncSetAttribute((const void*)k_svd,
                            hipFuncAttributeMaxDynamicSharedMemorySize, SVD_LDS);
  (void)hipFuncSetAttribute((const void*)k_bsD,
                            hipFuncAttributeMaxDynamicSharedMemorySize, 73728);
  (void)hipFuncSetAttribute((const void*)k_qmultp,
                            hipFuncAttributeMaxDynamicSharedMemorySize, 73728);

  hipLaunchKernelGGL(k_init, dim3(NB), dim3(NT), 0, stream, cfg, tens);

  for (int r = 1; r <= 4; ++r) {
    int K = (r == 1) ? 36 : 144;
    int cK = (r == 1) ? 6 : 24;
    int cin = (r & 1) ? M_CA : M_CB;
    int cout = (r & 1) ? M_CB : M_CA;
    int co1 = 36;
    int co2 = co1 + 36 * cK;
    int co3 = co2 + cK * 6 * cK;
    int co4 = co3 + cK * 6 * cK;
    int co5 = co4 + cK * 36;
    int NP = (36 * cK + 63) / 64;   // panels for j2/j3 (216→4, 864→14)

    hipLaunchKernelGGL(k_pre, dim3(NB), dim3(NT), 18432, stream, cfg, tens, r, K, cin, co1);
    // j2
    hipLaunchKernelGGL(k_bsD, dim3(NB * NP), dim3(NT), 73728, stream,
                       NP, cin, co2, cK, cK, 1512, M_A, 6 * K, 36, K);
    hipLaunchKernelGGL(k_gram, dim3(NB * 8), dim3(NT), 0, stream, 8, M_A, K, 216);
    hipLaunchKernelGGL(k_choltrinv, dim3(NB), dim3(NT), 0, stream, K, M_T);
    if (K == 144)
      hipLaunchKernelGGL(k_qmultp, dim3(NB * 3), dim3(NT), 73728, stream,
                         3, M_A, M_T, M_Q2, 216, 144);
    else
      hipLaunchKernelGGL(k_mmflat, dim3(NB * 4), dim3(NT), 0, stream,
                         4, M_A, 36, M_T, 36, M_Q2, 36, 216, 36, 36);
    // j3
    hipLaunchKernelGGL(k_bsD, dim3(NB * NP), dim3(NT), 73728, stream,
                       NP, cin, co3, cK, cK, 2808, M_A3, 6 * K, K, K);
    hipLaunchKernelGGL(k_gram, dim3(NB * 8), dim3(NT), 0, stream, 8, M_A3, K, 6 * K);
    hipLaunchKernelGGL(k_choltrinv, dim3(NB), dim3(NT), 0, stream, K, M_T3);
    // j4
    hipLaunchKernelGGL(k_bsD, dim3(NB * 4), dim3(NT), 73728, stream,
                       4, cin, co4, cK, 6, 4104, M_A, 216, K, K);
    hipLaunchKernelGGL(k_gram, dim3(NB * 8), dim3(NT), 0, stream, 8, M_A, 36, 6 * K);
    hipLaunchKernelGGL(k_choltrinv, dim3(NB), dim3(NT), 0, stream, 36, M_T);
    hipLaunchKernelGGL(k_mmflat, dim3(NB * 8), dim3(NT), 0, stream,
                       8, M_A, 36, M_T, 36, M_Q4, 36, 6 * K, 36, 36);   // Q4
    // j5
    hipLaunchKernelGGL(k_j5, dim3(NB), dim3(NT), 0, stream, cin, co5, cout);
    // SVD sweep
    hipLaunchKernelGGL(k_mmflat, dim3(NB * 8), dim3(NT), 0, stream,
                       8, M_Q4, 36, M_X5, 6, M_TB, 6, 6 * K, 6, 36);     // t4
    hipLaunchKernelGGL(k_svd, dim3(NB), dim3(NT), SVD_LDS, stream, 0, K, cout + 7812, M_X);
    hipLaunchKernelGGL(k_mmflat, dim3(NB * 8), dim3(NT), 0, stream,
                       8, M_T3, K, M_X, 24, M_Z, 24, K, 24, K);          // Z
    hipLaunchKernelGGL(k_mmflat, dim3(NB * 8), dim3(NT), 0, stream,
                       8, M_A3, K, M_Z, 24, M_TB, 24, 6 * K, 24, K);     // t3
    hipLaunchKernelGGL(k_svd, dim3(NB), dim3(NT), SVD_LDS, stream, 1, K, cout + 4356, M_X);
    hipLaunchKernelGGL(k_mmflat, dim3(NB * 8), dim3(NT), 0, stream,
                       8, M_Q2, K, M_X, 24, M_TB, 24, 216, 24, K);       // t2
    hipLaunchKernelGGL(k_svd, dim3(NB), dim3(NT), SVD_LDS, stream, 2, K, cout + 900, M_X);
    hipLaunchKernelGGL(k_tail, dim3(NB), dim3(NT), 0, stream, cout);
  }
  hipLaunchKernelGGL(k_final, dim3(NB), dim3(NT), 0, stream, cfg, tens, out);
}